// Round 13
// baseline (606.522 us; speedup 1.0000x reference)
//
#include <hip/hip_runtime.h>
#include <hip/hip_fp16.h>
#include <math.h>

// Shapes (fixed): B=2, H=16, L=8192, dh=64, D=1024, 3*INNER=3072, NPROJ=7,
// BLOCK=256, SAMPLE=256.

typedef _Float16 f16x8 __attribute__((ext_vector_type(8)));
typedef _Float16 f16x4 __attribute__((ext_vector_type(4)));
typedef __fp16 fp16x2 __attribute__((ext_vector_type(2)));   // cvt_pkrtz native type
typedef float f32x4 __attribute__((ext_vector_type(4)));

#define WLIST_CAP 524288
#define TAU 0.08f

__device__ __forceinline__ void gl_lds16(const void* g, void* s) {
    __builtin_amdgcn_global_load_lds(
        (const __attribute__((address_space(1))) unsigned int*)g,
        (__attribute__((address_space(3))) unsigned int*)s, 16, 0, 0);
}

// ---- fold (fp64 exact) + f16 fold matrix for the MFMA hash pass ----
__global__ __launch_bounds__(256) void fold_kernel(
    const float* __restrict__ W, const float* __restrict__ bias,
    const float* __restrict__ proj, double* __restrict__ fold,
    double* __restrict__ bfold, _Float16* __restrict__ foldh,
    float* __restrict__ bfold32)
{
    int idx = blockIdx.x * 256 + threadIdx.x;
    if (idx < 2 * 16 * 7 * 1024) {
        int task = idx / 7168;
        int rem = idx - task * 7168;
        int i = rem / 7;
        int r = rem - i * 7;
        int h = task & 15, w = task >> 4;
        double s = 0.0;
        const float* wp = W + (size_t)i * 3072 + w * 1024 + h * 64;
        for (int d = 0; d < 64; ++d)
            s += (double)wp[d] * (double)proj[d * 7 + r];
        fold[idx] = s;
        foldh[((size_t)task * 7 + r) * 1024 + i] = (_Float16)s;
    }
    if (idx < 32768)    // zero-pad foldh rows 224..255
        foldh[229376 + idx] = (_Float16)0.f;
    if (idx < 224) {
        int r = idx % 7;
        int task = idx / 7;
        int h = task & 15, w = task >> 4;
        double s = 0.0;
        for (int d = 0; d < 64; ++d)
            s += (double)bias[w * 1024 + h * 64 + d] * (double)proj[d * 7 + r];
        bfold[idx] = s;
        bfold32[idx] = (float)s;
    }
}

// ---- hash extract: scores + bias -> gray hash; flag |val|<TAU ----
__global__ __launch_bounds__(256) void hashext_kernel(
    const float* __restrict__ scores, const float* __restrict__ bfold32,
    int* __restrict__ hq, int* __restrict__ hk,
    int* __restrict__ wcount, int* __restrict__ wlist)
{
    int tid = blockIdx.x * 256 + threadIdx.x;
    int row = tid >> 5, task = tid & 31;
    const float* sp = scores + (size_t)row * 256 + task * 7;
    int id = 0, fl = 0;
#pragma unroll
    for (int r = 0; r < 7; ++r) {
        float val = sp[r] + bfold32[task * 7 + r];
        if (fabsf(val) < TAU) fl = 1;
        if (val > 0.f) id |= (1 << r);
    }
    int hsh = id ^ (id >> 1);
    int w = task >> 4, h = task & 15;
    int b = row >> 13, l = row & 8191;
    (w ? hk : hq)[((size_t)(b * 16 + h) << 13) + l] = hsh;
    if (fl) {
        int slot = atomicAdd(wcount, 1);
        if (slot < WLIST_CAP) wlist[slot] = task * 16384 + row;
    }
}

// ---- refine: one WAVE per flagged (task,row); lane-parallel exact fp64 dot ----
__global__ __launch_bounds__(256) void refine_kernel(
    const float* __restrict__ x, const double* __restrict__ fold,
    const double* __restrict__ bfold, const int* __restrict__ wcount,
    const int* __restrict__ wlist, int* __restrict__ hq, int* __restrict__ hk)
{
    int n = *wcount;
    if (n > WLIST_CAP) n = WLIST_CAP;
    int lane = threadIdx.x & 63;
    int wid = (blockIdx.x * 256 + threadIdx.x) >> 6;
    int nw = gridDim.x * 4;
    for (int e = wid; e < n; e += nw) {
        int code = wlist[e];
        int task = code >> 14, grow = code & 16383;
        const double* f = fold + (size_t)task * 7168;
        const float* xp = x + (size_t)grow * 1024;
        double acc[7] = {0, 0, 0, 0, 0, 0, 0};
        for (int i = lane; i < 1024; i += 64) {
            double xv = (double)xp[i];
#pragma unroll
            for (int rr = 0; rr < 7; ++rr)
                acc[rr] = fma(xv, f[(size_t)i * 7 + rr], acc[rr]);
        }
        int id = 0;
#pragma unroll
        for (int rr = 0; rr < 7; ++rr) {
            double a = acc[rr];
#pragma unroll
            for (int off = 32; off > 0; off >>= 1) a += __shfl_xor(a, off, 64);
            if (a + bfold[task * 7 + rr] > 0.0) id |= (1 << rr);
        }
        if (lane == 0) {
            int hsh = id ^ (id >> 1);
            int w = task >> 4, h = task & 15;
            int b = grow >> 13, l = grow & 8191;
            (w ? hk : hq)[((size_t)(b * 16 + h) << 13) + l] = hsh;
        }
    }
}

// ---- stable counting sort (128 buckets) per (b,h); also emits rank (inverse) ----
__global__ __launch_bounds__(256) void sort_kernel(
    const int* __restrict__ hq, const int* __restrict__ hk,
    int* __restrict__ qidx, int* __restrict__ kidx,
    int* __restrict__ qrank, int* __restrict__ krank)
{
    __shared__ unsigned short cnt[128][128];
    __shared__ int tot[128];
    __shared__ int base[128];
    int blk = blockIdx.x;
    int sel = blk >> 5, bh = blk & 31;
    const int* hp = (sel ? hk : hq) + ((size_t)bh << 13);
    int* op = (sel ? kidx : qidx) + ((size_t)bh << 13);
    int* rp = (sel ? krank : qrank) + ((size_t)bh << 13);
    int t = threadIdx.x;
    for (int i = t; i < 128 * 128 / 2; i += 256) ((unsigned int*)cnt)[i] = 0u;
    __syncthreads();
    if (t < 128) {
        const int* p = hp + t * 64;
        for (int j = 0; j < 64; ++j) cnt[t][p[j]]++;
    }
    __syncthreads();
    if (t < 128) {
        int run = 0;
        for (int c = 0; c < 128; ++c) {
            int x2 = cnt[c][t];
            cnt[c][t] = (unsigned short)run;
            run += x2;
        }
        tot[t] = run;
    }
    __syncthreads();
    if (t == 0) {
        int run = 0;
        for (int v = 0; v < 128; ++v) { base[v] = run; run += tot[v]; }
    }
    __syncthreads();
    if (t < 128) {
        const int* p = hp + t * 64;
        for (int j = 0; j < 64; ++j) {
            int v = p[j];
            int c = cnt[t][v];
            cnt[t][v] = (unsigned short)(c + 1);
            int pos = base[v] + c;
            op[pos] = t * 64 + j;
            rp[t * 64 + j] = pos;
        }
    }
}

// ---- cast x fp32 -> f16 ----
__global__ __launch_bounds__(256) void castx_kernel(
    const float* __restrict__ x, _Float16* __restrict__ xh)
{
    int i = blockIdx.x * 256 + threadIdx.x;
    float4 f = ((const float4*)x)[i];
    _Float16 h4[4] = {(_Float16)f.x, (_Float16)f.y, (_Float16)f.z, (_Float16)f.w};
    *(short4*)&xh[(size_t)i * 4] = *(short4*)h4;
}

// ---- transpose+cast: W[K][N] fp32 -> Wt[N][K] f16 ----
__global__ __launch_bounds__(256) void transpose_kernel(
    const float* __restrict__ W, _Float16* __restrict__ Wt, int K, int N)
{
    __shared__ float tile[32][33];
    int bx = blockIdx.x, by = blockIdx.y;
    int tx = threadIdx.x & 31, ty = threadIdx.x >> 5;
    for (int i = ty; i < 32; i += 8)
        tile[i][tx] = W[(size_t)(by * 32 + i) * N + bx * 32 + tx];
    __syncthreads();
    for (int i = ty; i < 32; i += 8)
        Wt[(size_t)(bx * 32 + i) * K + by * 32 + tx] = (_Float16)tile[tx][i];
}

// ---- gather sampled K/V rows (sorted order) into dense per-bh buffers ----
__global__ __launch_bounds__(256) void gather_samp_kernel(
    const _Float16* __restrict__ ks, const _Float16* __restrict__ vs,
    const int* __restrict__ sampled, _Float16* __restrict__ ksamp,
    _Float16* __restrict__ vsamp)
{
    int bh = blockIdx.x;
    int key = blockIdx.y * 64 + (threadIdx.x >> 2);
    int qtr = (threadIdx.x & 3) * 16;
    size_t hb = (size_t)bh << 13;
    int p = sampled[bh * 256 + key];
    size_t src = (hb + p) * 64 + qtr;
    size_t dst = ((size_t)bh * 256 + key) * 64 + qtr;
    *(f16x8*)(ksamp + dst)     = *(const f16x8*)(ks + src);
    *(f16x8*)(ksamp + dst + 8) = *(const f16x8*)(ks + src + 8);
    *(f16x8*)(vsamp + dst)     = *(const f16x8*)(vs + src);
    *(f16x8*)(vsamp + dst + 8) = *(const f16x8*)(vs + src + 8);
}

// ---- plain f16 MFMA GEMM (m97 structure): MODE 0 = +bias, MODE 2 = no bias ----
template <int MODE>
__global__ __launch_bounds__(256) void mfma_gemm(
    const _Float16* __restrict__ A, const _Float16* __restrict__ Bt,
    const float* __restrict__ bias, float* __restrict__ C, int K, int N)
{
    __shared__ __align__(16) _Float16 As[128 * 32];
    __shared__ __align__(16) _Float16 Bs[128 * 32];
    int t = threadIdx.x;
    int w = t >> 6, l = t & 63;
    int m0 = blockIdx.y * 128, n0 = blockIdx.x * 128;
    const _Float16* ga = A + (size_t)(m0 + 32 * w + (l >> 2)) * K + (l & 3) * 8;
    const _Float16* gb = Bt + (size_t)(n0 + 32 * w + (l >> 2)) * K + (l & 3) * 8;
    char* lasA = (char*)As + w * 2048;
    char* lasB = (char*)Bs + w * 2048;
    int wr = w >> 1, wc = w & 1;
    int rl = l & 15, ks = l >> 4;
    f32x4 acc[4][4];
#pragma unroll
    for (int m = 0; m < 4; ++m)
#pragma unroll
        for (int n = 0; n < 4; ++n) acc[m][n] = (f32x4){0.f, 0.f, 0.f, 0.f};
    for (int kk = 0; kk < K; kk += 32) {
        __syncthreads();
        gl_lds16(ga, lasA);
        gl_lds16(ga + 16 * K, lasA + 1024);
        gl_lds16(gb, lasB);
        gl_lds16(gb + 16 * K, lasB + 1024);
        ga += 32; gb += 32;
        __syncthreads();
        f16x8 af[4], bf[4];
#pragma unroll
        for (int m = 0; m < 4; ++m)
            af[m] = *(const f16x8*)((char*)As + (64 * wr + 16 * m + rl) * 64 + ks * 16);
#pragma unroll
        for (int n = 0; n < 4; ++n)
            bf[n] = *(const f16x8*)((char*)Bs + (64 * wc + 16 * n + rl) * 64 + ks * 16);
#pragma unroll
        for (int m = 0; m < 4; ++m)
#pragma unroll
            for (int n = 0; n < 4; ++n)
                acc[m][n] = __builtin_amdgcn_mfma_f32_16x16x32_f16(
                    af[m], bf[n], acc[m][n], 0, 0, 0);
    }
#pragma unroll
    for (int m = 0; m < 4; ++m)
#pragma unroll
        for (int n = 0; n < 4; ++n) {
            int gn = n0 + 64 * wc + 16 * n + rl;
            float bv = (MODE == 2) ? 0.f : bias[gn];
#pragma unroll
            for (int j = 0; j < 4; ++j) {
                int gm = m0 + 64 * wr + 16 * m + 4 * ks + j;
                C[(size_t)gm * N + gn] = acc[m][n][j] + bv;
            }
        }
}

// ---- QKV GEMM with SWAPPED operands: D^T = Wqkv_rows · x_rows.
// M = 3072 features (x tiles, 24), N = 16384 tokens (y tiles, 128).
// Lane holds 4 consecutive FEATURES for a fixed token -> f16x4 stores into
// sorted q/k/v; rank loads lane-coalesced. (R12: 64 scalar stores -> 16x 8B.)
__global__ __launch_bounds__(256) void gemm_qkv_kernel(
    const _Float16* __restrict__ Wt, const _Float16* __restrict__ xh,
    const float* __restrict__ bias, _Float16* __restrict__ Q,
    _Float16* __restrict__ Kb, _Float16* __restrict__ Vb,
    const int* __restrict__ qrank, const int* __restrict__ krank)
{
    const int K = 1024;
    __shared__ __align__(16) _Float16 As[128 * 32];
    __shared__ __align__(16) _Float16 Bs[128 * 32];
    int t = threadIdx.x;
    int w = t >> 6, l = t & 63;
    int m0 = blockIdx.x * 128;   // feature base
    int n0 = blockIdx.y * 128;   // token base
    const _Float16* ga = Wt + (size_t)(m0 + 32 * w + (l >> 2)) * K + (l & 3) * 8;
    const _Float16* gb = xh + (size_t)(n0 + 32 * w + (l >> 2)) * K + (l & 3) * 8;
    char* lasA = (char*)As + w * 2048;
    char* lasB = (char*)Bs + w * 2048;
    int wr = w >> 1, wc = w & 1;
    int rl = l & 15, ks = l >> 4;
    f32x4 acc[4][4];
#pragma unroll
    for (int m = 0; m < 4; ++m)
#pragma unroll
        for (int n = 0; n < 4; ++n) acc[m][n] = (f32x4){0.f, 0.f, 0.f, 0.f};
    for (int kk = 0; kk < K; kk += 32) {
        __syncthreads();
        gl_lds16(ga, lasA);
        gl_lds16(ga + 16 * K, lasA + 1024);
        gl_lds16(gb, lasB);
        gl_lds16(gb + 16 * K, lasB + 1024);
        ga += 32; gb += 32;
        __syncthreads();
        f16x8 af[4], bf[4];
#pragma unroll
        for (int m = 0; m < 4; ++m)
            af[m] = *(const f16x8*)((char*)As + (64 * wr + 16 * m + rl) * 64 + ks * 16);
#pragma unroll
        for (int n = 0; n < 4; ++n)
            bf[n] = *(const f16x8*)((char*)Bs + (64 * wc + 16 * n + rl) * 64 + ks * 16);
#pragma unroll
        for (int m = 0; m < 4; ++m)
#pragma unroll
            for (int n = 0; n < 4; ++n)
                acc[m][n] = __builtin_amdgcn_mfma_f32_16x16x32_f16(
                    af[m], bf[n], acc[m][n], 0, 0, 0);
    }
    // epilogue: rows = features (gm), cols = tokens (gn)
    int fbase = m0 + 64 * wr;                // 64-aligned feature block
    int s0 = fbase >> 10;                    // 0=q,1=k,2=v (uniform)
    int h = (fbase >> 6) & 15;               // head (uniform)
    int b2 = n0 >> 13;                       // batch (uniform)
    const int* rk = (s0 == 0) ? qrank : krank;
    _Float16* dst = (s0 == 0) ? Q : (s0 == 1 ? Kb : Vb);
    size_t bhb = ((size_t)(b2 * 16 + h) << 13);
    int tl = (n0 & 8191) + 64 * wc;          // token local base
    int pos[4];
#pragma unroll
    for (int n = 0; n < 4; ++n)
        pos[n] = rk[bhb + tl + 16 * n + rl]; // lane-coalesced
    float4 bias4[4];
#pragma unroll
    for (int m = 0; m < 4; ++m)
        bias4[m] = *(const float4*)&bias[fbase + 16 * m + 4 * ks];
#pragma unroll
    for (int m = 0; m < 4; ++m)
#pragma unroll
        for (int n = 0; n < 4; ++n) {
            f16x4 st;
            st[0] = (_Float16)(acc[m][n][0] + bias4[m].x);
            st[1] = (_Float16)(acc[m][n][1] + bias4[m].y);
            st[2] = (_Float16)(acc[m][n][2] + bias4[m].z);
            st[3] = (_Float16)(acc[m][n][3] + bias4[m].w);
            *(f16x4*)(dst + (bhb + pos[n]) * 64 + 16 * m + 4 * ks) = st;
        }
}

// ---- MFMA fused attention; all K/V reads COALESCED (sorted + pre-gathered
// sampled buffers). 2048 blocks (bh,qb,half), 4 waves x 32 queries. ----
__global__ __launch_bounds__(256) void attn_mfma_kernel(
    const _Float16* __restrict__ qs_, const _Float16* __restrict__ ks_,
    const _Float16* __restrict__ vs_, const _Float16* __restrict__ ksamp,
    const _Float16* __restrict__ vsamp, const int* __restrict__ qidx,
    const int* __restrict__ sampled, _Float16* __restrict__ pre)
{
    __shared__ __align__(16) _Float16 Vt[2][64 * 68];  // [buf][d*68 + key]
    int bh = blockIdx.x >> 6, qb = (blockIdx.x >> 1) & 31, half = blockIdx.x & 1;
    int bb = bh >> 4, hh = bh & 15;
    size_t hb = (size_t)bh << 13;
    size_t bhs = (size_t)bh * 256;
    int t = threadIdx.x;
    int w = t >> 6, l = t & 63;
    int g = l >> 4, c16 = l & 15;
    int kg = t & 15, dg = t >> 4;
    int qw0 = qb * 256 + half * 128 + w * 32;
    const _Float16 qs = (_Float16)0.125f;

    int orig[2];
    f16x8 qf[2][2];
#pragma unroll
    for (int n = 0; n < 2; ++n) {
        int row = qw0 + 16 * n + c16;
        orig[n] = qidx[hb + row];
        const _Float16* qp = qs_ + (hb + row) * 64 + g * 8;
        qf[n][0] = *(const f16x8*)(qp);
        qf[n][1] = *(const f16x8*)(qp + 32);
#pragma unroll
        for (int j = 0; j < 8; ++j) { qf[n][0][j] *= qs; qf[n][1][j] *= qs; }
    }
    f32x4 o[4][2];
    float mr[2], lr[2];
#pragma unroll
    for (int n = 0; n < 2; ++n) {
        mr[n] = -1e30f; lr[n] = 0.f;
#pragma unroll
        for (int d2 = 0; d2 < 4; ++d2) o[d2][n] = (f32x4){0.f, 0.f, 0.f, 0.f};
    }
    const float LOG32 = 3.4657359027997265f;

    {
        const _Float16* vb = vs_ + (hb + qb * 256) * 64;
        f16x4 vr[4];
#pragma unroll
        for (int j2 = 0; j2 < 4; ++j2)
            vr[j2] = *(const f16x4*)(vb + (4 * kg + j2) * 64 + 4 * dg);
#pragma unroll
        for (int i = 0; i < 4; ++i) {
            f16x4 o4 = {vr[0][i], vr[1][i], vr[2][i], vr[3][i]};
            *(f16x4*)&Vt[0][(4 * dg + i) * 68 + 4 * kg] = o4;
        }
    }

    for (int c = 0; c < 8; ++c) {
        int cur = c & 1, nxt = cur ^ 1;
        bool samp = c >= 4;
        __syncthreads();
        const _Float16* kb = samp ? ksamp + (bhs + (size_t)(c - 4) * 64) * 64
                                  : ks_ + (hb + qb * 256 + (size_t)c * 64) * 64;
        f16x8 kf[4][2];
#pragma unroll
        for (int m = 0; m < 4; ++m) {
            const _Float16* kp = kb + (16 * m + c16) * 64 + g * 8;
            kf[m][0] = *(const f16x8*)(kp);
            kf[m][1] = *(const f16x8*)(kp + 32);
        }
        int4 spv[4];
        if (samp) {
#pragma unroll
            for (int m = 0; m < 4; ++m)
                spv[m] = *(const int4*)(sampled + bhs + (c - 4) * 64 + 16 * m + 4 * g);
        }
        f32x4 sacc[4][2];
#pragma unroll
        for (int m = 0; m < 4; ++m)
#pragma unroll
            for (int n = 0; n < 2; ++n) sacc[m][n] = (f32x4){0.f, 0.f, 0.f, 0.f};
#pragma unroll
        for (int m = 0; m < 4; ++m) {
#pragma unroll
            for (int n = 0; n < 2; ++n)
                sacc[m][n] = __builtin_amdgcn_mfma_f32_16x16x32_f16(
                    kf[m][0], qf[n][0], sacc[m][n], 0, 0, 0);
#pragma unroll
            for (int n = 0; n < 2; ++n)
                sacc[m][n] = __builtin_amdgcn_mfma_f32_16x16x32_f16(
                    kf[m][1], qf[n][1], sacc[m][n], 0, 0, 0);
        }
        f16x4 vrn[4];
        if (c < 7) {
            const _Float16* vb = (c + 1 >= 4)
                ? vsamp + (bhs + (size_t)(c - 3) * 64) * 64
                : vs_ + (hb + qb * 256 + (size_t)(c + 1) * 64) * 64;
#pragma unroll
            for (int j2 = 0; j2 < 4; ++j2)
                vrn[j2] = *(const f16x4*)(vb + (4 * kg + j2) * 64 + 4 * dg);
        }
        f16x4 av[4][4];
#pragma unroll
        for (int m = 0; m < 4; ++m)
#pragma unroll
            for (int d2 = 0; d2 < 4; ++d2)
                av[m][d2] = *(const f16x4*)&Vt[cur][(16 * d2 + c16) * 68 + 16 * m + 4 * g];
        bool msk[4][4];
#pragma unroll
        for (int m = 0; m < 4; ++m) {
            msk[m][0] = samp && ((spv[m].x >> 8) == qb);
            msk[m][1] = samp && ((spv[m].y >> 8) == qb);
            msk[m][2] = samp && ((spv[m].z >> 8) == qb);
            msk[m][3] = samp && ((spv[m].w >> 8) == qb);
        }
        float badd = samp ? LOG32 : 0.f;
#pragma unroll
        for (int n = 0; n < 2; ++n) {
            float sv[16];
#pragma unroll
            for (int m = 0; m < 4; ++m)
#pragma unroll
                for (int r = 0; r < 4; ++r)
                    sv[4 * m + r] = msk[m][r] ? -1e30f : sacc[m][n][r] + badd;
            float a0 = fmaxf(fmaxf(sv[0], sv[1]), sv[2]);
            float a1 = fmaxf(fmaxf(sv[3], sv[4]), sv[5]);
            float a2 = fmaxf(fmaxf(sv[6], sv[7]), sv[8]);
            float a3 = fmaxf(fmaxf(sv[9], sv[10]), sv[11]);
            float a4 = fmaxf(fmaxf(sv[12], sv[13]), sv[14]);
            float cm = fmaxf(fmaxf(fmaxf(a0, a1), a2), fmaxf(fmaxf(a3, a4), sv[15]));
            cm = fmaxf(cm, __shfl_xor(cm, 16, 64));
            cm = fmaxf(cm, __shfl_xor(cm, 32, 64));
            if (__any(cm > mr[n])) {
                float nm = fmaxf(mr[n], cm);
                float fq = __expf(mr[n] - nm);
                mr[n] = nm;
                lr[n] *= fq;
#pragma unroll
                for (int d2 = 0; d2 < 4; ++d2) {
                    o[d2][n][0] *= fq; o[d2][n][1] *= fq;
                    o[d2][n][2] *= fq; o[d2][n][3] *= fq;
                }
            }
            float pv16[16];
#pragma unroll
            for (int r = 0; r < 16; ++r) pv16[r] = __expf(sv[r] - mr[n]);
            float s0 = (pv16[0] + pv16[1]) + (pv16[2] + pv16[3]);
            float s1 = (pv16[4] + pv16[5]) + (pv16[6] + pv16[7]);
            float s2 = (pv16[8] + pv16[9]) + (pv16[10] + pv16[11]);
            float s3 = (pv16[12] + pv16[13]) + (pv16[14] + pv16[15]);
            float ps = (s0 + s1) + (s2 + s3);
            ps += __shfl_xor(ps, 16, 64);
            ps += __shfl_xor(ps, 32, 64);
            lr[n] += ps;
            f16x4 pb[4];
#pragma unroll
            for (int m = 0; m < 4; ++m) {
                fp16x2 c0 = __builtin_amdgcn_cvt_pkrtz(pv16[4 * m + 0], pv16[4 * m + 1]);
                fp16x2 c1 = __builtin_amdgcn_cvt_pkrtz(pv16[4 * m + 2], pv16[4 * m + 3]);
                pb[m][0] = (_Float16)c0[0]; pb[m][1] = (_Float16)c0[1];
                pb[m][2] = (_Float16)c1[0]; pb[m][3] = (_Float16)c1[1];
            }
#pragma unroll
            for (int d2 = 0; d2 < 4; ++d2)
#pragma unroll
                for (int m = 0; m < 4; ++m)
                    o[d2][n] = __builtin_amdgcn_mfma_f32_16x16x16f16(
                        av[m][d2], pb[m], o[d2][n], 0, 0, 0);
        }
        if (c < 7) {
#pragma unroll
            for (int i = 0; i < 4; ++i) {
                f16x4 o4 = {vrn[0][i], vrn[1][i], vrn[2][i], vrn[3][i]};
                *(f16x4*)&Vt[nxt][(4 * dg + i) * 68 + 4 * kg] = o4;
            }
        }
    }
#pragma unroll
    for (int n = 0; n < 2; ++n) {
        float invl = 1.f / lr[n];
        _Float16* pp = pre + ((size_t)(bb * 8192 + orig[n])) * 1024 + hh * 64;
#pragma unroll
        for (int d2 = 0; d2 < 4; ++d2) {
            f16x4 st;
            st[0] = (_Float16)(o[d2][n][0] * invl);
            st[1] = (_Float16)(o[d2][n][1] * invl);
            st[2] = (_Float16)(o[d2][n][2] * invl);
            st[3] = (_Float16)(o[d2][n][3] * invl);
            *(f16x4*)(pp + 16 * d2 + 4 * g) = st;
        }
    }
}

extern "C" void kernel_launch(void* const* d_in, const int* in_sizes, int n_in,
                              void* d_out, int out_size, void* d_ws, size_t ws_size,
                              hipStream_t stream)
{
    (void)in_sizes; (void)n_in; (void)out_size; (void)ws_size;
    const float* x     = (const float*)d_in[0];
    const float* Wqkv  = (const float*)d_in[1];
    const float* bqkv  = (const float*)d_in[2];
    const float* Wproj = (const float*)d_in[3];
    const float* bproj = (const float*)d_in[4];
    const float* proj  = (const float*)d_in[5];
    const int*   samp  = (const int*)d_in[6];
    float* out = (float*)d_out;

    char* ws = (char*)d_ws;
    size_t off = 0;
    auto take = [&](size_t bytes) {
        char* p = ws + off;
        off = (off + bytes + 255) & ~(size_t)255;
        return p;
    };
    _Float16* xh  = (_Float16*)take(33554432);   // x f16; reused as `pre`
    _Float16* q   = (_Float16*)take(33554432);   // [B,H,L,64] f16, SORTED rows
    _Float16* k   = (_Float16*)take(33554432);
    _Float16* v   = (_Float16*)take(33554432);
    float* scores = (float*)take(16777216);
    _Float16* Wtq = (_Float16*)take(6291456);
    _Float16* Wtp = (_Float16*)take(2097152);
    _Float16* foldh = (_Float16*)take(524288);
    _Float16* ksamp = (_Float16*)take(1048576);  // [32][256][64] f16
    _Float16* vsamp = (_Float16*)take(1048576);
    double* fold   = (double*)take(1835008);
    double* bfold  = (double*)take(1792);
    float* bfold32 = (float*)take(896);
    int* wcount = (int*)take(256);
    int* wlist  = (int*)take(WLIST_CAP * 4);
    int* hq    = (int*)take(1048576);
    int* hk    = (int*)take(1048576);
    int* qidx  = (int*)take(1048576);
    int* kidx  = (int*)take(1048576);
    int* qrank = (int*)take(1048576);
    int* krank = (int*)take(1048576);
    _Float16* pre = xh;   // alias: xh dead after gemm_qkv
    // total ~170 MB

    (void)hipMemsetAsync(wcount, 0, 4, stream);
    castx_kernel<<<dim3(16384), dim3(256), 0, stream>>>(x, xh);
    fold_kernel<<<dim3(896), dim3(256), 0, stream>>>(
        Wqkv, bqkv, proj, fold, bfold, foldh, bfold32);
    mfma_gemm<2><<<dim3(2, 128), dim3(256), 0, stream>>>(
        xh, foldh, nullptr, scores, 1024, 256);
    hashext_kernel<<<dim3(2048), dim3(256), 0, stream>>>(
        scores, bfold32, hq, hk, wcount, wlist);
    refine_kernel<<<dim3(2048), dim3(256), 0, stream>>>(
        x, fold, bfold, wcount, wlist, hq, hk);
    sort_kernel<<<dim3(64), dim3(256), 0, stream>>>(
        hq, hk, qidx, kidx, qrank, krank);
    transpose_kernel<<<dim3(96, 32), dim3(256), 0, stream>>>(Wqkv, Wtq, 1024, 3072);
    transpose_kernel<<<dim3(32, 32), dim3(256), 0, stream>>>(Wproj, Wtp, 1024, 1024);
    gemm_qkv_kernel<<<dim3(24, 128), dim3(256), 0, stream>>>(
        Wtq, xh, bqkv, q, k, v, qrank, krank);
    gather_samp_kernel<<<dim3(32, 4), dim3(256), 0, stream>>>(
        k, v, samp, ksamp, vsamp);
    attn_mfma_kernel<<<dim3(2048), dim3(256), 0, stream>>>(
        q, k, v, ksamp, vsamp, qidx, samp, pre);
    mfma_gemm<0><<<dim3(8, 128), dim3(256), 0, stream>>>(
        pre, Wtp, bproj, out, 1024, 1024);
}

// Round 14
// 579.001 us; speedup vs baseline: 1.0475x; 1.0475x over previous
//
#include <hip/hip_runtime.h>
#include <hip/hip_fp16.h>
#include <math.h>

// Shapes (fixed): B=2, H=16, L=8192, dh=64, D=1024, 3*INNER=3072, NPROJ=7,
// BLOCK=256, SAMPLE=256.

typedef _Float16 f16x8 __attribute__((ext_vector_type(8)));
typedef _Float16 f16x4 __attribute__((ext_vector_type(4)));
typedef __fp16 fp16x2 __attribute__((ext_vector_type(2)));   // cvt_pkrtz native type
typedef float f32x4 __attribute__((ext_vector_type(4)));

#define WLIST_CAP 524288
#define TAU 0.06f

__device__ __forceinline__ void gl_lds16(const void* g, void* s) {
    __builtin_amdgcn_global_load_lds(
        (const __attribute__((address_space(1))) unsigned int*)g,
        (__attribute__((address_space(3))) unsigned int*)s, 16, 0, 0);
}

// ---- fold (fp64 exact) + f16 fold matrix for the MFMA hash pass ----
__global__ __launch_bounds__(256) void fold_kernel(
    const float* __restrict__ W, const float* __restrict__ bias,
    const float* __restrict__ proj, double* __restrict__ fold,
    double* __restrict__ bfold, _Float16* __restrict__ foldh,
    float* __restrict__ bfold32)
{
    int idx = blockIdx.x * 256 + threadIdx.x;
    if (idx < 2 * 16 * 7 * 1024) {
        int task = idx / 7168;
        int rem = idx - task * 7168;
        int i = rem / 7;
        int r = rem - i * 7;
        int h = task & 15, w = task >> 4;
        double s = 0.0;
        const float* wp = W + (size_t)i * 3072 + w * 1024 + h * 64;
        for (int d = 0; d < 64; ++d)
            s += (double)wp[d] * (double)proj[d * 7 + r];
        fold[idx] = s;
        foldh[((size_t)task * 7 + r) * 1024 + i] = (_Float16)s;
    }
    if (idx < 32768)    // zero-pad foldh rows 224..255
        foldh[229376 + idx] = (_Float16)0.f;
    if (idx < 224) {
        int r = idx % 7;
        int task = idx / 7;
        int h = task & 15, w = task >> 4;
        double s = 0.0;
        for (int d = 0; d < 64; ++d)
            s += (double)bias[w * 1024 + h * 64 + d] * (double)proj[d * 7 + r];
        bfold[idx] = s;
        bfold32[idx] = (float)s;
    }
}

// ---- hash extract: scores + bias -> gray hash; flag |val|<TAU ----
__global__ __launch_bounds__(256) void hashext_kernel(
    const float* __restrict__ scores, const float* __restrict__ bfold32,
    int* __restrict__ hq, int* __restrict__ hk,
    int* __restrict__ wcount, int* __restrict__ wlist)
{
    int tid = blockIdx.x * 256 + threadIdx.x;
    int row = tid >> 5, task = tid & 31;
    const float* sp = scores + (size_t)row * 256 + task * 7;
    int id = 0, fl = 0;
#pragma unroll
    for (int r = 0; r < 7; ++r) {
        float val = sp[r] + bfold32[task * 7 + r];
        if (fabsf(val) < TAU) fl = 1;
        if (val > 0.f) id |= (1 << r);
    }
    int hsh = id ^ (id >> 1);
    int w = task >> 4, h = task & 15;
    int b = row >> 13, l = row & 8191;
    (w ? hk : hq)[((size_t)(b * 16 + h) << 13) + l] = hsh;
    if (fl) {
        int slot = atomicAdd(wcount, 1);
        if (slot < WLIST_CAP) wlist[slot] = task * 16384 + row;
    }
}

// ---- refine: one WAVE per flagged (task,row); lane-parallel exact fp64 dot ----
__global__ __launch_bounds__(256) void refine_kernel(
    const float* __restrict__ x, const double* __restrict__ fold,
    const double* __restrict__ bfold, const int* __restrict__ wcount,
    const int* __restrict__ wlist, int* __restrict__ hq, int* __restrict__ hk)
{
    int n = *wcount;
    if (n > WLIST_CAP) n = WLIST_CAP;
    int lane = threadIdx.x & 63;
    int wid = (blockIdx.x * 256 + threadIdx.x) >> 6;
    int nw = gridDim.x * 4;
    for (int e = wid; e < n; e += nw) {
        int code = wlist[e];
        int task = code >> 14, grow = code & 16383;
        const double* f = fold + (size_t)task * 7168;
        const float* xp = x + (size_t)grow * 1024;
        double acc[7] = {0, 0, 0, 0, 0, 0, 0};
        for (int i = lane; i < 1024; i += 64) {
            double xv = (double)xp[i];
#pragma unroll
            for (int rr = 0; rr < 7; ++rr)
                acc[rr] = fma(xv, f[(size_t)i * 7 + rr], acc[rr]);
        }
        int id = 0;
#pragma unroll
        for (int rr = 0; rr < 7; ++rr) {
            double a = acc[rr];
#pragma unroll
            for (int off = 32; off > 0; off >>= 1) a += __shfl_xor(a, off, 64);
            if (a + bfold[task * 7 + rr] > 0.0) id |= (1 << rr);
        }
        if (lane == 0) {
            int hsh = id ^ (id >> 1);
            int w = task >> 4, h = task & 15;
            int b = grow >> 13, l = grow & 8191;
            (w ? hk : hq)[((size_t)(b * 16 + h) << 13) + l] = hsh;
        }
    }
}

// ---- stable counting sort (128 buckets) per (b,h); also emits rank (inverse) ----
__global__ __launch_bounds__(256) void sort_kernel(
    const int* __restrict__ hq, const int* __restrict__ hk,
    int* __restrict__ qidx, int* __restrict__ kidx,
    int* __restrict__ qrank, int* __restrict__ krank)
{
    __shared__ unsigned short cnt[128][128];
    __shared__ int tot[128];
    __shared__ int base[128];
    int blk = blockIdx.x;
    int sel = blk >> 5, bh = blk & 31;
    const int* hp = (sel ? hk : hq) + ((size_t)bh << 13);
    int* op = (sel ? kidx : qidx) + ((size_t)bh << 13);
    int* rp = (sel ? krank : qrank) + ((size_t)bh << 13);
    int t = threadIdx.x;
    for (int i = t; i < 128 * 128 / 2; i += 256) ((unsigned int*)cnt)[i] = 0u;
    __syncthreads();
    if (t < 128) {
        const int* p = hp + t * 64;
        for (int j = 0; j < 64; ++j) cnt[t][p[j]]++;
    }
    __syncthreads();
    if (t < 128) {
        int run = 0;
        for (int c = 0; c < 128; ++c) {
            int x2 = cnt[c][t];
            cnt[c][t] = (unsigned short)run;
            run += x2;
        }
        tot[t] = run;
    }
    __syncthreads();
    if (t == 0) {
        int run = 0;
        for (int v = 0; v < 128; ++v) { base[v] = run; run += tot[v]; }
    }
    __syncthreads();
    if (t < 128) {
        const int* p = hp + t * 64;
        for (int j = 0; j < 64; ++j) {
            int v = p[j];
            int c = cnt[t][v];
            cnt[t][v] = (unsigned short)(c + 1);
            int pos = base[v] + c;
            op[pos] = t * 64 + j;
            rp[t * 64 + j] = pos;
        }
    }
}

// ---- cast x fp32 -> f16 ----
__global__ __launch_bounds__(256) void castx_kernel(
    const float* __restrict__ x, _Float16* __restrict__ xh)
{
    int i = blockIdx.x * 256 + threadIdx.x;
    float4 f = ((const float4*)x)[i];
    _Float16 h4[4] = {(_Float16)f.x, (_Float16)f.y, (_Float16)f.z, (_Float16)f.w};
    *(short4*)&xh[(size_t)i * 4] = *(short4*)h4;
}

// ---- transpose+cast: W[K][N] fp32 -> Wt[N][K] f16 ----
__global__ __launch_bounds__(256) void transpose_kernel(
    const float* __restrict__ W, _Float16* __restrict__ Wt, int K, int N)
{
    __shared__ float tile[32][33];
    int bx = blockIdx.x, by = blockIdx.y;
    int tx = threadIdx.x & 31, ty = threadIdx.x >> 5;
    for (int i = ty; i < 32; i += 8)
        tile[i][tx] = W[(size_t)(by * 32 + i) * N + bx * 32 + tx];
    __syncthreads();
    for (int i = ty; i < 32; i += 8)
        Wt[(size_t)(bx * 32 + i) * K + by * 32 + tx] = (_Float16)tile[tx][i];
}

// ---- gather sampled K/V rows (sorted order) into dense per-bh buffers ----
__global__ __launch_bounds__(256) void gather_samp_kernel(
    const _Float16* __restrict__ ks, const _Float16* __restrict__ vs,
    const int* __restrict__ sampled, _Float16* __restrict__ ksamp,
    _Float16* __restrict__ vsamp)
{
    int bh = blockIdx.x;
    int key = blockIdx.y * 64 + (threadIdx.x >> 2);
    int qtr = (threadIdx.x & 3) * 16;
    size_t hb = (size_t)bh << 13;
    int p = sampled[bh * 256 + key];
    size_t src = (hb + p) * 64 + qtr;
    size_t dst = ((size_t)bh * 256 + key) * 64 + qtr;
    *(f16x8*)(ksamp + dst)     = *(const f16x8*)(ks + src);
    *(f16x8*)(ksamp + dst + 8) = *(const f16x8*)(ks + src + 8);
    *(f16x8*)(vsamp + dst)     = *(const f16x8*)(vs + src);
    *(f16x8*)(vsamp + dst + 8) = *(const f16x8*)(vs + src + 8);
}

// ---- plain f16 MFMA GEMM (m97 structure): MODE 0 = +bias, MODE 2 = no bias ----
template <int MODE>
__global__ __launch_bounds__(256) void mfma_gemm(
    const _Float16* __restrict__ A, const _Float16* __restrict__ Bt,
    const float* __restrict__ bias, float* __restrict__ C, int K, int N)
{
    __shared__ __align__(16) _Float16 As[128 * 32];
    __shared__ __align__(16) _Float16 Bs[128 * 32];
    int t = threadIdx.x;
    int w = t >> 6, l = t & 63;
    int m0 = blockIdx.y * 128, n0 = blockIdx.x * 128;
    const _Float16* ga = A + (size_t)(m0 + 32 * w + (l >> 2)) * K + (l & 3) * 8;
    const _Float16* gb = Bt + (size_t)(n0 + 32 * w + (l >> 2)) * K + (l & 3) * 8;
    char* lasA = (char*)As + w * 2048;
    char* lasB = (char*)Bs + w * 2048;
    int wr = w >> 1, wc = w & 1;
    int rl = l & 15, ks = l >> 4;
    f32x4 acc[4][4];
#pragma unroll
    for (int m = 0; m < 4; ++m)
#pragma unroll
        for (int n = 0; n < 4; ++n) acc[m][n] = (f32x4){0.f, 0.f, 0.f, 0.f};
    for (int kk = 0; kk < K; kk += 32) {
        __syncthreads();
        gl_lds16(ga, lasA);
        gl_lds16(ga + 16 * K, lasA + 1024);
        gl_lds16(gb, lasB);
        gl_lds16(gb + 16 * K, lasB + 1024);
        ga += 32; gb += 32;
        __syncthreads();
        f16x8 af[4], bf[4];
#pragma unroll
        for (int m = 0; m < 4; ++m)
            af[m] = *(const f16x8*)((char*)As + (64 * wr + 16 * m + rl) * 64 + ks * 16);
#pragma unroll
        for (int n = 0; n < 4; ++n)
            bf[n] = *(const f16x8*)((char*)Bs + (64 * wc + 16 * n + rl) * 64 + ks * 16);
#pragma unroll
        for (int m = 0; m < 4; ++m)
#pragma unroll
            for (int n = 0; n < 4; ++n)
                acc[m][n] = __builtin_amdgcn_mfma_f32_16x16x32_f16(
                    af[m], bf[n], acc[m][n], 0, 0, 0);
    }
#pragma unroll
    for (int m = 0; m < 4; ++m)
#pragma unroll
        for (int n = 0; n < 4; ++n) {
            int gn = n0 + 64 * wc + 16 * n + rl;
            float bv = (MODE == 2) ? 0.f : bias[gn];
#pragma unroll
            for (int j = 0; j < 4; ++j) {
                int gm = m0 + 64 * wr + 16 * m + 4 * ks + j;
                C[(size_t)gm * N + gn] = acc[m][n][j] + bv;
            }
        }
}

// ---- QKV GEMM, swapped operands (features x tokens), XCD-chunked grid.
// 1-D grid 3072; xcd = bid&7 owns features [3*xcd*128, (3*xcd+3)*128) x all
// tokens, token-major -> xh token panel L2-hot, W panel L2-resident.
__global__ __launch_bounds__(256) void gemm_qkv_kernel(
    const _Float16* __restrict__ Wt, const _Float16* __restrict__ xh,
    const float* __restrict__ bias, _Float16* __restrict__ Q,
    _Float16* __restrict__ Kb, _Float16* __restrict__ Vb,
    const int* __restrict__ qrank, const int* __restrict__ krank)
{
    const int K = 1024;
    __shared__ __align__(16) _Float16 As[128 * 32];
    __shared__ __align__(16) _Float16 Bs[128 * 32];
    int bid = blockIdx.x;
    int xcd = bid & 7, slot = bid >> 3;      // slot 0..383
    int y = slot / 3, xl = slot - y * 3;
    int xt = xcd * 3 + xl;
    int m0 = xt * 128;                       // feature base
    int n0 = y * 128;                        // token base
    int t = threadIdx.x;
    int w = t >> 6, l = t & 63;
    const _Float16* ga = Wt + (size_t)(m0 + 32 * w + (l >> 2)) * K + (l & 3) * 8;
    const _Float16* gb = xh + (size_t)(n0 + 32 * w + (l >> 2)) * K + (l & 3) * 8;
    char* lasA = (char*)As + w * 2048;
    char* lasB = (char*)Bs + w * 2048;
    int wr = w >> 1, wc = w & 1;
    int rl = l & 15, ks = l >> 4;
    // epilogue metadata hoisted above K-loop (latency off the tail)
    int fbase = m0 + 64 * wr;
    int s0 = fbase >> 10;
    int h = (fbase >> 6) & 15;
    int b2 = n0 >> 13;
    const int* rk = (s0 == 0) ? qrank : krank;
    _Float16* dst = (s0 == 0) ? Q : (s0 == 1 ? Kb : Vb);
    size_t bhb = ((size_t)(b2 * 16 + h) << 13);
    int tl = (n0 & 8191) + 64 * wc;
    int pos[4];
#pragma unroll
    for (int n = 0; n < 4; ++n)
        pos[n] = rk[bhb + tl + 16 * n + rl];
    float4 bias4[4];
#pragma unroll
    for (int m = 0; m < 4; ++m)
        bias4[m] = *(const float4*)&bias[fbase + 16 * m + 4 * ks];
    f32x4 acc[4][4];
#pragma unroll
    for (int m = 0; m < 4; ++m)
#pragma unroll
        for (int n = 0; n < 4; ++n) acc[m][n] = (f32x4){0.f, 0.f, 0.f, 0.f};
    for (int kk = 0; kk < K; kk += 32) {
        __syncthreads();
        gl_lds16(ga, lasA);
        gl_lds16(ga + 16 * K, lasA + 1024);
        gl_lds16(gb, lasB);
        gl_lds16(gb + 16 * K, lasB + 1024);
        ga += 32; gb += 32;
        __syncthreads();
        f16x8 af[4], bf[4];
#pragma unroll
        for (int m = 0; m < 4; ++m)
            af[m] = *(const f16x8*)((char*)As + (64 * wr + 16 * m + rl) * 64 + ks * 16);
#pragma unroll
        for (int n = 0; n < 4; ++n)
            bf[n] = *(const f16x8*)((char*)Bs + (64 * wc + 16 * n + rl) * 64 + ks * 16);
#pragma unroll
        for (int m = 0; m < 4; ++m)
#pragma unroll
            for (int n = 0; n < 4; ++n)
                acc[m][n] = __builtin_amdgcn_mfma_f32_16x16x32_f16(
                    af[m], bf[n], acc[m][n], 0, 0, 0);
    }
#pragma unroll
    for (int m = 0; m < 4; ++m)
#pragma unroll
        for (int n = 0; n < 4; ++n) {
            f16x4 st;
            st[0] = (_Float16)(acc[m][n][0] + bias4[m].x);
            st[1] = (_Float16)(acc[m][n][1] + bias4[m].y);
            st[2] = (_Float16)(acc[m][n][2] + bias4[m].z);
            st[3] = (_Float16)(acc[m][n][3] + bias4[m].w);
            *(f16x4*)(dst + (bhb + pos[n]) * 64 + 16 * m + 4 * ks) = st;
        }
}

// ---- MFMA fused attention; coalesced K/V; XCD-chunked grid (4 bh per XCD) ----
__global__ __launch_bounds__(256) void attn_mfma_kernel(
    const _Float16* __restrict__ qs_, const _Float16* __restrict__ ks_,
    const _Float16* __restrict__ vs_, const _Float16* __restrict__ ksamp,
    const _Float16* __restrict__ vsamp, const int* __restrict__ qidx,
    const int* __restrict__ sampled, _Float16* __restrict__ pre)
{
    __shared__ __align__(16) _Float16 Vt[2][64 * 68];  // [buf][d*68 + key]
    int bid = blockIdx.x;
    int nb = (bid & 7) * 256 + (bid >> 3);   // XCD-chunked remap (2048%8==0)
    int bh = nb >> 6, qb = (nb >> 1) & 31, half = nb & 1;
    int bb = bh >> 4, hh = bh & 15;
    size_t hb = (size_t)bh << 13;
    size_t bhs = (size_t)bh * 256;
    int t = threadIdx.x;
    int w = t >> 6, l = t & 63;
    int g = l >> 4, c16 = l & 15;
    int kg = t & 15, dg = t >> 4;
    int qw0 = qb * 256 + half * 128 + w * 32;
    const _Float16 qs = (_Float16)0.125f;

    int orig[2];
    f16x8 qf[2][2];
#pragma unroll
    for (int n = 0; n < 2; ++n) {
        int row = qw0 + 16 * n + c16;
        orig[n] = qidx[hb + row];
        const _Float16* qp = qs_ + (hb + row) * 64 + g * 8;
        qf[n][0] = *(const f16x8*)(qp);
        qf[n][1] = *(const f16x8*)(qp + 32);
#pragma unroll
        for (int j = 0; j < 8; ++j) { qf[n][0][j] *= qs; qf[n][1][j] *= qs; }
    }
    f32x4 o[4][2];
    float mr[2], lr[2];
#pragma unroll
    for (int n = 0; n < 2; ++n) {
        mr[n] = -1e30f; lr[n] = 0.f;
#pragma unroll
        for (int d2 = 0; d2 < 4; ++d2) o[d2][n] = (f32x4){0.f, 0.f, 0.f, 0.f};
    }
    const float LOG32 = 3.4657359027997265f;

    {
        const _Float16* vb = vs_ + (hb + qb * 256) * 64;
        f16x4 vr[4];
#pragma unroll
        for (int j2 = 0; j2 < 4; ++j2)
            vr[j2] = *(const f16x4*)(vb + (4 * kg + j2) * 64 + 4 * dg);
#pragma unroll
        for (int i = 0; i < 4; ++i) {
            f16x4 o4 = {vr[0][i], vr[1][i], vr[2][i], vr[3][i]};
            *(f16x4*)&Vt[0][(4 * dg + i) * 68 + 4 * kg] = o4;
        }
    }

    for (int c = 0; c < 8; ++c) {
        int cur = c & 1, nxt = cur ^ 1;
        bool samp = c >= 4;
        __syncthreads();
        const _Float16* kb = samp ? ksamp + (bhs + (size_t)(c - 4) * 64) * 64
                                  : ks_ + (hb + qb * 256 + (size_t)c * 64) * 64;
        f16x8 kf[4][2];
#pragma unroll
        for (int m = 0; m < 4; ++m) {
            const _Float16* kp = kb + (16 * m + c16) * 64 + g * 8;
            kf[m][0] = *(const f16x8*)(kp);
            kf[m][1] = *(const f16x8*)(kp + 32);
        }
        int4 spv[4];
        if (samp) {
#pragma unroll
            for (int m = 0; m < 4; ++m)
                spv[m] = *(const int4*)(sampled + bhs + (c - 4) * 64 + 16 * m + 4 * g);
        }
        f32x4 sacc[4][2];
#pragma unroll
        for (int m = 0; m < 4; ++m)
#pragma unroll
            for (int n = 0; n < 2; ++n) sacc[m][n] = (f32x4){0.f, 0.f, 0.f, 0.f};
#pragma unroll
        for (int m = 0; m < 4; ++m) {
#pragma unroll
            for (int n = 0; n < 2; ++n)
                sacc[m][n] = __builtin_amdgcn_mfma_f32_16x16x32_f16(
                    kf[m][0], qf[n][0], sacc[m][n], 0, 0, 0);
#pragma unroll
            for (int n = 0; n < 2; ++n)
                sacc[m][n] = __builtin_amdgcn_mfma_f32_16x16x32_f16(
                    kf[m][1], qf[n][1], sacc[m][n], 0, 0, 0);
        }
        f16x4 vrn[4];
        if (c < 7) {
            const _Float16* vb = (c + 1 >= 4)
                ? vsamp + (bhs + (size_t)(c - 3) * 64) * 64
                : vs_ + (hb + qb * 256 + (size_t)(c + 1) * 64) * 64;
#pragma unroll
            for (int j2 = 0; j2 < 4; ++j2)
                vrn[j2] = *(const f16x4*)(vb + (4 * kg + j2) * 64 + 4 * dg);
        }
        f16x4 av[4][4];
#pragma unroll
        for (int m = 0; m < 4; ++m)
#pragma unroll
            for (int d2 = 0; d2 < 4; ++d2)
                av[m][d2] = *(const f16x4*)&Vt[cur][(16 * d2 + c16) * 68 + 16 * m + 4 * g];
        bool msk[4][4];
#pragma unroll
        for (int m = 0; m < 4; ++m) {
            msk[m][0] = samp && ((spv[m].x >> 8) == qb);
            msk[m][1] = samp && ((spv[m].y >> 8) == qb);
            msk[m][2] = samp && ((spv[m].z >> 8) == qb);
            msk[m][3] = samp && ((spv[m].w >> 8) == qb);
        }
        float badd = samp ? LOG32 : 0.f;
#pragma unroll
        for (int n = 0; n < 2; ++n) {
            float sv[16];
#pragma unroll
            for (int m = 0; m < 4; ++m)
#pragma unroll
                for (int r = 0; r < 4; ++r)
                    sv[4 * m + r] = msk[m][r] ? -1e30f : sacc[m][n][r] + badd;
            float a0 = fmaxf(fmaxf(sv[0], sv[1]), sv[2]);
            float a1 = fmaxf(fmaxf(sv[3], sv[4]), sv[5]);
            float a2 = fmaxf(fmaxf(sv[6], sv[7]), sv[8]);
            float a3 = fmaxf(fmaxf(sv[9], sv[10]), sv[11]);
            float a4 = fmaxf(fmaxf(sv[12], sv[13]), sv[14]);
            float cm = fmaxf(fmaxf(fmaxf(a0, a1), a2), fmaxf(fmaxf(a3, a4), sv[15]));
            cm = fmaxf(cm, __shfl_xor(cm, 16, 64));
            cm = fmaxf(cm, __shfl_xor(cm, 32, 64));
            if (__any(cm > mr[n])) {
                float nm = fmaxf(mr[n], cm);
                float fq = __expf(mr[n] - nm);
                mr[n] = nm;
                lr[n] *= fq;
#pragma unroll
                for (int d2 = 0; d2 < 4; ++d2) {
                    o[d2][n][0] *= fq; o[d2][n][1] *= fq;
                    o[d2][n][2] *= fq; o[d2][n][3] *= fq;
                }
            }
            float pv16[16];
#pragma unroll
            for (int r = 0; r < 16; ++r) pv16[r] = __expf(sv[r] - mr[n]);
            float s0 = (pv16[0] + pv16[1]) + (pv16[2] + pv16[3]);
            float s1 = (pv16[4] + pv16[5]) + (pv16[6] + pv16[7]);
            float s2 = (pv16[8] + pv16[9]) + (pv16[10] + pv16[11]);
            float s3 = (pv16[12] + pv16[13]) + (pv16[14] + pv16[15]);
            float ps = (s0 + s1) + (s2 + s3);
            ps += __shfl_xor(ps, 16, 64);
            ps += __shfl_xor(ps, 32, 64);
            lr[n] += ps;
            f16x4 pb[4];
#pragma unroll
            for (int m = 0; m < 4; ++m) {
                fp16x2 c0 = __builtin_amdgcn_cvt_pkrtz(pv16[4 * m + 0], pv16[4 * m + 1]);
                fp16x2 c1 = __builtin_amdgcn_cvt_pkrtz(pv16[4 * m + 2], pv16[4 * m + 3]);
                pb[m][0] = (_Float16)c0[0]; pb[m][1] = (_Float16)c0[1];
                pb[m][2] = (_Float16)c1[0]; pb[m][3] = (_Float16)c1[1];
            }
#pragma unroll
            for (int d2 = 0; d2 < 4; ++d2)
#pragma unroll
                for (int m = 0; m < 4; ++m)
                    o[d2][n] = __builtin_amdgcn_mfma_f32_16x16x16f16(
                        av[m][d2], pb[m], o[d2][n], 0, 0, 0);
        }
        if (c < 7) {
#pragma unroll
            for (int i = 0; i < 4; ++i) {
                f16x4 o4 = {vrn[0][i], vrn[1][i], vrn[2][i], vrn[3][i]};
                *(f16x4*)&Vt[nxt][(4 * dg + i) * 68 + 4 * kg] = o4;
            }
        }
    }
#pragma unroll
    for (int n = 0; n < 2; ++n) {
        float invl = 1.f / lr[n];
        _Float16* pp = pre + ((size_t)(bb * 8192 + orig[n])) * 1024 + hh * 64;
#pragma unroll
        for (int d2 = 0; d2 < 4; ++d2) {
            f16x4 st;
            st[0] = (_Float16)(o[d2][n][0] * invl);
            st[1] = (_Float16)(o[d2][n][1] * invl);
            st[2] = (_Float16)(o[d2][n][2] * invl);
            st[3] = (_Float16)(o[d2][n][3] * invl);
            *(f16x4*)(pp + 16 * d2 + 4 * g) = st;
        }
    }
}

extern "C" void kernel_launch(void* const* d_in, const int* in_sizes, int n_in,
                              void* d_out, int out_size, void* d_ws, size_t ws_size,
                              hipStream_t stream)
{
    (void)in_sizes; (void)n_in; (void)out_size; (void)ws_size;
    const float* x     = (const float*)d_in[0];
    const float* Wqkv  = (const float*)d_in[1];
    const float* bqkv  = (const float*)d_in[2];
    const float* Wproj = (const float*)d_in[3];
    const float* bproj = (const float*)d_in[4];
    const float* proj  = (const float*)d_in[5];
    const int*   samp  = (const int*)d_in[6];
    float* out = (float*)d_out;

    char* ws = (char*)d_ws;
    size_t off = 0;
    auto take = [&](size_t bytes) {
        char* p = ws + off;
        off = (off + bytes + 255) & ~(size_t)255;
        return p;
    };
    _Float16* xh  = (_Float16*)take(33554432);   // x f16; reused as `pre`
    _Float16* q   = (_Float16*)take(33554432);   // [B,H,L,64] f16, SORTED rows
    _Float16* k   = (_Float16*)take(33554432);
    _Float16* v   = (_Float16*)take(33554432);
    float* scores = (float*)take(16777216);
    _Float16* Wtq = (_Float16*)take(6291456);
    _Float16* Wtp = (_Float16*)take(2097152);
    _Float16* foldh = (_Float16*)take(524288);
    _Float16* ksamp = (_Float16*)take(1048576);  // [32][256][64] f16
    _Float16* vsamp = (_Float16*)take(1048576);
    double* fold   = (double*)take(1835008);
    double* bfold  = (double*)take(1792);
    float* bfold32 = (float*)take(896);
    int* wcount = (int*)take(256);
    int* wlist  = (int*)take(WLIST_CAP * 4);
    int* hq    = (int*)take(1048576);
    int* hk    = (int*)take(1048576);
    int* qidx  = (int*)take(1048576);
    int* kidx  = (int*)take(1048576);
    int* qrank = (int*)take(1048576);
    int* krank = (int*)take(1048576);
    _Float16* pre = xh;   // alias: xh dead after gemm_qkv
    // total ~170 MB

    (void)hipMemsetAsync(wcount, 0, 4, stream);
    castx_kernel<<<dim3(16384), dim3(256), 0, stream>>>(x, xh);
    fold_kernel<<<dim3(896), dim3(256), 0, stream>>>(
        Wqkv, bqkv, proj, fold, bfold, foldh, bfold32);
    mfma_gemm<2><<<dim3(2, 128), dim3(256), 0, stream>>>(
        xh, foldh, nullptr, scores, 1024, 256);
    hashext_kernel<<<dim3(2048), dim3(256), 0, stream>>>(
        scores, bfold32, hq, hk, wcount, wlist);
    refine_kernel<<<dim3(2048), dim3(256), 0, stream>>>(
        x, fold, bfold, wcount, wlist, hq, hk);
    sort_kernel<<<dim3(64), dim3(256), 0, stream>>>(
        hq, hk, qidx, kidx, qrank, krank);
    transpose_kernel<<<dim3(96, 32), dim3(256), 0, stream>>>(Wqkv, Wtq, 1024, 3072);
    transpose_kernel<<<dim3(32, 32), dim3(256), 0, stream>>>(Wproj, Wtp, 1024, 1024);
    gemm_qkv_kernel<<<dim3(3072), dim3(256), 0, stream>>>(
        Wtq, xh, bqkv, q, k, v, qrank, krank);
    gather_samp_kernel<<<dim3(32, 4), dim3(256), 0, stream>>>(
        k, v, samp, ksamp, vsamp);
    attn_mfma_kernel<<<dim3(2048), dim3(256), 0, stream>>>(
        q, k, v, ksamp, vsamp, qidx, samp, pre);
    mfma_gemm<0><<<dim3(8, 128), dim3(256), 0, stream>>>(
        pre, Wtp, bproj, out, 1024, 1024);
}

// Round 15
// 568.283 us; speedup vs baseline: 1.0673x; 1.0189x over previous
//
#include <hip/hip_runtime.h>
#include <hip/hip_fp16.h>
#include <math.h>

// Shapes (fixed): B=2, H=16, L=8192, dh=64, D=1024, 3*INNER=3072, NPROJ=7,
// BLOCK=256, SAMPLE=256.

typedef _Float16 f16x8 __attribute__((ext_vector_type(8)));
typedef _Float16 f16x4 __attribute__((ext_vector_type(4)));
typedef __fp16 fp16x2 __attribute__((ext_vector_type(2)));   // cvt_pkrtz native type
typedef float f32x4 __attribute__((ext_vector_type(4)));

#define WLIST_CAP 524288
#define TAU 0.06f

__device__ __forceinline__ void gl_lds16(const void* g, void* s) {
    __builtin_amdgcn_global_load_lds(
        (const __attribute__((address_space(1))) unsigned int*)g,
        (__attribute__((address_space(3))) unsigned int*)s, 16, 0, 0);
}

// ---- fold (fp64 exact) + f16 fold matrix for the MFMA hash pass ----
__global__ __launch_bounds__(256) void fold_kernel(
    const float* __restrict__ W, const float* __restrict__ bias,
    const float* __restrict__ proj, double* __restrict__ fold,
    double* __restrict__ bfold, _Float16* __restrict__ foldh,
    float* __restrict__ bfold32)
{
    int idx = blockIdx.x * 256 + threadIdx.x;
    if (idx < 2 * 16 * 7 * 1024) {
        int task = idx / 7168;
        int rem = idx - task * 7168;
        int i = rem / 7;
        int r = rem - i * 7;
        int h = task & 15, w = task >> 4;
        double s = 0.0;
        const float* wp = W + (size_t)i * 3072 + w * 1024 + h * 64;
        for (int d = 0; d < 64; ++d)
            s += (double)wp[d] * (double)proj[d * 7 + r];
        fold[idx] = s;
        foldh[((size_t)task * 7 + r) * 1024 + i] = (_Float16)s;
    }
    if (idx < 32768)    // zero-pad foldh rows 224..255
        foldh[229376 + idx] = (_Float16)0.f;
    if (idx < 224) {
        int r = idx % 7;
        int task = idx / 7;
        int h = task & 15, w = task >> 4;
        double s = 0.0;
        for (int d = 0; d < 64; ++d)
            s += (double)bias[w * 1024 + h * 64 + d] * (double)proj[d * 7 + r];
        bfold[idx] = s;
        bfold32[idx] = (float)s;
    }
}

// ---- hash extract: scores + bias -> gray hash; flag |val|<TAU ----
__global__ __launch_bounds__(256) void hashext_kernel(
    const float* __restrict__ scores, const float* __restrict__ bfold32,
    int* __restrict__ hq, int* __restrict__ hk,
    int* __restrict__ wcount, int* __restrict__ wlist)
{
    int tid = blockIdx.x * 256 + threadIdx.x;
    int row = tid >> 5, task = tid & 31;
    const float* sp = scores + (size_t)row * 256 + task * 7;
    int id = 0, fl = 0;
#pragma unroll
    for (int r = 0; r < 7; ++r) {
        float val = sp[r] + bfold32[task * 7 + r];
        if (fabsf(val) < TAU) fl = 1;
        if (val > 0.f) id |= (1 << r);
    }
    int hsh = id ^ (id >> 1);
    int w = task >> 4, h = task & 15;
    int b = row >> 13, l = row & 8191;
    (w ? hk : hq)[((size_t)(b * 16 + h) << 13) + l] = hsh;
    if (fl) {
        int slot = atomicAdd(wcount, 1);
        if (slot < WLIST_CAP) wlist[slot] = task * 16384 + row;
    }
}

// ---- refine: one WAVE per flagged (task,row); lane-parallel exact fp64 dot ----
__global__ __launch_bounds__(256) void refine_kernel(
    const float* __restrict__ x, const double* __restrict__ fold,
    const double* __restrict__ bfold, const int* __restrict__ wcount,
    const int* __restrict__ wlist, int* __restrict__ hq, int* __restrict__ hk)
{
    int n = *wcount;
    if (n > WLIST_CAP) n = WLIST_CAP;
    int lane = threadIdx.x & 63;
    int wid = (blockIdx.x * 256 + threadIdx.x) >> 6;
    int nw = gridDim.x * 4;
    for (int e = wid; e < n; e += nw) {
        int code = wlist[e];
        int task = code >> 14, grow = code & 16383;
        const double* f = fold + (size_t)task * 7168;
        const float* xp = x + (size_t)grow * 1024;
        double acc[7] = {0, 0, 0, 0, 0, 0, 0};
        for (int i = lane; i < 1024; i += 64) {
            double xv = (double)xp[i];
#pragma unroll
            for (int rr = 0; rr < 7; ++rr)
                acc[rr] = fma(xv, f[(size_t)i * 7 + rr], acc[rr]);
        }
        int id = 0;
#pragma unroll
        for (int rr = 0; rr < 7; ++rr) {
            double a = acc[rr];
#pragma unroll
            for (int off = 32; off > 0; off >>= 1) a += __shfl_xor(a, off, 64);
            if (a + bfold[task * 7 + rr] > 0.0) id |= (1 << rr);
        }
        if (lane == 0) {
            int hsh = id ^ (id >> 1);
            int w = task >> 4, h = task & 15;
            int b = grow >> 13, l = grow & 8191;
            (w ? hk : hq)[((size_t)(b * 16 + h) << 13) + l] = hsh;
        }
    }
}

// ---- stable counting sort (128 buckets) per (b,h); also emits rank (inverse) ----
__global__ __launch_bounds__(256) void sort_kernel(
    const int* __restrict__ hq, const int* __restrict__ hk,
    int* __restrict__ qidx, int* __restrict__ kidx,
    int* __restrict__ qrank, int* __restrict__ krank)
{
    __shared__ unsigned short cnt[128][128];
    __shared__ int tot[128];
    __shared__ int base[128];
    int blk = blockIdx.x;
    int sel = blk >> 5, bh = blk & 31;
    const int* hp = (sel ? hk : hq) + ((size_t)bh << 13);
    int* op = (sel ? kidx : qidx) + ((size_t)bh << 13);
    int* rp = (sel ? krank : qrank) + ((size_t)bh << 13);
    int t = threadIdx.x;
    for (int i = t; i < 128 * 128 / 2; i += 256) ((unsigned int*)cnt)[i] = 0u;
    __syncthreads();
    if (t < 128) {
        const int* p = hp + t * 64;
        for (int j = 0; j < 64; ++j) cnt[t][p[j]]++;
    }
    __syncthreads();
    if (t < 128) {
        int run = 0;
        for (int c = 0; c < 128; ++c) {
            int x2 = cnt[c][t];
            cnt[c][t] = (unsigned short)run;
            run += x2;
        }
        tot[t] = run;
    }
    __syncthreads();
    if (t == 0) {
        int run = 0;
        for (int v = 0; v < 128; ++v) { base[v] = run; run += tot[v]; }
    }
    __syncthreads();
    if (t < 128) {
        const int* p = hp + t * 64;
        for (int j = 0; j < 64; ++j) {
            int v = p[j];
            int c = cnt[t][v];
            cnt[t][v] = (unsigned short)(c + 1);
            int pos = base[v] + c;
            op[pos] = t * 64 + j;
            rp[t * 64 + j] = pos;
        }
    }
}

// ---- cast x fp32 -> f16 ----
__global__ __launch_bounds__(256) void castx_kernel(
    const float* __restrict__ x, _Float16* __restrict__ xh)
{
    int i = blockIdx.x * 256 + threadIdx.x;
    float4 f = ((const float4*)x)[i];
    _Float16 h4[4] = {(_Float16)f.x, (_Float16)f.y, (_Float16)f.z, (_Float16)f.w};
    *(short4*)&xh[(size_t)i * 4] = *(short4*)h4;
}

// ---- transpose+cast: W[K][N] fp32 -> Wt[N][K] f16 ----
__global__ __launch_bounds__(256) void transpose_kernel(
    const float* __restrict__ W, _Float16* __restrict__ Wt, int K, int N)
{
    __shared__ float tile[32][33];
    int bx = blockIdx.x, by = blockIdx.y;
    int tx = threadIdx.x & 31, ty = threadIdx.x >> 5;
    for (int i = ty; i < 32; i += 8)
        tile[i][tx] = W[(size_t)(by * 32 + i) * N + bx * 32 + tx];
    __syncthreads();
    for (int i = ty; i < 32; i += 8)
        Wt[(size_t)(bx * 32 + i) * K + by * 32 + tx] = (_Float16)tile[tx][i];
}

// ---- gather sampled K/V rows (sorted order) into dense per-bh buffers ----
__global__ __launch_bounds__(256) void gather_samp_kernel(
    const _Float16* __restrict__ ks, const _Float16* __restrict__ vs,
    const int* __restrict__ sampled, _Float16* __restrict__ ksamp,
    _Float16* __restrict__ vsamp)
{
    int bh = blockIdx.x;
    int key = blockIdx.y * 64 + (threadIdx.x >> 2);
    int qtr = (threadIdx.x & 3) * 16;
    size_t hb = (size_t)bh << 13;
    int p = sampled[bh * 256 + key];
    size_t src = (hb + p) * 64 + qtr;
    size_t dst = ((size_t)bh * 256 + key) * 64 + qtr;
    *(f16x8*)(ksamp + dst)     = *(const f16x8*)(ks + src);
    *(f16x8*)(ksamp + dst + 8) = *(const f16x8*)(ks + src + 8);
    *(f16x8*)(vsamp + dst)     = *(const f16x8*)(vs + src);
    *(f16x8*)(vsamp + dst + 8) = *(const f16x8*)(vs + src + 8);
}

// ---- plain f16 MFMA GEMM (m97 structure): MODE 0 = +bias, MODE 2 = no bias ----
template <int MODE>
__global__ __launch_bounds__(256) void mfma_gemm(
    const _Float16* __restrict__ A, const _Float16* __restrict__ Bt,
    const float* __restrict__ bias, float* __restrict__ C, int K, int N)
{
    __shared__ __align__(16) _Float16 As[128 * 32];
    __shared__ __align__(16) _Float16 Bs[128 * 32];
    int t = threadIdx.x;
    int w = t >> 6, l = t & 63;
    int m0 = blockIdx.y * 128, n0 = blockIdx.x * 128;
    const _Float16* ga = A + (size_t)(m0 + 32 * w + (l >> 2)) * K + (l & 3) * 8;
    const _Float16* gb = Bt + (size_t)(n0 + 32 * w + (l >> 2)) * K + (l & 3) * 8;
    char* lasA = (char*)As + w * 2048;
    char* lasB = (char*)Bs + w * 2048;
    int wr = w >> 1, wc = w & 1;
    int rl = l & 15, ks = l >> 4;
    f32x4 acc[4][4];
#pragma unroll
    for (int m = 0; m < 4; ++m)
#pragma unroll
        for (int n = 0; n < 4; ++n) acc[m][n] = (f32x4){0.f, 0.f, 0.f, 0.f};
    for (int kk = 0; kk < K; kk += 32) {
        __syncthreads();
        gl_lds16(ga, lasA);
        gl_lds16(ga + 16 * K, lasA + 1024);
        gl_lds16(gb, lasB);
        gl_lds16(gb + 16 * K, lasB + 1024);
        ga += 32; gb += 32;
        __syncthreads();
        f16x8 af[4], bf[4];
#pragma unroll
        for (int m = 0; m < 4; ++m)
            af[m] = *(const f16x8*)((char*)As + (64 * wr + 16 * m + rl) * 64 + ks * 16);
#pragma unroll
        for (int n = 0; n < 4; ++n)
            bf[n] = *(const f16x8*)((char*)Bs + (64 * wc + 16 * n + rl) * 64 + ks * 16);
#pragma unroll
        for (int m = 0; m < 4; ++m)
#pragma unroll
            for (int n = 0; n < 4; ++n)
                acc[m][n] = __builtin_amdgcn_mfma_f32_16x16x32_f16(
                    af[m], bf[n], acc[m][n], 0, 0, 0);
    }
#pragma unroll
    for (int m = 0; m < 4; ++m)
#pragma unroll
        for (int n = 0; n < 4; ++n) {
            int gn = n0 + 64 * wc + 16 * n + rl;
            float bv = (MODE == 2) ? 0.f : bias[gn];
#pragma unroll
            for (int j = 0; j < 4; ++j) {
                int gm = m0 + 64 * wr + 16 * m + 4 * ks + j;
                C[(size_t)gm * N + gn] = acc[m][n][j] + bv;
            }
        }
}

// ---- QKV GEMM, swapped operands, XCD-chunked, 3-buffer T4 pipeline:
// one barrier per K-step, counted vmcnt(4) (never 0 in loop) -> staging loads
// stay in flight across barriers instead of draining (R14: 2-phase stall).
// Race audit: STAGE(buf[(k+2)%3]) after barrier k; that buffer's last compute
// was iter k-1 (before barrier k) -> no WAR race. vmcnt(4) leaves only the
// newest 4 loads (buf[k+1]) outstanding -> buf[k] complete (FIFO).
__global__ __launch_bounds__(256) void gemm_qkv_kernel(
    const _Float16* __restrict__ Wt, const _Float16* __restrict__ xh,
    const float* __restrict__ bias, _Float16* __restrict__ Q,
    _Float16* __restrict__ Kb, _Float16* __restrict__ Vb,
    const int* __restrict__ qrank, const int* __restrict__ krank)
{
    const int K = 1024;
    __shared__ __align__(16) _Float16 As[3][128 * 32];   // 3-buffer, 48 KB total
    __shared__ __align__(16) _Float16 Bs[3][128 * 32];
    int bid = blockIdx.x;
    int xcd = bid & 7, slot = bid >> 3;
    int y = slot / 3, xl = slot - y * 3;
    int xt = xcd * 3 + xl;
    int m0 = xt * 128;                       // feature base
    int n0 = y * 128;                        // token base
    int t = threadIdx.x;
    int w = t >> 6, l = t & 63;
    const _Float16* ga = Wt + (size_t)(m0 + 32 * w + (l >> 2)) * K + (l & 3) * 8;
    const _Float16* gb = xh + (size_t)(n0 + 32 * w + (l >> 2)) * K + (l & 3) * 8;
    int wOff = w * 2048;
    int wr = w >> 1, wc = w & 1;
    int rl = l & 15, ks = l >> 4;
    // epilogue metadata hoisted above K-loop
    int fbase = m0 + 64 * wr;
    int s0 = fbase >> 10;
    int h = (fbase >> 6) & 15;
    int b2 = n0 >> 13;
    const int* rk = (s0 == 0) ? qrank : krank;
    _Float16* dst = (s0 == 0) ? Q : (s0 == 1 ? Kb : Vb);
    size_t bhb = ((size_t)(b2 * 16 + h) << 13);
    int tl = (n0 & 8191) + 64 * wc;
    int pos[4];
#pragma unroll
    for (int n = 0; n < 4; ++n)
        pos[n] = rk[bhb + tl + 16 * n + rl];
    float4 bias4[4];
#pragma unroll
    for (int m = 0; m < 4; ++m)
        bias4[m] = *(const float4*)&bias[fbase + 16 * m + 4 * ks];
    f32x4 acc[4][4];
#pragma unroll
    for (int m = 0; m < 4; ++m)
#pragma unroll
        for (int n = 0; n < 4; ++n) acc[m][n] = (f32x4){0.f, 0.f, 0.f, 0.f};

    auto STAGE = [&](int s, int kk) {
        gl_lds16(ga + kk, (char*)&As[s][0] + wOff);
        gl_lds16(ga + kk + 16 * K, (char*)&As[s][0] + wOff + 1024);
        gl_lds16(gb + kk, (char*)&Bs[s][0] + wOff);
        gl_lds16(gb + kk + 16 * K, (char*)&Bs[s][0] + wOff + 1024);
    };

    STAGE(0, 0);
    STAGE(1, 32);
    for (int k = 0; k < 32; ++k) {
        if (k < 31) asm volatile("s_waitcnt vmcnt(4)" ::: "memory");
        else        asm volatile("s_waitcnt vmcnt(0)" ::: "memory");
        __builtin_amdgcn_sched_barrier(0);
        __builtin_amdgcn_s_barrier();
        __builtin_amdgcn_sched_barrier(0);
        if (k + 2 < 32) STAGE((k + 2) % 3, (k + 2) * 32);
        int cur = k % 3;
        const char* pa = (const char*)&As[cur][0];
        const char* pb = (const char*)&Bs[cur][0];
        f16x8 af[4], bf[4];
#pragma unroll
        for (int m = 0; m < 4; ++m)
            af[m] = *(const f16x8*)(pa + (64 * wr + 16 * m + rl) * 64 + ks * 16);
#pragma unroll
        for (int n = 0; n < 4; ++n)
            bf[n] = *(const f16x8*)(pb + (64 * wc + 16 * n + rl) * 64 + ks * 16);
#pragma unroll
        for (int m = 0; m < 4; ++m)
#pragma unroll
            for (int n = 0; n < 4; ++n)
                acc[m][n] = __builtin_amdgcn_mfma_f32_16x16x32_f16(
                    af[m], bf[n], acc[m][n], 0, 0, 0);
    }
#pragma unroll
    for (int m = 0; m < 4; ++m)
#pragma unroll
        for (int n = 0; n < 4; ++n) {
            f16x4 st;
            st[0] = (_Float16)(acc[m][n][0] + bias4[m].x);
            st[1] = (_Float16)(acc[m][n][1] + bias4[m].y);
            st[2] = (_Float16)(acc[m][n][2] + bias4[m].z);
            st[3] = (_Float16)(acc[m][n][3] + bias4[m].w);
            *(f16x4*)(dst + (bhb + pos[n]) * 64 + 16 * m + 4 * ks) = st;
        }
}

// ---- MFMA fused attention; coalesced K/V; XCD-chunked grid (4 bh per XCD) ----
__global__ __launch_bounds__(256) void attn_mfma_kernel(
    const _Float16* __restrict__ qs_, const _Float16* __restrict__ ks_,
    const _Float16* __restrict__ vs_, const _Float16* __restrict__ ksamp,
    const _Float16* __restrict__ vsamp, const int* __restrict__ qidx,
    const int* __restrict__ sampled, _Float16* __restrict__ pre)
{
    __shared__ __align__(16) _Float16 Vt[2][64 * 68];  // [buf][d*68 + key]
    int bid = blockIdx.x;
    int nb = (bid & 7) * 256 + (bid >> 3);   // XCD-chunked remap (2048%8==0)
    int bh = nb >> 6, qb = (nb >> 1) & 31, half = nb & 1;
    int bb = bh >> 4, hh = bh & 15;
    size_t hb = (size_t)bh << 13;
    size_t bhs = (size_t)bh * 256;
    int t = threadIdx.x;
    int w = t >> 6, l = t & 63;
    int g = l >> 4, c16 = l & 15;
    int kg = t & 15, dg = t >> 4;
    int qw0 = qb * 256 + half * 128 + w * 32;
    const _Float16 qs = (_Float16)0.125f;

    int orig[2];
    f16x8 qf[2][2];
#pragma unroll
    for (int n = 0; n < 2; ++n) {
        int row = qw0 + 16 * n + c16;
        orig[n] = qidx[hb + row];
        const _Float16* qp = qs_ + (hb + row) * 64 + g * 8;
        qf[n][0] = *(const f16x8*)(qp);
        qf[n][1] = *(const f16x8*)(qp + 32);
#pragma unroll
        for (int j = 0; j < 8; ++j) { qf[n][0][j] *= qs; qf[n][1][j] *= qs; }
    }
    f32x4 o[4][2];
    float mr[2], lr[2];
#pragma unroll
    for (int n = 0; n < 2; ++n) {
        mr[n] = -1e30f; lr[n] = 0.f;
#pragma unroll
        for (int d2 = 0; d2 < 4; ++d2) o[d2][n] = (f32x4){0.f, 0.f, 0.f, 0.f};
    }
    const float LOG32 = 3.4657359027997265f;

    {
        const _Float16* vb = vs_ + (hb + qb * 256) * 64;
        f16x4 vr[4];
#pragma unroll
        for (int j2 = 0; j2 < 4; ++j2)
            vr[j2] = *(const f16x4*)(vb + (4 * kg + j2) * 64 + 4 * dg);
#pragma unroll
        for (int i = 0; i < 4; ++i) {
            f16x4 o4 = {vr[0][i], vr[1][i], vr[2][i], vr[3][i]};
            *(f16x4*)&Vt[0][(4 * dg + i) * 68 + 4 * kg] = o4;
        }
    }

    for (int c = 0; c < 8; ++c) {
        int cur = c & 1, nxt = cur ^ 1;
        bool samp = c >= 4;
        __syncthreads();
        const _Float16* kb = samp ? ksamp + (bhs + (size_t)(c - 4) * 64) * 64
                                  : ks_ + (hb + qb * 256 + (size_t)c * 64) * 64;
        f16x8 kf[4][2];
#pragma unroll
        for (int m = 0; m < 4; ++m) {
            const _Float16* kp = kb + (16 * m + c16) * 64 + g * 8;
            kf[m][0] = *(const f16x8*)(kp);
            kf[m][1] = *(const f16x8*)(kp + 32);
        }
        int4 spv[4];
        if (samp) {
#pragma unroll
            for (int m = 0; m < 4; ++m)
                spv[m] = *(const int4*)(sampled + bhs + (c - 4) * 64 + 16 * m + 4 * g);
        }
        f32x4 sacc[4][2];
#pragma unroll
        for (int m = 0; m < 4; ++m)
#pragma unroll
            for (int n = 0; n < 2; ++n) sacc[m][n] = (f32x4){0.f, 0.f, 0.f, 0.f};
#pragma unroll
        for (int m = 0; m < 4; ++m) {
#pragma unroll
            for (int n = 0; n < 2; ++n)
                sacc[m][n] = __builtin_amdgcn_mfma_f32_16x16x32_f16(
                    kf[m][0], qf[n][0], sacc[m][n], 0, 0, 0);
#pragma unroll
            for (int n = 0; n < 2; ++n)
                sacc[m][n] = __builtin_amdgcn_mfma_f32_16x16x32_f16(
                    kf[m][1], qf[n][1], sacc[m][n], 0, 0, 0);
        }
        f16x4 vrn[4];
        if (c < 7) {
            const _Float16* vb = (c + 1 >= 4)
                ? vsamp + (bhs + (size_t)(c - 3) * 64) * 64
                : vs_ + (hb + qb * 256 + (size_t)(c + 1) * 64) * 64;
#pragma unroll
            for (int j2 = 0; j2 < 4; ++j2)
                vrn[j2] = *(const f16x4*)(vb + (4 * kg + j2) * 64 + 4 * dg);
        }
        f16x4 av[4][4];
#pragma unroll
        for (int m = 0; m < 4; ++m)
#pragma unroll
            for (int d2 = 0; d2 < 4; ++d2)
                av[m][d2] = *(const f16x4*)&Vt[cur][(16 * d2 + c16) * 68 + 16 * m + 4 * g];
        bool msk[4][4];
#pragma unroll
        for (int m = 0; m < 4; ++m) {
            msk[m][0] = samp && ((spv[m].x >> 8) == qb);
            msk[m][1] = samp && ((spv[m].y >> 8) == qb);
            msk[m][2] = samp && ((spv[m].z >> 8) == qb);
            msk[m][3] = samp && ((spv[m].w >> 8) == qb);
        }
        float badd = samp ? LOG32 : 0.f;
#pragma unroll
        for (int n = 0; n < 2; ++n) {
            float sv[16];
#pragma unroll
            for (int m = 0; m < 4; ++m)
#pragma unroll
                for (int r = 0; r < 4; ++r)
                    sv[4 * m + r] = msk[m][r] ? -1e30f : sacc[m][n][r] + badd;
            float a0 = fmaxf(fmaxf(sv[0], sv[1]), sv[2]);
            float a1 = fmaxf(fmaxf(sv[3], sv[4]), sv[5]);
            float a2 = fmaxf(fmaxf(sv[6], sv[7]), sv[8]);
            float a3 = fmaxf(fmaxf(sv[9], sv[10]), sv[11]);
            float a4 = fmaxf(fmaxf(sv[12], sv[13]), sv[14]);
            float cm = fmaxf(fmaxf(fmaxf(a0, a1), a2), fmaxf(fmaxf(a3, a4), sv[15]));
            cm = fmaxf(cm, __shfl_xor(cm, 16, 64));
            cm = fmaxf(cm, __shfl_xor(cm, 32, 64));
            if (__any(cm > mr[n])) {
                float nm = fmaxf(mr[n], cm);
                float fq = __expf(mr[n] - nm);
                mr[n] = nm;
                lr[n] *= fq;
#pragma unroll
                for (int d2 = 0; d2 < 4; ++d2) {
                    o[d2][n][0] *= fq; o[d2][n][1] *= fq;
                    o[d2][n][2] *= fq; o[d2][n][3] *= fq;
                }
            }
            float pv16[16];
#pragma unroll
            for (int r = 0; r < 16; ++r) pv16[r] = __expf(sv[r] - mr[n]);
            float s0 = (pv16[0] + pv16[1]) + (pv16[2] + pv16[3]);
            float s1 = (pv16[4] + pv16[5]) + (pv16[6] + pv16[7]);
            float s2 = (pv16[8] + pv16[9]) + (pv16[10] + pv16[11]);
            float s3 = (pv16[12] + pv16[13]) + (pv16[14] + pv16[15]);
            float ps = (s0 + s1) + (s2 + s3);
            ps += __shfl_xor(ps, 16, 64);
            ps += __shfl_xor(ps, 32, 64);
            lr[n] += ps;
            f16x4 pb[4];
#pragma unroll
            for (int m = 0; m < 4; ++m) {
                fp16x2 c0 = __builtin_amdgcn_cvt_pkrtz(pv16[4 * m + 0], pv16[4 * m + 1]);
                fp16x2 c1 = __builtin_amdgcn_cvt_pkrtz(pv16[4 * m + 2], pv16[4 * m + 3]);
                pb[m][0] = (_Float16)c0[0]; pb[m][1] = (_Float16)c0[1];
                pb[m][2] = (_Float16)c1[0]; pb[m][3] = (_Float16)c1[1];
            }
#pragma unroll
            for (int d2 = 0; d2 < 4; ++d2)
#pragma unroll
                for (int m = 0; m < 4; ++m)
                    o[d2][n] = __builtin_amdgcn_mfma_f32_16x16x16f16(
                        av[m][d2], pb[m], o[d2][n], 0, 0, 0);
        }
        if (c < 7) {
#pragma unroll
            for (int i = 0; i < 4; ++i) {
                f16x4 o4 = {vrn[0][i], vrn[1][i], vrn[2][i], vrn[3][i]};
                *(f16x4*)&Vt[nxt][(4 * dg + i) * 68 + 4 * kg] = o4;
            }
        }
    }
#pragma unroll
    for (int n = 0; n < 2; ++n) {
        float invl = 1.f / lr[n];
        _Float16* pp = pre + ((size_t)(bb * 8192 + orig[n])) * 1024 + hh * 64;
#pragma unroll
        for (int d2 = 0; d2 < 4; ++d2) {
            f16x4 st;
            st[0] = (_Float16)(o[d2][n][0] * invl);
            st[1] = (_Float16)(o[d2][n][1] * invl);
            st[2] = (_Float16)(o[d2][n][2] * invl);
            st[3] = (_Float16)(o[d2][n][3] * invl);
            *(f16x4*)(pp + 16 * d2 + 4 * g) = st;
        }
    }
}

extern "C" void kernel_launch(void* const* d_in, const int* in_sizes, int n_in,
                              void* d_out, int out_size, void* d_ws, size_t ws_size,
                              hipStream_t stream)
{
    (void)in_sizes; (void)n_in; (void)out_size; (void)ws_size;
    const float* x     = (const float*)d_in[0];
    const float* Wqkv  = (const float*)d_in[1];
    const float* bqkv  = (const float*)d_in[2];
    const float* Wproj = (const float*)d_in[3];
    const float* bproj = (const float*)d_in[4];
    const float* proj  = (const float*)d_in[5];
    const int*   samp  = (const int*)d_in[6];
    float* out = (float*)d_out;

    char* ws = (char*)d_ws;
    size_t off = 0;
    auto take = [&](size_t bytes) {
        char* p = ws + off;
        off = (off + bytes + 255) & ~(size_t)255;
        return p;
    };
    _Float16* xh  = (_Float16*)take(33554432);   // x f16; reused as `pre`
    _Float16* q   = (_Float16*)take(33554432);   // [B,H,L,64] f16, SORTED rows
    _Float16* k   = (_Float16*)take(33554432);
    _Float16* v   = (_Float16*)take(33554432);
    float* scores = (float*)take(16777216);
    _Float16* Wtq = (_Float16*)take(6291456);
    _Float16* Wtp = (_Float16*)take(2097152);
    _Float16* foldh = (_Float16*)take(524288);
    _Float16* ksamp = (_Float16*)take(1048576);  // [32][256][64] f16
    _Float16* vsamp = (_Float16*)take(1048576);
    double* fold   = (double*)take(1835008);
    double* bfold  = (double*)take(1792);
    float* bfold32 = (float*)take(896);
    int* wcount = (int*)take(256);
    int* wlist  = (int*)take(WLIST_CAP * 4);
    int* hq    = (int*)take(1048576);
    int* hk    = (int*)take(1048576);
    int* qidx  = (int*)take(1048576);
    int* kidx  = (int*)take(1048576);
    int* qrank = (int*)take(1048576);
    int* krank = (int*)take(1048576);
    _Float16* pre = xh;   // alias: xh dead after gemm_qkv
    // total ~170 MB

    (void)hipMemsetAsync(wcount, 0, 4, stream);
    castx_kernel<<<dim3(16384), dim3(256), 0, stream>>>(x, xh);
    fold_kernel<<<dim3(896), dim3(256), 0, stream>>>(
        Wqkv, bqkv, proj, fold, bfold, foldh, bfold32);
    mfma_gemm<2><<<dim3(2, 128), dim3(256), 0, stream>>>(
        xh, foldh, nullptr, scores, 1024, 256);
    hashext_kernel<<<dim3(2048), dim3(256), 0, stream>>>(
        scores, bfold32, hq, hk, wcount, wlist);
    refine_kernel<<<dim3(2048), dim3(256), 0, stream>>>(
        x, fold, bfold, wcount, wlist, hq, hk);
    sort_kernel<<<dim3(64), dim3(256), 0, stream>>>(
        hq, hk, qidx, kidx, qrank, krank);
    transpose_kernel<<<dim3(96, 32), dim3(256), 0, stream>>>(Wqkv, Wtq, 1024, 3072);
    transpose_kernel<<<dim3(32, 32), dim3(256), 0, stream>>>(Wproj, Wtp, 1024, 1024);
    gemm_qkv_kernel<<<dim3(3072), dim3(256), 0, stream>>>(
        Wtq, xh, bqkv, q, k, v, qrank, krank);
    gather_samp_kernel<<<dim3(32, 4), dim3(256), 0, stream>>>(
        k, v, samp, ksamp, vsamp);
    attn_mfma_kernel<<<dim3(2048), dim3(256), 0, stream>>>(
        q, k, v, ksamp, vsamp, qidx, samp, pre);
    mfma_gemm<0><<<dim3(8, 128), dim3(256), 0, stream>>>(
        pre, Wtp, bproj, out, 1024, 1024);
}

// Round 16
// 561.180 us; speedup vs baseline: 1.0808x; 1.0127x over previous
//
#include <hip/hip_runtime.h>
#include <hip/hip_fp16.h>
#include <math.h>

// Shapes (fixed): B=2, H=16, L=8192, dh=64, D=1024, 3*INNER=3072, NPROJ=7,
// BLOCK=256, SAMPLE=256.

typedef _Float16 f16x8 __attribute__((ext_vector_type(8)));
typedef _Float16 f16x4 __attribute__((ext_vector_type(4)));
typedef __fp16 fp16x2 __attribute__((ext_vector_type(2)));   // cvt_pkrtz native type
typedef float f32x4 __attribute__((ext_vector_type(4)));

#define WLIST_CAP 524288
#define TAU 0.06f

__device__ __forceinline__ void gl_lds16(const void* g, void* s) {
    __builtin_amdgcn_global_load_lds(
        (const __attribute__((address_space(1))) unsigned int*)g,
        (__attribute__((address_space(3))) unsigned int*)s, 16, 0, 0);
}

// ---- fold (fp64 exact) + f16 fold matrix for the MFMA hash pass ----
__global__ __launch_bounds__(256) void fold_kernel(
    const float* __restrict__ W, const float* __restrict__ bias,
    const float* __restrict__ proj, double* __restrict__ fold,
    double* __restrict__ bfold, _Float16* __restrict__ foldh,
    float* __restrict__ bfold32)
{
    int idx = blockIdx.x * 256 + threadIdx.x;
    if (idx < 2 * 16 * 7 * 1024) {
        int task = idx / 7168;
        int rem = idx - task * 7168;
        int i = rem / 7;
        int r = rem - i * 7;
        int h = task & 15, w = task >> 4;
        double s = 0.0;
        const float* wp = W + (size_t)i * 3072 + w * 1024 + h * 64;
        for (int d = 0; d < 64; ++d)
            s += (double)wp[d] * (double)proj[d * 7 + r];
        fold[idx] = s;
        foldh[((size_t)task * 7 + r) * 1024 + i] = (_Float16)s;
    }
    if (idx < 32768)    // zero-pad foldh rows 224..255
        foldh[229376 + idx] = (_Float16)0.f;
    if (idx < 224) {
        int r = idx % 7;
        int task = idx / 7;
        int h = task & 15, w = task >> 4;
        double s = 0.0;
        for (int d = 0; d < 64; ++d)
            s += (double)bias[w * 1024 + h * 64 + d] * (double)proj[d * 7 + r];
        bfold[idx] = s;
        bfold32[idx] = (float)s;
    }
}

// ---- hash extract: scores + bias -> gray hash; flag |val|<TAU ----
__global__ __launch_bounds__(256) void hashext_kernel(
    const float* __restrict__ scores, const float* __restrict__ bfold32,
    int* __restrict__ hq, int* __restrict__ hk,
    int* __restrict__ wcount, int* __restrict__ wlist)
{
    int tid = blockIdx.x * 256 + threadIdx.x;
    int row = tid >> 5, task = tid & 31;
    const float* sp = scores + (size_t)row * 256 + task * 7;
    int id = 0, fl = 0;
#pragma unroll
    for (int r = 0; r < 7; ++r) {
        float val = sp[r] + bfold32[task * 7 + r];
        if (fabsf(val) < TAU) fl = 1;
        if (val > 0.f) id |= (1 << r);
    }
    int hsh = id ^ (id >> 1);
    int w = task >> 4, h = task & 15;
    int b = row >> 13, l = row & 8191;
    (w ? hk : hq)[((size_t)(b * 16 + h) << 13) + l] = hsh;
    if (fl) {
        int slot = atomicAdd(wcount, 1);
        if (slot < WLIST_CAP) wlist[slot] = task * 16384 + row;
    }
}

// ---- refine: one WAVE per flagged (task,row); lane-parallel exact fp64 dot ----
__global__ __launch_bounds__(256) void refine_kernel(
    const float* __restrict__ x, const double* __restrict__ fold,
    const double* __restrict__ bfold, const int* __restrict__ wcount,
    const int* __restrict__ wlist, int* __restrict__ hq, int* __restrict__ hk)
{
    int n = *wcount;
    if (n > WLIST_CAP) n = WLIST_CAP;
    int lane = threadIdx.x & 63;
    int wid = (blockIdx.x * 256 + threadIdx.x) >> 6;
    int nw = gridDim.x * 4;
    for (int e = wid; e < n; e += nw) {
        int code = wlist[e];
        int task = code >> 14, grow = code & 16383;
        const double* f = fold + (size_t)task * 7168;
        const float* xp = x + (size_t)grow * 1024;
        double acc[7] = {0, 0, 0, 0, 0, 0, 0};
        for (int i = lane; i < 1024; i += 64) {
            double xv = (double)xp[i];
#pragma unroll
            for (int rr = 0; rr < 7; ++rr)
                acc[rr] = fma(xv, f[(size_t)i * 7 + rr], acc[rr]);
        }
        int id = 0;
#pragma unroll
        for (int rr = 0; rr < 7; ++rr) {
            double a = acc[rr];
#pragma unroll
            for (int off = 32; off > 0; off >>= 1) a += __shfl_xor(a, off, 64);
            if (a + bfold[task * 7 + rr] > 0.0) id |= (1 << rr);
        }
        if (lane == 0) {
            int hsh = id ^ (id >> 1);
            int w = task >> 4, h = task & 15;
            int b = grow >> 13, l = grow & 8191;
            (w ? hk : hq)[((size_t)(b * 16 + h) << 13) + l] = hsh;
        }
    }
}

// ---- stable counting sort (128 buckets) per (b,h); also emits rank (inverse) ----
__global__ __launch_bounds__(256) void sort_kernel(
    const int* __restrict__ hq, const int* __restrict__ hk,
    int* __restrict__ qidx, int* __restrict__ kidx,
    int* __restrict__ qrank, int* __restrict__ krank)
{
    __shared__ unsigned short cnt[128][128];
    __shared__ int tot[128];
    __shared__ int base[128];
    int blk = blockIdx.x;
    int sel = blk >> 5, bh = blk & 31;
    const int* hp = (sel ? hk : hq) + ((size_t)bh << 13);
    int* op = (sel ? kidx : qidx) + ((size_t)bh << 13);
    int* rp = (sel ? krank : qrank) + ((size_t)bh << 13);
    int t = threadIdx.x;
    for (int i = t; i < 128 * 128 / 2; i += 256) ((unsigned int*)cnt)[i] = 0u;
    __syncthreads();
    if (t < 128) {
        const int* p = hp + t * 64;
        for (int j = 0; j < 64; ++j) cnt[t][p[j]]++;
    }
    __syncthreads();
    if (t < 128) {
        int run = 0;
        for (int c = 0; c < 128; ++c) {
            int x2 = cnt[c][t];
            cnt[c][t] = (unsigned short)run;
            run += x2;
        }
        tot[t] = run;
    }
    __syncthreads();
    if (t == 0) {
        int run = 0;
        for (int v = 0; v < 128; ++v) { base[v] = run; run += tot[v]; }
    }
    __syncthreads();
    if (t < 128) {
        const int* p = hp + t * 64;
        for (int j = 0; j < 64; ++j) {
            int v = p[j];
            int c = cnt[t][v];
            cnt[t][v] = (unsigned short)(c + 1);
            int pos = base[v] + c;
            op[pos] = t * 64 + j;
            rp[t * 64 + j] = pos;
        }
    }
}

// ---- cast x fp32 -> f16 ----
__global__ __launch_bounds__(256) void castx_kernel(
    const float* __restrict__ x, _Float16* __restrict__ xh)
{
    int i = blockIdx.x * 256 + threadIdx.x;
    float4 f = ((const float4*)x)[i];
    _Float16 h4[4] = {(_Float16)f.x, (_Float16)f.y, (_Float16)f.z, (_Float16)f.w};
    *(short4*)&xh[(size_t)i * 4] = *(short4*)h4;
}

// ---- transpose+cast: W[K][N] fp32 -> Wt[N][K] f16 ----
__global__ __launch_bounds__(256) void transpose_kernel(
    const float* __restrict__ W, _Float16* __restrict__ Wt, int K, int N)
{
    __shared__ float tile[32][33];
    int bx = blockIdx.x, by = blockIdx.y;
    int tx = threadIdx.x & 31, ty = threadIdx.x >> 5;
    for (int i = ty; i < 32; i += 8)
        tile[i][tx] = W[(size_t)(by * 32 + i) * N + bx * 32 + tx];
    __syncthreads();
    for (int i = ty; i < 32; i += 8)
        Wt[(size_t)(bx * 32 + i) * K + by * 32 + tx] = (_Float16)tile[tx][i];
}

// ---- gather sampled K/V rows (sorted order) into dense per-bh buffers ----
__global__ __launch_bounds__(256) void gather_samp_kernel(
    const _Float16* __restrict__ ks, const _Float16* __restrict__ vs,
    const int* __restrict__ sampled, _Float16* __restrict__ ksamp,
    _Float16* __restrict__ vsamp)
{
    int bh = blockIdx.x;
    int key = blockIdx.y * 64 + (threadIdx.x >> 2);
    int qtr = (threadIdx.x & 3) * 16;
    size_t hb = (size_t)bh << 13;
    int p = sampled[bh * 256 + key];
    size_t src = (hb + p) * 64 + qtr;
    size_t dst = ((size_t)bh * 256 + key) * 64 + qtr;
    *(f16x8*)(ksamp + dst)     = *(const f16x8*)(ks + src);
    *(f16x8*)(ksamp + dst + 8) = *(const f16x8*)(ks + src + 8);
    *(f16x8*)(vsamp + dst)     = *(const f16x8*)(vs + src);
    *(f16x8*)(vsamp + dst + 8) = *(const f16x8*)(vs + src + 8);
}

// ======= BK=64 + XOR-swizzled LDS GEMM core (G4 fix, rule-21 both-sides) ====
// LDS tile [128 rows][64 f16] = 128 B/row. Linear-dest global_load_lds with
// PRE-SWIZZLED source col-slot: for all staging issues row&7 == l>>3, so lane
// l loads global 16B-slot (l&7)^(l>>3); reads XOR byte-col with (r&7)<<4.
// Result: 16 rl-lanes spread over all 8 slots -> ~2-way (free) vs 8-way before.

// ---- plain f16 MFMA GEMM: MODE 0 = +bias, MODE 2 = no bias ----
template <int MODE>
__global__ __launch_bounds__(256) void mfma_gemm(
    const _Float16* __restrict__ A, const _Float16* __restrict__ Bt,
    const float* __restrict__ bias, float* __restrict__ C, int K, int N)
{
    __shared__ __align__(16) _Float16 As[128 * 64];
    __shared__ __align__(16) _Float16 Bs[128 * 64];
    int t = threadIdx.x;
    int w = t >> 6, l = t & 63;
    int m0 = blockIdx.y * 128, n0 = blockIdx.x * 128;
    int srow = 32 * w + (l >> 3);                 // staging row (issue 0)
    int sslot = ((l & 7) ^ (l >> 3)) * 8;         // pre-swizzled col (f16 elems)
    const _Float16* ga = A + (size_t)(m0 + srow) * K + sslot;
    const _Float16* gb = Bt + (size_t)(n0 + srow) * K + sslot;
    int wr = w >> 1, wc = w & 1;
    int rl = l & 15, ks = l >> 4;
    f32x4 acc[4][4];
#pragma unroll
    for (int m = 0; m < 4; ++m)
#pragma unroll
        for (int n = 0; n < 4; ++n) acc[m][n] = (f32x4){0.f, 0.f, 0.f, 0.f};
    for (int kk = 0; kk < K; kk += 64) {
        __syncthreads();
#pragma unroll
        for (int i = 0; i < 4; ++i) {
            gl_lds16(ga + (size_t)(8 * i) * K + kk, (char*)As + (32 * w + 8 * i) * 128);
            gl_lds16(gb + (size_t)(8 * i) * K + kk, (char*)Bs + (32 * w + 8 * i) * 128);
        }
        __syncthreads();
        f16x8 af[4][2], bf[4][2];
#pragma unroll
        for (int m = 0; m < 4; ++m) {
            int r = 64 * wr + 16 * m + rl;
            int sw = (r & 7) << 4;
#pragma unroll
            for (int s = 0; s < 2; ++s)
                af[m][s] = *(const f16x8*)((char*)As + r * 128 + (((s * 4 + ks) << 4) ^ sw));
        }
#pragma unroll
        for (int n = 0; n < 4; ++n) {
            int r = 64 * wc + 16 * n + rl;
            int sw = (r & 7) << 4;
#pragma unroll
            for (int s = 0; s < 2; ++s)
                bf[n][s] = *(const f16x8*)((char*)Bs + r * 128 + (((s * 4 + ks) << 4) ^ sw));
        }
#pragma unroll
        for (int m = 0; m < 4; ++m)
#pragma unroll
            for (int n = 0; n < 4; ++n) {
                acc[m][n] = __builtin_amdgcn_mfma_f32_16x16x32_f16(
                    af[m][0], bf[n][0], acc[m][n], 0, 0, 0);
                acc[m][n] = __builtin_amdgcn_mfma_f32_16x16x32_f16(
                    af[m][1], bf[n][1], acc[m][n], 0, 0, 0);
            }
    }
#pragma unroll
    for (int m = 0; m < 4; ++m)
#pragma unroll
        for (int n = 0; n < 4; ++n) {
            int gn = n0 + 64 * wc + 16 * n + rl;
            float bv = (MODE == 2) ? 0.f : bias[gn];
#pragma unroll
            for (int j = 0; j < 4; ++j) {
                int gm = m0 + 64 * wr + 16 * m + 4 * ks + j;
                C[(size_t)gm * N + gn] = acc[m][n][j] + bv;
            }
        }
}

// ---- QKV GEMM, swapped operands (features x tokens), XCD-chunked,
// BK=64 + swizzle core, vectorized sorted-scatter epilogue ----
__global__ __launch_bounds__(256) void gemm_qkv_kernel(
    const _Float16* __restrict__ Wt, const _Float16* __restrict__ xh,
    const float* __restrict__ bias, _Float16* __restrict__ Q,
    _Float16* __restrict__ Kb, _Float16* __restrict__ Vb,
    const int* __restrict__ qrank, const int* __restrict__ krank)
{
    const int K = 1024;
    __shared__ __align__(16) _Float16 As[128 * 64];
    __shared__ __align__(16) _Float16 Bs[128 * 64];
    int bid = blockIdx.x;
    int xcd = bid & 7, slot = bid >> 3;
    int y = slot / 3, xl = slot - y * 3;
    int xt = xcd * 3 + xl;
    int m0 = xt * 128;                       // feature base
    int n0 = y * 128;                        // token base
    int t = threadIdx.x;
    int w = t >> 6, l = t & 63;
    int srow = 32 * w + (l >> 3);
    int sslot = ((l & 7) ^ (l >> 3)) * 8;
    const _Float16* ga = Wt + (size_t)(m0 + srow) * K + sslot;
    const _Float16* gb = xh + (size_t)(n0 + srow) * K + sslot;
    int wr = w >> 1, wc = w & 1;
    int rl = l & 15, ks = l >> 4;
    // epilogue metadata hoisted above K-loop
    int fbase = m0 + 64 * wr;
    int s0 = fbase >> 10;
    int h = (fbase >> 6) & 15;
    int b2 = n0 >> 13;
    const int* rk = (s0 == 0) ? qrank : krank;
    _Float16* dst = (s0 == 0) ? Q : (s0 == 1 ? Kb : Vb);
    size_t bhb = ((size_t)(b2 * 16 + h) << 13);
    int tl = (n0 & 8191) + 64 * wc;
    int pos[4];
#pragma unroll
    for (int n = 0; n < 4; ++n)
        pos[n] = rk[bhb + tl + 16 * n + rl];
    float4 bias4[4];
#pragma unroll
    for (int m = 0; m < 4; ++m)
        bias4[m] = *(const float4*)&bias[fbase + 16 * m + 4 * ks];
    f32x4 acc[4][4];
#pragma unroll
    for (int m = 0; m < 4; ++m)
#pragma unroll
        for (int n = 0; n < 4; ++n) acc[m][n] = (f32x4){0.f, 0.f, 0.f, 0.f};
    for (int kk = 0; kk < K; kk += 64) {
        __syncthreads();
#pragma unroll
        for (int i = 0; i < 4; ++i) {
            gl_lds16(ga + (size_t)(8 * i) * K + kk, (char*)As + (32 * w + 8 * i) * 128);
            gl_lds16(gb + (size_t)(8 * i) * K + kk, (char*)Bs + (32 * w + 8 * i) * 128);
        }
        __syncthreads();
        f16x8 af[4][2], bf[4][2];
#pragma unroll
        for (int m = 0; m < 4; ++m) {
            int r = 64 * wr + 16 * m + rl;
            int sw = (r & 7) << 4;
#pragma unroll
            for (int s = 0; s < 2; ++s)
                af[m][s] = *(const f16x8*)((char*)As + r * 128 + (((s * 4 + ks) << 4) ^ sw));
        }
#pragma unroll
        for (int n = 0; n < 4; ++n) {
            int r = 64 * wc + 16 * n + rl;
            int sw = (r & 7) << 4;
#pragma unroll
            for (int s = 0; s < 2; ++s)
                bf[n][s] = *(const f16x8*)((char*)Bs + r * 128 + (((s * 4 + ks) << 4) ^ sw));
        }
#pragma unroll
        for (int m = 0; m < 4; ++m)
#pragma unroll
            for (int n = 0; n < 4; ++n) {
                acc[m][n] = __builtin_amdgcn_mfma_f32_16x16x32_f16(
                    af[m][0], bf[n][0], acc[m][n], 0, 0, 0);
                acc[m][n] = __builtin_amdgcn_mfma_f32_16x16x32_f16(
                    af[m][1], bf[n][1], acc[m][n], 0, 0, 0);
            }
    }
#pragma unroll
    for (int m = 0; m < 4; ++m)
#pragma unroll
        for (int n = 0; n < 4; ++n) {
            f16x4 st;
            st[0] = (_Float16)(acc[m][n][0] + bias4[m].x);
            st[1] = (_Float16)(acc[m][n][1] + bias4[m].y);
            st[2] = (_Float16)(acc[m][n][2] + bias4[m].z);
            st[3] = (_Float16)(acc[m][n][3] + bias4[m].w);
            *(f16x4*)(dst + (bhb + pos[n]) * 64 + 16 * m + 4 * ks) = st;
        }
}

// ---- MFMA fused attention; coalesced K/V; XCD-chunked grid (4 bh per XCD) ----
__global__ __launch_bounds__(256) void attn_mfma_kernel(
    const _Float16* __restrict__ qs_, const _Float16* __restrict__ ks_,
    const _Float16* __restrict__ vs_, const _Float16* __restrict__ ksamp,
    const _Float16* __restrict__ vsamp, const int* __restrict__ qidx,
    const int* __restrict__ sampled, _Float16* __restrict__ pre)
{
    __shared__ __align__(16) _Float16 Vt[2][64 * 68];  // [buf][d*68 + key]
    int bid = blockIdx.x;
    int nb = (bid & 7) * 256 + (bid >> 3);   // XCD-chunked remap (2048%8==0)
    int bh = nb >> 6, qb = (nb >> 1) & 31, half = nb & 1;
    int bb = bh >> 4, hh = bh & 15;
    size_t hb = (size_t)bh << 13;
    size_t bhs = (size_t)bh * 256;
    int t = threadIdx.x;
    int w = t >> 6, l = t & 63;
    int g = l >> 4, c16 = l & 15;
    int kg = t & 15, dg = t >> 4;
    int qw0 = qb * 256 + half * 128 + w * 32;
    const _Float16 qs = (_Float16)0.125f;

    int orig[2];
    f16x8 qf[2][2];
#pragma unroll
    for (int n = 0; n < 2; ++n) {
        int row = qw0 + 16 * n + c16;
        orig[n] = qidx[hb + row];
        const _Float16* qp = qs_ + (hb + row) * 64 + g * 8;
        qf[n][0] = *(const f16x8*)(qp);
        qf[n][1] = *(const f16x8*)(qp + 32);
#pragma unroll
        for (int j = 0; j < 8; ++j) { qf[n][0][j] *= qs; qf[n][1][j] *= qs; }
    }
    f32x4 o[4][2];
    float mr[2], lr[2];
#pragma unroll
    for (int n = 0; n < 2; ++n) {
        mr[n] = -1e30f; lr[n] = 0.f;
#pragma unroll
        for (int d2 = 0; d2 < 4; ++d2) o[d2][n] = (f32x4){0.f, 0.f, 0.f, 0.f};
    }
    const float LOG32 = 3.4657359027997265f;

    {
        const _Float16* vb = vs_ + (hb + qb * 256) * 64;
        f16x4 vr[4];
#pragma unroll
        for (int j2 = 0; j2 < 4; ++j2)
            vr[j2] = *(const f16x4*)(vb + (4 * kg + j2) * 64 + 4 * dg);
#pragma unroll
        for (int i = 0; i < 4; ++i) {
            f16x4 o4 = {vr[0][i], vr[1][i], vr[2][i], vr[3][i]};
            *(f16x4*)&Vt[0][(4 * dg + i) * 68 + 4 * kg] = o4;
        }
    }

    for (int c = 0; c < 8; ++c) {
        int cur = c & 1, nxt = cur ^ 1;
        bool samp = c >= 4;
        __syncthreads();
        const _Float16* kb = samp ? ksamp + (bhs + (size_t)(c - 4) * 64) * 64
                                  : ks_ + (hb + qb * 256 + (size_t)c * 64) * 64;
        f16x8 kf[4][2];
#pragma unroll
        for (int m = 0; m < 4; ++m) {
            const _Float16* kp = kb + (16 * m + c16) * 64 + g * 8;
            kf[m][0] = *(const f16x8*)(kp);
            kf[m][1] = *(const f16x8*)(kp + 32);
        }
        int4 spv[4];
        if (samp) {
#pragma unroll
            for (int m = 0; m < 4; ++m)
                spv[m] = *(const int4*)(sampled + bhs + (c - 4) * 64 + 16 * m + 4 * g);
        }
        f32x4 sacc[4][2];
#pragma unroll
        for (int m = 0; m < 4; ++m)
#pragma unroll
            for (int n = 0; n < 2; ++n) sacc[m][n] = (f32x4){0.f, 0.f, 0.f, 0.f};
#pragma unroll
        for (int m = 0; m < 4; ++m) {
#pragma unroll
            for (int n = 0; n < 2; ++n)
                sacc[m][n] = __builtin_amdgcn_mfma_f32_16x16x32_f16(
                    kf[m][0], qf[n][0], sacc[m][n], 0, 0, 0);
#pragma unroll
            for (int n = 0; n < 2; ++n)
                sacc[m][n] = __builtin_amdgcn_mfma_f32_16x16x32_f16(
                    kf[m][1], qf[n][1], sacc[m][n], 0, 0, 0);
        }
        f16x4 vrn[4];
        if (c < 7) {
            const _Float16* vb = (c + 1 >= 4)
                ? vsamp + (bhs + (size_t)(c - 3) * 64) * 64
                : vs_ + (hb + qb * 256 + (size_t)(c + 1) * 64) * 64;
#pragma unroll
            for (int j2 = 0; j2 < 4; ++j2)
                vrn[j2] = *(const f16x4*)(vb + (4 * kg + j2) * 64 + 4 * dg);
        }
        f16x4 av[4][4];
#pragma unroll
        for (int m = 0; m < 4; ++m)
#pragma unroll
            for (int d2 = 0; d2 < 4; ++d2)
                av[m][d2] = *(const f16x4*)&Vt[cur][(16 * d2 + c16) * 68 + 16 * m + 4 * g];
        bool msk[4][4];
#pragma unroll
        for (int m = 0; m < 4; ++m) {
            msk[m][0] = samp && ((spv[m].x >> 8) == qb);
            msk[m][1] = samp && ((spv[m].y >> 8) == qb);
            msk[m][2] = samp && ((spv[m].z >> 8) == qb);
            msk[m][3] = samp && ((spv[m].w >> 8) == qb);
        }
        float badd = samp ? LOG32 : 0.f;
#pragma unroll
        for (int n = 0; n < 2; ++n) {
            float sv[16];
#pragma unroll
            for (int m = 0; m < 4; ++m)
#pragma unroll
                for (int r = 0; r < 4; ++r)
                    sv[4 * m + r] = msk[m][r] ? -1e30f : sacc[m][n][r] + badd;
            float a0 = fmaxf(fmaxf(sv[0], sv[1]), sv[2]);
            float a1 = fmaxf(fmaxf(sv[3], sv[4]), sv[5]);
            float a2 = fmaxf(fmaxf(sv[6], sv[7]), sv[8]);
            float a3 = fmaxf(fmaxf(sv[9], sv[10]), sv[11]);
            float a4 = fmaxf(fmaxf(sv[12], sv[13]), sv[14]);
            float cm = fmaxf(fmaxf(fmaxf(a0, a1), a2), fmaxf(fmaxf(a3, a4), sv[15]));
            cm = fmaxf(cm, __shfl_xor(cm, 16, 64));
            cm = fmaxf(cm, __shfl_xor(cm, 32, 64));
            if (__any(cm > mr[n])) {
                float nm = fmaxf(mr[n], cm);
                float fq = __expf(mr[n] - nm);
                mr[n] = nm;
                lr[n] *= fq;
#pragma unroll
                for (int d2 = 0; d2 < 4; ++d2) {
                    o[d2][n][0] *= fq; o[d2][n][1] *= fq;
                    o[d2][n][2] *= fq; o[d2][n][3] *= fq;
                }
            }
            float pv16[16];
#pragma unroll
            for (int r = 0; r < 16; ++r) pv16[r] = __expf(sv[r] - mr[n]);
            float s0 = (pv16[0] + pv16[1]) + (pv16[2] + pv16[3]);
            float s1 = (pv16[4] + pv16[5]) + (pv16[6] + pv16[7]);
            float s2 = (pv16[8] + pv16[9]) + (pv16[10] + pv16[11]);
            float s3 = (pv16[12] + pv16[13]) + (pv16[14] + pv16[15]);
            float ps = (s0 + s1) + (s2 + s3);
            ps += __shfl_xor(ps, 16, 64);
            ps += __shfl_xor(ps, 32, 64);
            lr[n] += ps;
            f16x4 pb[4];
#pragma unroll
            for (int m = 0; m < 4; ++m) {
                fp16x2 c0 = __builtin_amdgcn_cvt_pkrtz(pv16[4 * m + 0], pv16[4 * m + 1]);
                fp16x2 c1 = __builtin_amdgcn_cvt_pkrtz(pv16[4 * m + 2], pv16[4 * m + 3]);
                pb[m][0] = (_Float16)c0[0]; pb[m][1] = (_Float16)c0[1];
                pb[m][2] = (_Float16)c1[0]; pb[m][3] = (_Float16)c1[1];
            }
#pragma unroll
            for (int d2 = 0; d2 < 4; ++d2)
#pragma unroll
                for (int m = 0; m < 4; ++m)
                    o[d2][n] = __builtin_amdgcn_mfma_f32_16x16x16f16(
                        av[m][d2], pb[m], o[d2][n], 0, 0, 0);
        }
        if (c < 7) {
#pragma unroll
            for (int i = 0; i < 4; ++i) {
                f16x4 o4 = {vrn[0][i], vrn[1][i], vrn[2][i], vrn[3][i]};
                *(f16x4*)&Vt[nxt][(4 * dg + i) * 68 + 4 * kg] = o4;
            }
        }
    }
#pragma unroll
    for (int n = 0; n < 2; ++n) {
        float invl = 1.f / lr[n];
        _Float16* pp = pre + ((size_t)(bb * 8192 + orig[n])) * 1024 + hh * 64;
#pragma unroll
        for (int d2 = 0; d2 < 4; ++d2) {
            f16x4 st;
            st[0] = (_Float16)(o[d2][n][0] * invl);
            st[1] = (_Float16)(o[d2][n][1] * invl);
            st[2] = (_Float16)(o[d2][n][2] * invl);
            st[3] = (_Float16)(o[d2][n][3] * invl);
            *(f16x4*)(pp + 16 * d2 + 4 * g) = st;
        }
    }
}

extern "C" void kernel_launch(void* const* d_in, const int* in_sizes, int n_in,
                              void* d_out, int out_size, void* d_ws, size_t ws_size,
                              hipStream_t stream)
{
    (void)in_sizes; (void)n_in; (void)out_size; (void)ws_size;
    const float* x     = (const float*)d_in[0];
    const float* Wqkv  = (const float*)d_in[1];
    const float* bqkv  = (const float*)d_in[2];
    const float* Wproj = (const float*)d_in[3];
    const float* bproj = (const float*)d_in[4];
    const float* proj  = (const float*)d_in[5];
    const int*   samp  = (const int*)d_in[6];
    float* out = (float*)d_out;

    char* ws = (char*)d_ws;
    size_t off = 0;
    auto take = [&](size_t bytes) {
        char* p = ws + off;
        off = (off + bytes + 255) & ~(size_t)255;
        return p;
    };
    _Float16* xh  = (_Float16*)take(33554432);   // x f16; reused as `pre`
    _Float16* q   = (_Float16*)take(33554432);   // [B,H,L,64] f16, SORTED rows
    _Float16* k   = (_Float16*)take(33554432);
    _Float16* v   = (_Float16*)take(33554432);
    float* scores = (float*)take(16777216);
    _Float16* Wtq = (_Float16*)take(6291456);
    _Float16* Wtp = (_Float16*)take(2097152);
    _Float16* foldh = (_Float16*)take(524288);
    _Float16* ksamp = (_Float16*)take(1048576);  // [32][256][64] f16
    _Float16* vsamp = (_Float16*)take(1048576);
    double* fold   = (double*)take(1835008);
    double* bfold  = (double*)take(1792);
    float* bfold32 = (float*)take(896);
    int* wcount = (int*)take(256);
    int* wlist  = (int*)take(WLIST_CAP * 4);
    int* hq    = (int*)take(1048576);
    int* hk    = (int*)take(1048576);
    int* qidx  = (int*)take(1048576);
    int* kidx  = (int*)take(1048576);
    int* qrank = (int*)take(1048576);
    int* krank = (int*)take(1048576);
    _Float16* pre = xh;   // alias: xh dead after gemm_qkv
    // total ~170 MB

    (void)hipMemsetAsync(wcount, 0, 4, stream);
    castx_kernel<<<dim3(16384), dim3(256), 0, stream>>>(x, xh);
    fold_kernel<<<dim3(896), dim3(256), 0, stream>>>(
        Wqkv, bqkv, proj, fold, bfold, foldh, bfold32);
    mfma_gemm<2><<<dim3(2, 128), dim3(256), 0, stream>>>(
        xh, foldh, nullptr, scores, 1024, 256);
    hashext_kernel<<<dim3(2048), dim3(256), 0, stream>>>(
        scores, bfold32, hq, hk, wcount, wlist);
    refine_kernel<<<dim3(2048), dim3(256), 0, stream>>>(
        x, fold, bfold, wcount, wlist, hq, hk);
    sort_kernel<<<dim3(64), dim3(256), 0, stream>>>(
        hq, hk, qidx, kidx, qrank, krank);
    transpose_kernel<<<dim3(96, 32), dim3(256), 0, stream>>>(Wqkv, Wtq, 1024, 3072);
    transpose_kernel<<<dim3(32, 32), dim3(256), 0, stream>>>(Wproj, Wtp, 1024, 1024);
    gemm_qkv_kernel<<<dim3(3072), dim3(256), 0, stream>>>(
        Wtq, xh, bqkv, q, k, v, qrank, krank);
    gather_samp_kernel<<<dim3(32, 4), dim3(256), 0, stream>>>(
        k, v, samp, ksamp, vsamp);
    attn_mfma_kernel<<<dim3(2048), dim3(256), 0, stream>>>(
        q, k, v, ksamp, vsamp, qidx, samp, pre);
    mfma_gemm<0><<<dim3(8, 128), dim3(256), 0, stream>>>(
        pre, Wtp, bproj, out, 1024, 1024);
}

// Round 17
// 550.642 us; speedup vs baseline: 1.1015x; 1.0191x over previous
//
#include <hip/hip_runtime.h>
#include <hip/hip_fp16.h>
#include <math.h>

// Shapes (fixed): B=2, H=16, L=8192, dh=64, D=1024, 3*INNER=3072, NPROJ=7,
// BLOCK=256, SAMPLE=256.

typedef _Float16 f16x8 __attribute__((ext_vector_type(8)));
typedef _Float16 f16x4 __attribute__((ext_vector_type(4)));
typedef __fp16 fp16x2 __attribute__((ext_vector_type(2)));   // cvt_pkrtz native type
typedef float f32x4 __attribute__((ext_vector_type(4)));

#define WLIST_CAP 524288
#define TAU 0.06f

__device__ __forceinline__ void gl_lds16(const void* g, void* s) {
    __builtin_amdgcn_global_load_lds(
        (const __attribute__((address_space(1))) unsigned int*)g,
        (__attribute__((address_space(3))) unsigned int*)s, 16, 0, 0);
}

// ---- fold (fp64 exact) + f16 fold matrix for the MFMA hash pass ----
__global__ __launch_bounds__(256) void fold_kernel(
    const float* __restrict__ W, const float* __restrict__ bias,
    const float* __restrict__ proj, double* __restrict__ fold,
    double* __restrict__ bfold, _Float16* __restrict__ foldh,
    float* __restrict__ bfold32)
{
    int idx = blockIdx.x * 256 + threadIdx.x;
    if (idx < 2 * 16 * 7 * 1024) {
        int task = idx / 7168;
        int rem = idx - task * 7168;
        int i = rem / 7;
        int r = rem - i * 7;
        int h = task & 15, w = task >> 4;
        double s = 0.0;
        const float* wp = W + (size_t)i * 3072 + w * 1024 + h * 64;
        for (int d = 0; d < 64; ++d)
            s += (double)wp[d] * (double)proj[d * 7 + r];
        fold[idx] = s;
        foldh[((size_t)task * 7 + r) * 1024 + i] = (_Float16)s;
    }
    if (idx < 32768)    // zero-pad foldh rows 224..255
        foldh[229376 + idx] = (_Float16)0.f;
    if (idx < 224) {
        int r = idx % 7;
        int task = idx / 7;
        int h = task & 15, w = task >> 4;
        double s = 0.0;
        for (int d = 0; d < 64; ++d)
            s += (double)bias[w * 1024 + h * 64 + d] * (double)proj[d * 7 + r];
        bfold[idx] = s;
        bfold32[idx] = (float)s;
    }
}

// ---- hash extract: scores + bias -> gray hash; flag |val|<TAU ----
__global__ __launch_bounds__(256) void hashext_kernel(
    const float* __restrict__ scores, const float* __restrict__ bfold32,
    int* __restrict__ hq, int* __restrict__ hk,
    int* __restrict__ wcount, int* __restrict__ wlist)
{
    int tid = blockIdx.x * 256 + threadIdx.x;
    int row = tid >> 5, task = tid & 31;
    const float* sp = scores + (size_t)row * 256 + task * 7;
    int id = 0, fl = 0;
#pragma unroll
    for (int r = 0; r < 7; ++r) {
        float val = sp[r] + bfold32[task * 7 + r];
        if (fabsf(val) < TAU) fl = 1;
        if (val > 0.f) id |= (1 << r);
    }
    int hsh = id ^ (id >> 1);
    int w = task >> 4, h = task & 15;
    int b = row >> 13, l = row & 8191;
    (w ? hk : hq)[((size_t)(b * 16 + h) << 13) + l] = hsh;
    if (fl) {
        int slot = atomicAdd(wcount, 1);
        if (slot < WLIST_CAP) wlist[slot] = task * 16384 + row;
    }
}

// ---- refine: one WAVE per flagged (task,row); lane-parallel exact fp64 dot ----
__global__ __launch_bounds__(256) void refine_kernel(
    const float* __restrict__ x, const double* __restrict__ fold,
    const double* __restrict__ bfold, const int* __restrict__ wcount,
    const int* __restrict__ wlist, int* __restrict__ hq, int* __restrict__ hk)
{
    int n = *wcount;
    if (n > WLIST_CAP) n = WLIST_CAP;
    int lane = threadIdx.x & 63;
    int wid = (blockIdx.x * 256 + threadIdx.x) >> 6;
    int nw = gridDim.x * 4;
    for (int e = wid; e < n; e += nw) {
        int code = wlist[e];
        int task = code >> 14, grow = code & 16383;
        const double* f = fold + (size_t)task * 7168;
        const float* xp = x + (size_t)grow * 1024;
        double acc[7] = {0, 0, 0, 0, 0, 0, 0};
        for (int i = lane; i < 1024; i += 64) {
            double xv = (double)xp[i];
#pragma unroll
            for (int rr = 0; rr < 7; ++rr)
                acc[rr] = fma(xv, f[(size_t)i * 7 + rr], acc[rr]);
        }
        int id = 0;
#pragma unroll
        for (int rr = 0; rr < 7; ++rr) {
            double a = acc[rr];
#pragma unroll
            for (int off = 32; off > 0; off >>= 1) a += __shfl_xor(a, off, 64);
            if (a + bfold[task * 7 + rr] > 0.0) id |= (1 << rr);
        }
        if (lane == 0) {
            int hsh = id ^ (id >> 1);
            int w = task >> 4, h = task & 15;
            int b = grow >> 13, l = grow & 8191;
            (w ? hk : hq)[((size_t)(b * 16 + h) << 13) + l] = hsh;
        }
    }
}

// ---- stable counting sort (128 buckets) per (b,h); also emits rank (inverse) ----
__global__ __launch_bounds__(256) void sort_kernel(
    const int* __restrict__ hq, const int* __restrict__ hk,
    int* __restrict__ qidx, int* __restrict__ kidx,
    int* __restrict__ qrank, int* __restrict__ krank)
{
    __shared__ unsigned short cnt[128][128];
    __shared__ int tot[128];
    __shared__ int base[128];
    int blk = blockIdx.x;
    int sel = blk >> 5, bh = blk & 31;
    const int* hp = (sel ? hk : hq) + ((size_t)bh << 13);
    int* op = (sel ? kidx : qidx) + ((size_t)bh << 13);
    int* rp = (sel ? krank : qrank) + ((size_t)bh << 13);
    int t = threadIdx.x;
    for (int i = t; i < 128 * 128 / 2; i += 256) ((unsigned int*)cnt)[i] = 0u;
    __syncthreads();
    if (t < 128) {
        const int* p = hp + t * 64;
        for (int j = 0; j < 64; ++j) cnt[t][p[j]]++;
    }
    __syncthreads();
    if (t < 128) {
        int run = 0;
        for (int c = 0; c < 128; ++c) {
            int x2 = cnt[c][t];
            cnt[c][t] = (unsigned short)run;
            run += x2;
        }
        tot[t] = run;
    }
    __syncthreads();
    if (t == 0) {
        int run = 0;
        for (int v = 0; v < 128; ++v) { base[v] = run; run += tot[v]; }
    }
    __syncthreads();
    if (t < 128) {
        const int* p = hp + t * 64;
        for (int j = 0; j < 64; ++j) {
            int v = p[j];
            int c = cnt[t][v];
            cnt[t][v] = (unsigned short)(c + 1);
            int pos = base[v] + c;
            op[pos] = t * 64 + j;
            rp[t * 64 + j] = pos;
        }
    }
}

// ---- cast x fp32 -> f16 ----
__global__ __launch_bounds__(256) void castx_kernel(
    const float* __restrict__ x, _Float16* __restrict__ xh)
{
    int i = blockIdx.x * 256 + threadIdx.x;
    float4 f = ((const float4*)x)[i];
    _Float16 h4[4] = {(_Float16)f.x, (_Float16)f.y, (_Float16)f.z, (_Float16)f.w};
    *(short4*)&xh[(size_t)i * 4] = *(short4*)h4;
}

// ---- transpose+cast: W[K][N] fp32 -> Wt[N][K] f16 ----
__global__ __launch_bounds__(256) void transpose_kernel(
    const float* __restrict__ W, _Float16* __restrict__ Wt, int K, int N)
{
    __shared__ float tile[32][33];
    int bx = blockIdx.x, by = blockIdx.y;
    int tx = threadIdx.x & 31, ty = threadIdx.x >> 5;
    for (int i = ty; i < 32; i += 8)
        tile[i][tx] = W[(size_t)(by * 32 + i) * N + bx * 32 + tx];
    __syncthreads();
    for (int i = ty; i < 32; i += 8)
        Wt[(size_t)(bx * 32 + i) * K + by * 32 + tx] = (_Float16)tile[tx][i];
}

// ---- gather sampled K/V rows (sorted order) into dense per-bh buffers ----
__global__ __launch_bounds__(256) void gather_samp_kernel(
    const _Float16* __restrict__ ks, const _Float16* __restrict__ vs,
    const int* __restrict__ sampled, _Float16* __restrict__ ksamp,
    _Float16* __restrict__ vsamp)
{
    int bh = blockIdx.x;
    int key = blockIdx.y * 64 + (threadIdx.x >> 2);
    int qtr = (threadIdx.x & 3) * 16;
    size_t hb = (size_t)bh << 13;
    int p = sampled[bh * 256 + key];
    size_t src = (hb + p) * 64 + qtr;
    size_t dst = ((size_t)bh * 256 + key) * 64 + qtr;
    *(f16x8*)(ksamp + dst)     = *(const f16x8*)(ks + src);
    *(f16x8*)(ksamp + dst + 8) = *(const f16x8*)(ks + src + 8);
    *(f16x8*)(vsamp + dst)     = *(const f16x8*)(vs + src);
    *(f16x8*)(vsamp + dst + 8) = *(const f16x8*)(vs + src + 8);
}

// ---- plain f16 MFMA GEMM, BK=64 + XOR swizzle (R16): MODE 0=+bias, 2=no bias ----
template <int MODE>
__global__ __launch_bounds__(256) void mfma_gemm(
    const _Float16* __restrict__ A, const _Float16* __restrict__ Bt,
    const float* __restrict__ bias, float* __restrict__ C, int K, int N)
{
    __shared__ __align__(16) _Float16 As[128 * 64];
    __shared__ __align__(16) _Float16 Bs[128 * 64];
    int t = threadIdx.x;
    int w = t >> 6, l = t & 63;
    int m0 = blockIdx.y * 128, n0 = blockIdx.x * 128;
    int srow = 32 * w + (l >> 3);
    int sslot = ((l & 7) ^ (l >> 3)) * 8;
    const _Float16* ga = A + (size_t)(m0 + srow) * K + sslot;
    const _Float16* gb = Bt + (size_t)(n0 + srow) * K + sslot;
    int wr = w >> 1, wc = w & 1;
    int rl = l & 15, ks = l >> 4;
    f32x4 acc[4][4];
#pragma unroll
    for (int m = 0; m < 4; ++m)
#pragma unroll
        for (int n = 0; n < 4; ++n) acc[m][n] = (f32x4){0.f, 0.f, 0.f, 0.f};
    for (int kk = 0; kk < K; kk += 64) {
        __syncthreads();
#pragma unroll
        for (int i = 0; i < 4; ++i) {
            gl_lds16(ga + (size_t)(8 * i) * K + kk, (char*)As + (32 * w + 8 * i) * 128);
            gl_lds16(gb + (size_t)(8 * i) * K + kk, (char*)Bs + (32 * w + 8 * i) * 128);
        }
        __syncthreads();
        f16x8 af[4][2], bf[4][2];
#pragma unroll
        for (int m = 0; m < 4; ++m) {
            int r = 64 * wr + 16 * m + rl;
            int sw = (r & 7) << 4;
#pragma unroll
            for (int s = 0; s < 2; ++s)
                af[m][s] = *(const f16x8*)((char*)As + r * 128 + (((s * 4 + ks) << 4) ^ sw));
        }
#pragma unroll
        for (int n = 0; n < 4; ++n) {
            int r = 64 * wc + 16 * n + rl;
            int sw = (r & 7) << 4;
#pragma unroll
            for (int s = 0; s < 2; ++s)
                bf[n][s] = *(const f16x8*)((char*)Bs + r * 128 + (((s * 4 + ks) << 4) ^ sw));
        }
#pragma unroll
        for (int m = 0; m < 4; ++m)
#pragma unroll
            for (int n = 0; n < 4; ++n) {
                acc[m][n] = __builtin_amdgcn_mfma_f32_16x16x32_f16(
                    af[m][0], bf[n][0], acc[m][n], 0, 0, 0);
                acc[m][n] = __builtin_amdgcn_mfma_f32_16x16x32_f16(
                    af[m][1], bf[n][1], acc[m][n], 0, 0, 0);
            }
    }
#pragma unroll
    for (int m = 0; m < 4; ++m)
#pragma unroll
        for (int n = 0; n < 4; ++n) {
            int gn = n0 + 64 * wc + 16 * n + rl;
            float bv = (MODE == 2) ? 0.f : bias[gn];
#pragma unroll
            for (int j = 0; j < 4; ++j) {
                int gm = m0 + 64 * wr + 16 * m + 4 * ks + j;
                C[(size_t)gm * N + gn] = acc[m][n][j] + bv;
            }
        }
}

// ---- QKV GEMM: 256x256 tile, BK=64, 8 waves, double-buffered deep pipeline
// (T3/T4): per K-tile 4 phases, counted vmcnt(4) at tile top (vmcnt(0) only at
// the last tile), 2 barriers/tile. Stage schedule (tile t):
//   ph1: stage A-half0(t+1)->otherbuf   ph2: stage A-half1(t+1)->otherbuf
//   [barrier]  ph3: stage B-half0(t+2)->curbuf  ph4: stage B-half1(t+2)->curbuf
// Race audit: A-stages hit the buffer whose readers all finished before this
// tile's top barrier; B-stages hit current-buf B-region only after the mid
// barrier that follows every wave's B-reads (ph1). vmcnt(4) leaves exactly the
// 4 newest loads (next tile's B halves) in flight -> FIFO ensures current tile
// landed. LDS 128 KB dynamic; R16-proven XOR swizzle (preswizzled source).
__global__ __launch_bounds__(512) void gemm_qkv_kernel(
    const _Float16* __restrict__ Wt, const _Float16* __restrict__ xh,
    const float* __restrict__ bias, _Float16* __restrict__ Q,
    _Float16* __restrict__ Kb, _Float16* __restrict__ Vb,
    const int* __restrict__ qrank, const int* __restrict__ krank)
{
    extern __shared__ __align__(16) char smem[];   // [buf][A 32K | B 32K] = 128 KB
    const int K = 1024;
    int bid = blockIdx.x;                 // 768 = 8 xcd x (8 token-groups x 12 feat)
    int xcd = bid & 7, slot = bid >> 3;
    int ty = slot / 12, tx = slot - ty * 12;
    int m0 = tx * 256;                    // feature base
    int n0 = (xcd * 8 + ty) * 256;        // token base
    int t = threadIdx.x;                  // 0..511
    int w = t >> 6, l = t & 63;
    int wr = w >> 2, wc = w & 3;          // 2 x 4 wave grid
    int rl = l & 15, ks = l >> 4;
    int srow = t >> 3;                    // 0..63
    int sslot = (t & 7) ^ ((t >> 3) & 7); // pre-swizzled 16B slot
    const _Float16* gA = Wt + (size_t)m0 * K + sslot * 8;
    const _Float16* gB = xh + (size_t)n0 * K + sslot * 8;
    char* dstT = smem + t * 16;

    auto STAGE = [&](int buf, int op, int half, int kt) {
        const _Float16* src = op ? gB : gA;
        char* d = dstT + buf * 65536 + op * 32768 + half * 16384;
        size_t ro = (size_t)(half * 128 + srow) * K + kt * 64;
        gl_lds16(src + ro, d);
        gl_lds16(src + ro + (size_t)64 * K, d + 8192);
    };

    // epilogue metadata (hoisted)
    int fbase = m0 + 128 * wr;
    int s0 = fbase >> 10;                 // 0=q,1=k,2=v (uniform per wave)
    int h0 = (fbase >> 6) & 15;           // head of m<4 half; m>=4 -> h0+1
    int b2 = n0 >> 13;
    const int* rk = (s0 == 0) ? qrank : krank;
    _Float16* dq = (s0 == 0) ? Q : (s0 == 1 ? Kb : Vb);
    int tl = (n0 & 8191) + 64 * wc;
    int pos[2][4];
#pragma unroll
    for (int hf = 0; hf < 2; ++hf)
#pragma unroll
        for (int n = 0; n < 4; ++n)
            pos[hf][n] = rk[((size_t)(b2 * 16 + h0 + hf) << 13) + tl + 16 * n + rl];
    float4 bias4[8];
#pragma unroll
    for (int m = 0; m < 8; ++m)
        bias4[m] = *(const float4*)&bias[fbase + 16 * m + 4 * ks];

    f32x4 acc[8][4];
#pragma unroll
    for (int m = 0; m < 8; ++m)
#pragma unroll
        for (int n = 0; n < 4; ++n) acc[m][n] = (f32x4){0.f, 0.f, 0.f, 0.f};

    // prologue: tile0 complete, tile1 B halves
    STAGE(0, 0, 0, 0); STAGE(0, 0, 1, 0); STAGE(0, 1, 0, 0); STAGE(0, 1, 1, 0);
    STAGE(1, 1, 0, 1); STAGE(1, 1, 1, 1);

    for (int tt = 0; tt < 16; ++tt) {
        int buf = tt & 1, obuf = buf ^ 1;
        // ---- tile top: counted wait + publish barrier ----
        if (tt < 15) asm volatile("s_waitcnt vmcnt(4)" ::: "memory");
        else         asm volatile("s_waitcnt vmcnt(0)" ::: "memory");
        __builtin_amdgcn_sched_barrier(0);
        __builtin_amdgcn_s_barrier();
        __builtin_amdgcn_sched_barrier(0);
        const char* Ab = smem + buf * 65536;
        const char* Bb = Ab + 32768;
        // ---- ph1: read bf (all n) + af[0..1]; stage A0(tt+1); MFMA m=0,1 ----
        f16x8 bf[4][2], af01[2][2];
#pragma unroll
        for (int n = 0; n < 4; ++n) {
            int r = 64 * wc + 16 * n + rl;
            int sw = (r & 7) << 4;
            bf[n][0] = *(const f16x8*)(Bb + r * 128 + ((ks << 4) ^ sw));
            bf[n][1] = *(const f16x8*)(Bb + r * 128 + (((4 + ks) << 4) ^ sw));
        }
#pragma unroll
        for (int m = 0; m < 2; ++m) {
            int r = 128 * wr + 16 * m + rl;
            int sw = (r & 7) << 4;
            af01[m][0] = *(const f16x8*)(Ab + r * 128 + ((ks << 4) ^ sw));
            af01[m][1] = *(const f16x8*)(Ab + r * 128 + (((4 + ks) << 4) ^ sw));
        }
        if (tt + 1 < 16) STAGE(obuf, 0, 0, tt + 1);
        __builtin_amdgcn_s_setprio(1);
#pragma unroll
        for (int m = 0; m < 2; ++m)
#pragma unroll
            for (int n = 0; n < 4; ++n) {
                acc[m][n] = __builtin_amdgcn_mfma_f32_16x16x32_f16(
                    af01[m][0], bf[n][0], acc[m][n], 0, 0, 0);
                acc[m][n] = __builtin_amdgcn_mfma_f32_16x16x32_f16(
                    af01[m][1], bf[n][1], acc[m][n], 0, 0, 0);
            }
        __builtin_amdgcn_s_setprio(0);
        // ---- ph2: read af[2..7]; stage A1(tt+1); MFMA m=2,3 ----
        f16x8 af27[6][2];
#pragma unroll
        for (int m = 0; m < 6; ++m) {
            int r = 128 * wr + 16 * (m + 2) + rl;
            int sw = (r & 7) << 4;
            af27[m][0] = *(const f16x8*)(Ab + r * 128 + ((ks << 4) ^ sw));
            af27[m][1] = *(const f16x8*)(Ab + r * 128 + (((4 + ks) << 4) ^ sw));
        }
        if (tt + 1 < 16) STAGE(obuf, 0, 1, tt + 1);
        __builtin_amdgcn_s_setprio(1);
#pragma unroll
        for (int m = 0; m < 2; ++m)
#pragma unroll
            for (int n = 0; n < 4; ++n) {
                acc[m + 2][n] = __builtin_amdgcn_mfma_f32_16x16x32_f16(
                    af27[m][0], bf[n][0], acc[m + 2][n], 0, 0, 0);
                acc[m + 2][n] = __builtin_amdgcn_mfma_f32_16x16x32_f16(
                    af27[m][1], bf[n][1], acc[m + 2][n], 0, 0, 0);
            }
        __builtin_amdgcn_s_setprio(0);
        // ---- mid barrier: all waves' buf reads (ph1 B, ph1/2 A) complete ----
        asm volatile("" ::: "memory");
        __builtin_amdgcn_s_barrier();
        __builtin_amdgcn_sched_barrier(0);
        // ---- ph3: stage B0(tt+2) into current buf; MFMA m=4,5 ----
        if (tt + 2 < 16) STAGE(buf, 1, 0, tt + 2);
        __builtin_amdgcn_s_setprio(1);
#pragma unroll
        for (int m = 2; m < 4; ++m)
#pragma unroll
            for (int n = 0; n < 4; ++n) {
                acc[m + 2][n] = __builtin_amdgcn_mfma_f32_16x16x32_f16(
                    af27[m][0], bf[n][0], acc[m + 2][n], 0, 0, 0);
                acc[m + 2][n] = __builtin_amdgcn_mfma_f32_16x16x32_f16(
                    af27[m][1], bf[n][1], acc[m + 2][n], 0, 0, 0);
            }
        __builtin_amdgcn_s_setprio(0);
        // ---- ph4: stage B1(tt+2); MFMA m=6,7 ----
        if (tt + 2 < 16) STAGE(buf, 1, 1, tt + 2);
        __builtin_amdgcn_s_setprio(1);
#pragma unroll
        for (int m = 4; m < 6; ++m)
#pragma unroll
            for (int n = 0; n < 4; ++n) {
                acc[m + 2][n] = __builtin_amdgcn_mfma_f32_16x16x32_f16(
                    af27[m][0], bf[n][0], acc[m + 2][n], 0, 0, 0);
                acc[m + 2][n] = __builtin_amdgcn_mfma_f32_16x16x32_f16(
                    af27[m][1], bf[n][1], acc[m + 2][n], 0, 0, 0);
            }
        __builtin_amdgcn_s_setprio(0);
    }
    // ---- epilogue: f16x4 stores into sorted q/k/v ----
#pragma unroll
    for (int m = 0; m < 8; ++m) {
        int hf = m >> 2;
        size_t bhb = ((size_t)(b2 * 16 + h0 + hf) << 13);
        int d = 16 * (m & 3) + 4 * ks;
#pragma unroll
        for (int n = 0; n < 4; ++n) {
            f16x4 st;
            st[0] = (_Float16)(acc[m][n][0] + bias4[m].x);
            st[1] = (_Float16)(acc[m][n][1] + bias4[m].y);
            st[2] = (_Float16)(acc[m][n][2] + bias4[m].z);
            st[3] = (_Float16)(acc[m][n][3] + bias4[m].w);
            *(f16x4*)(dq + (bhb + pos[hf][n]) * 64 + d) = st;
        }
    }
}

// ---- MFMA fused attention; coalesced K/V; XCD-chunked grid (R12-R16) ----
__global__ __launch_bounds__(256) void attn_mfma_kernel(
    const _Float16* __restrict__ qs_, const _Float16* __restrict__ ks_,
    const _Float16* __restrict__ vs_, const _Float16* __restrict__ ksamp,
    const _Float16* __restrict__ vsamp, const int* __restrict__ qidx,
    const int* __restrict__ sampled, _Float16* __restrict__ pre)
{
    __shared__ __align__(16) _Float16 Vt[2][64 * 68];
    int bid = blockIdx.x;
    int nb = (bid & 7) * 256 + (bid >> 3);
    int bh = nb >> 6, qb = (nb >> 1) & 31, half = nb & 1;
    int bb = bh >> 4, hh = bh & 15;
    size_t hb = (size_t)bh << 13;
    size_t bhs = (size_t)bh * 256;
    int t = threadIdx.x;
    int w = t >> 6, l = t & 63;
    int g = l >> 4, c16 = l & 15;
    int kg = t & 15, dg = t >> 4;
    int qw0 = qb * 256 + half * 128 + w * 32;
    const _Float16 qs = (_Float16)0.125f;

    int orig[2];
    f16x8 qf[2][2];
#pragma unroll
    for (int n = 0; n < 2; ++n) {
        int row = qw0 + 16 * n + c16;
        orig[n] = qidx[hb + row];
        const _Float16* qp = qs_ + (hb + row) * 64 + g * 8;
        qf[n][0] = *(const f16x8*)(qp);
        qf[n][1] = *(const f16x8*)(qp + 32);
#pragma unroll
        for (int j = 0; j < 8; ++j) { qf[n][0][j] *= qs; qf[n][1][j] *= qs; }
    }
    f32x4 o[4][2];
    float mr[2], lr[2];
#pragma unroll
    for (int n = 0; n < 2; ++n) {
        mr[n] = -1e30f; lr[n] = 0.f;
#pragma unroll
        for (int d2 = 0; d2 < 4; ++d2) o[d2][n] = (f32x4){0.f, 0.f, 0.f, 0.f};
    }
    const float LOG32 = 3.4657359027997265f;

    {
        const _Float16* vb = vs_ + (hb + qb * 256) * 64;
        f16x4 vr[4];
#pragma unroll
        for (int j2 = 0; j2 < 4; ++j2)
            vr[j2] = *(const f16x4*)(vb + (4 * kg + j2) * 64 + 4 * dg);
#pragma unroll
        for (int i = 0; i < 4; ++i) {
            f16x4 o4 = {vr[0][i], vr[1][i], vr[2][i], vr[3][i]};
            *(f16x4*)&Vt[0][(4 * dg + i) * 68 + 4 * kg] = o4;
        }
    }

    for (int c = 0; c < 8; ++c) {
        int cur = c & 1, nxt = cur ^ 1;
        bool samp = c >= 4;
        __syncthreads();
        const _Float16* kb = samp ? ksamp + (bhs + (size_t)(c - 4) * 64) * 64
                                  : ks_ + (hb + qb * 256 + (size_t)c * 64) * 64;
        f16x8 kf[4][2];
#pragma unroll
        for (int m = 0; m < 4; ++m) {
            const _Float16* kp = kb + (16 * m + c16) * 64 + g * 8;
            kf[m][0] = *(const f16x8*)(kp);
            kf[m][1] = *(const f16x8*)(kp + 32);
        }
        int4 spv[4];
        if (samp) {
#pragma unroll
            for (int m = 0; m < 4; ++m)
                spv[m] = *(const int4*)(sampled + bhs + (c - 4) * 64 + 16 * m + 4 * g);
        }
        f32x4 sacc[4][2];
#pragma unroll
        for (int m = 0; m < 4; ++m)
#pragma unroll
            for (int n = 0; n < 2; ++n) sacc[m][n] = (f32x4){0.f, 0.f, 0.f, 0.f};
#pragma unroll
        for (int m = 0; m < 4; ++m) {
#pragma unroll
            for (int n = 0; n < 2; ++n)
                sacc[m][n] = __builtin_amdgcn_mfma_f32_16x16x32_f16(
                    kf[m][0], qf[n][0], sacc[m][n], 0, 0, 0);
#pragma unroll
            for (int n = 0; n < 2; ++n)
                sacc[m][n] = __builtin_amdgcn_mfma_f32_16x16x32_f16(
                    kf[m][1], qf[n][1], sacc[m][n], 0, 0, 0);
        }
        f16x4 vrn[4];
        if (c < 7) {
            const _Float16* vb = (c + 1 >= 4)
                ? vsamp + (bhs + (size_t)(c - 3) * 64) * 64
                : vs_ + (hb + qb * 256 + (size_t)(c + 1) * 64) * 64;
#pragma unroll
            for (int j2 = 0; j2 < 4; ++j2)
                vrn[j2] = *(const f16x4*)(vb + (4 * kg + j2) * 64 + 4 * dg);
        }
        f16x4 av[4][4];
#pragma unroll
        for (int m = 0; m < 4; ++m)
#pragma unroll
            for (int d2 = 0; d2 < 4; ++d2)
                av[m][d2] = *(const f16x4*)&Vt[cur][(16 * d2 + c16) * 68 + 16 * m + 4 * g];
        bool msk[4][4];
#pragma unroll
        for (int m = 0; m < 4; ++m) {
            msk[m][0] = samp && ((spv[m].x >> 8) == qb);
            msk[m][1] = samp && ((spv[m].y >> 8) == qb);
            msk[m][2] = samp && ((spv[m].z >> 8) == qb);
            msk[m][3] = samp && ((spv[m].w >> 8) == qb);
        }
        float badd = samp ? LOG32 : 0.f;
#pragma unroll
        for (int n = 0; n < 2; ++n) {
            float sv[16];
#pragma unroll
            for (int m = 0; m < 4; ++m)
#pragma unroll
                for (int r = 0; r < 4; ++r)
                    sv[4 * m + r] = msk[m][r] ? -1e30f : sacc[m][n][r] + badd;
            float a0 = fmaxf(fmaxf(sv[0], sv[1]), sv[2]);
            float a1 = fmaxf(fmaxf(sv[3], sv[4]), sv[5]);
            float a2 = fmaxf(fmaxf(sv[6], sv[7]), sv[8]);
            float a3 = fmaxf(fmaxf(sv[9], sv[10]), sv[11]);
            float a4 = fmaxf(fmaxf(sv[12], sv[13]), sv[14]);
            float cm = fmaxf(fmaxf(fmaxf(a0, a1), a2), fmaxf(fmaxf(a3, a4), sv[15]));
            cm = fmaxf(cm, __shfl_xor(cm, 16, 64));
            cm = fmaxf(cm, __shfl_xor(cm, 32, 64));
            if (__any(cm > mr[n])) {
                float nm = fmaxf(mr[n], cm);
                float fq = __expf(mr[n] - nm);
                mr[n] = nm;
                lr[n] *= fq;
#pragma unroll
                for (int d2 = 0; d2 < 4; ++d2) {
                    o[d2][n][0] *= fq; o[d2][n][1] *= fq;
                    o[d2][n][2] *= fq; o[d2][n][3] *= fq;
                }
            }
            float pv16[16];
#pragma unroll
            for (int r = 0; r < 16; ++r) pv16[r] = __expf(sv[r] - mr[n]);
            float s0 = (pv16[0] + pv16[1]) + (pv16[2] + pv16[3]);
            float s1 = (pv16[4] + pv16[5]) + (pv16[6] + pv16[7]);
            float s2 = (pv16[8] + pv16[9]) + (pv16[10] + pv16[11]);
            float s3 = (pv16[12] + pv16[13]) + (pv16[14] + pv16[15]);
            float ps = (s0 + s1) + (s2 + s3);
            ps += __shfl_xor(ps, 16, 64);
            ps += __shfl_xor(ps, 32, 64);
            lr[n] += ps;
            f16x4 pb[4];
#pragma unroll
            for (int m = 0; m < 4; ++m) {
                fp16x2 c0 = __builtin_amdgcn_cvt_pkrtz(pv16[4 * m + 0], pv16[4 * m + 1]);
                fp16x2 c1 = __builtin_amdgcn_cvt_pkrtz(pv16[4 * m + 2], pv16[4 * m + 3]);
                pb[m][0] = (_Float16)c0[0]; pb[m][1] = (_Float16)c0[1];
                pb[m][2] = (_Float16)c1[0]; pb[m][3] = (_Float16)c1[1];
            }
#pragma unroll
            for (int d2 = 0; d2 < 4; ++d2)
#pragma unroll
                for (int m = 0; m < 4; ++m)
                    o[d2][n] = __builtin_amdgcn_mfma_f32_16x16x16f16(
                        av[m][d2], pb[m], o[d2][n], 0, 0, 0);
        }
        if (c < 7) {
#pragma unroll
            for (int i = 0; i < 4; ++i) {
                f16x4 o4 = {vrn[0][i], vrn[1][i], vrn[2][i], vrn[3][i]};
                *(f16x4*)&Vt[nxt][(4 * dg + i) * 68 + 4 * kg] = o4;
            }
        }
    }
#pragma unroll
    for (int n = 0; n < 2; ++n) {
        float invl = 1.f / lr[n];
        _Float16* pp = pre + ((size_t)(bb * 8192 + orig[n])) * 1024 + hh * 64;
#pragma unroll
        for (int d2 = 0; d2 < 4; ++d2) {
            f16x4 st;
            st[0] = (_Float16)(o[d2][n][0] * invl);
            st[1] = (_Float16)(o[d2][n][1] * invl);
            st[2] = (_Float16)(o[d2][n][2] * invl);
            st[3] = (_Float16)(o[d2][n][3] * invl);
            *(f16x4*)(pp + 16 * d2 + 4 * g) = st;
        }
    }
}

extern "C" void kernel_launch(void* const* d_in, const int* in_sizes, int n_in,
                              void* d_out, int out_size, void* d_ws, size_t ws_size,
                              hipStream_t stream)
{
    (void)in_sizes; (void)n_in; (void)out_size; (void)ws_size;
    const float* x     = (const float*)d_in[0];
    const float* Wqkv  = (const float*)d_in[1];
    const float* bqkv  = (const float*)d_in[2];
    const float* Wproj = (const float*)d_in[3];
    const float* bproj = (const float*)d_in[4];
    const float* proj  = (const float*)d_in[5];
    const int*   samp  = (const int*)d_in[6];
    float* out = (float*)d_out;

    char* ws = (char*)d_ws;
    size_t off = 0;
    auto take = [&](size_t bytes) {
        char* p = ws + off;
        off = (off + bytes + 255) & ~(size_t)255;
        return p;
    };
    _Float16* xh  = (_Float16*)take(33554432);   // x f16; reused as `pre`
    _Float16* q   = (_Float16*)take(33554432);   // [B,H,L,64] f16, SORTED rows
    _Float16* k   = (_Float16*)take(33554432);
    _Float16* v   = (_Float16*)take(33554432);
    float* scores = (float*)take(16777216);
    _Float16* Wtq = (_Float16*)take(6291456);
    _Float16* Wtp = (_Float16*)take(2097152);
    _Float16* foldh = (_Float16*)take(524288);
    _Float16* ksamp = (_Float16*)take(1048576);  // [32][256][64] f16
    _Float16* vsamp = (_Float16*)take(1048576);
    double* fold   = (double*)take(1835008);
    double* bfold  = (double*)take(1792);
    float* bfold32 = (float*)take(896);
    int* wcount = (int*)take(256);
    int* wlist  = (int*)take(WLIST_CAP * 4);
    int* hq    = (int*)take(1048576);
    int* hk    = (int*)take(1048576);
    int* qidx  = (int*)take(1048576);
    int* kidx  = (int*)take(1048576);
    int* qrank = (int*)take(1048576);
    int* krank = (int*)take(1048576);
    _Float16* pre = xh;   // alias: xh dead after gemm_qkv
    // total ~170 MB

    (void)hipFuncSetAttribute((const void*)gemm_qkv_kernel,
                              hipFuncAttributeMaxDynamicSharedMemorySize, 131072);
    (void)hipMemsetAsync(wcount, 0, 4, stream);
    castx_kernel<<<dim3(16384), dim3(256), 0, stream>>>(x, xh);
    fold_kernel<<<dim3(896), dim3(256), 0, stream>>>(
        Wqkv, bqkv, proj, fold, bfold, foldh, bfold32);
    mfma_gemm<2><<<dim3(2, 128), dim3(256), 0, stream>>>(
        xh, foldh, nullptr, scores, 1024, 256);
    hashext_kernel<<<dim3(2048), dim3(256), 0, stream>>>(
        scores, bfold32, hq, hk, wcount, wlist);
    refine_kernel<<<dim3(2048), dim3(256), 0, stream>>>(
        x, fold, bfold, wcount, wlist, hq, hk);
    sort_kernel<<<dim3(64), dim3(256), 0, stream>>>(
        hq, hk, qidx, kidx, qrank, krank);
    transpose_kernel<<<dim3(96, 32), dim3(256), 0, stream>>>(Wqkv, Wtq, 1024, 3072);
    transpose_kernel<<<dim3(32, 32), dim3(256), 0, stream>>>(Wproj, Wtp, 1024, 1024);
    gemm_qkv_kernel<<<dim3(768), dim3(512), 131072, stream>>>(
        Wtq, xh, bqkv, q, k, v, qrank, krank);
    gather_samp_kernel<<<dim3(32, 4), dim3(256), 0, stream>>>(
        k, v, samp, ksamp, vsamp);
    attn_mfma_kernel<<<dim3(2048), dim3(256), 0, stream>>>(
        q, k, v, ksamp, vsamp, qidx, samp, pre);
    mfma_gemm<0><<<dim3(8, 128), dim3(256), 0, stream>>>(
        pre, Wtp, bproj, out, 1024, 1024);
}

// Round 18
// 531.074 us; speedup vs baseline: 1.1421x; 1.0368x over previous
//
#include <hip/hip_runtime.h>
#include <hip/hip_fp16.h>
#include <math.h>

// Shapes (fixed): B=2, H=16, L=8192, dh=64, D=1024, 3*INNER=3072, NPROJ=7,
// BLOCK=256, SAMPLE=256.

typedef _Float16 f16x8 __attribute__((ext_vector_type(8)));
typedef _Float16 f16x4 __attribute__((ext_vector_type(4)));
typedef __fp16 fp16x2 __attribute__((ext_vector_type(2)));   // cvt_pkrtz native type
typedef float f32x4 __attribute__((ext_vector_type(4)));

#define WLIST_CAP 524288
#define TAU 0.06f

__device__ __forceinline__ void gl_lds16(const void* g, void* s) {
    __builtin_amdgcn_global_load_lds(
        (const __attribute__((address_space(1))) unsigned int*)g,
        (__attribute__((address_space(3))) unsigned int*)s, 16, 0, 0);
}

// ---- fold (fp64 exact) + f16 fold matrix for the MFMA hash pass ----
__global__ __launch_bounds__(256) void fold_kernel(
    const float* __restrict__ W, const float* __restrict__ bias,
    const float* __restrict__ proj, double* __restrict__ fold,
    double* __restrict__ bfold, _Float16* __restrict__ foldh,
    float* __restrict__ bfold32)
{
    int idx = blockIdx.x * 256 + threadIdx.x;
    if (idx < 2 * 16 * 7 * 1024) {
        int task = idx / 7168;
        int rem = idx - task * 7168;
        int i = rem / 7;
        int r = rem - i * 7;
        int h = task & 15, w = task >> 4;
        double s = 0.0;
        const float* wp = W + (size_t)i * 3072 + w * 1024 + h * 64;
        for (int d = 0; d < 64; ++d)
            s += (double)wp[d] * (double)proj[d * 7 + r];
        fold[idx] = s;
        foldh[((size_t)task * 7 + r) * 1024 + i] = (_Float16)s;
    }
    if (idx < 32768)    // zero-pad foldh rows 224..255
        foldh[229376 + idx] = (_Float16)0.f;
    if (idx < 224) {
        int r = idx % 7;
        int task = idx / 7;
        int h = task & 15, w = task >> 4;
        double s = 0.0;
        for (int d = 0; d < 64; ++d)
            s += (double)bias[w * 1024 + h * 64 + d] * (double)proj[d * 7 + r];
        bfold[idx] = s;
        bfold32[idx] = (float)s;
    }
}

// ---- hash extract: scores + bias -> gray hash; flag |val|<TAU ----
__global__ __launch_bounds__(256) void hashext_kernel(
    const float* __restrict__ scores, const float* __restrict__ bfold32,
    int* __restrict__ hq, int* __restrict__ hk,
    int* __restrict__ wcount, int* __restrict__ wlist)
{
    int tid = blockIdx.x * 256 + threadIdx.x;
    int row = tid >> 5, task = tid & 31;
    const float* sp = scores + (size_t)row * 256 + task * 7;
    int id = 0, fl = 0;
#pragma unroll
    for (int r = 0; r < 7; ++r) {
        float val = sp[r] + bfold32[task * 7 + r];
        if (fabsf(val) < TAU) fl = 1;
        if (val > 0.f) id |= (1 << r);
    }
    int hsh = id ^ (id >> 1);
    int w = task >> 4, h = task & 15;
    int b = row >> 13, l = row & 8191;
    (w ? hk : hq)[((size_t)(b * 16 + h) << 13) + l] = hsh;
    if (fl) {
        int slot = atomicAdd(wcount, 1);
        if (slot < WLIST_CAP) wlist[slot] = task * 16384 + row;
    }
}

// ---- refine: one WAVE per flagged (task,row); lane-parallel exact fp64 dot ----
__global__ __launch_bounds__(256) void refine_kernel(
    const float* __restrict__ x, const double* __restrict__ fold,
    const double* __restrict__ bfold, const int* __restrict__ wcount,
    const int* __restrict__ wlist, int* __restrict__ hq, int* __restrict__ hk)
{
    int n = *wcount;
    if (n > WLIST_CAP) n = WLIST_CAP;
    int lane = threadIdx.x & 63;
    int wid = (blockIdx.x * 256 + threadIdx.x) >> 6;
    int nw = gridDim.x * 4;
    for (int e = wid; e < n; e += nw) {
        int code = wlist[e];
        int task = code >> 14, grow = code & 16383;
        const double* f = fold + (size_t)task * 7168;
        const float* xp = x + (size_t)grow * 1024;
        double acc[7] = {0, 0, 0, 0, 0, 0, 0};
        for (int i = lane; i < 1024; i += 64) {
            double xv = (double)xp[i];
#pragma unroll
            for (int rr = 0; rr < 7; ++rr)
                acc[rr] = fma(xv, f[(size_t)i * 7 + rr], acc[rr]);
        }
        int id = 0;
#pragma unroll
        for (int rr = 0; rr < 7; ++rr) {
            double a = acc[rr];
#pragma unroll
            for (int off = 32; off > 0; off >>= 1) a += __shfl_xor(a, off, 64);
            if (a + bfold[task * 7 + rr] > 0.0) id |= (1 << rr);
        }
        if (lane == 0) {
            int hsh = id ^ (id >> 1);
            int w = task >> 4, h = task & 15;
            int b = grow >> 13, l = grow & 8191;
            (w ? hk : hq)[((size_t)(b * 16 + h) << 13) + l] = hsh;
        }
    }
}

// ---- stable counting sort (128 buckets) per (b,h); also emits rank (inverse) ----
__global__ __launch_bounds__(256) void sort_kernel(
    const int* __restrict__ hq, const int* __restrict__ hk,
    int* __restrict__ qidx, int* __restrict__ kidx,
    int* __restrict__ qrank, int* __restrict__ krank)
{
    __shared__ unsigned short cnt[128][128];
    __shared__ int tot[128];
    __shared__ int base[128];
    int blk = blockIdx.x;
    int sel = blk >> 5, bh = blk & 31;
    const int* hp = (sel ? hk : hq) + ((size_t)bh << 13);
    int* op = (sel ? kidx : qidx) + ((size_t)bh << 13);
    int* rp = (sel ? krank : qrank) + ((size_t)bh << 13);
    int t = threadIdx.x;
    for (int i = t; i < 128 * 128 / 2; i += 256) ((unsigned int*)cnt)[i] = 0u;
    __syncthreads();
    if (t < 128) {
        const int* p = hp + t * 64;
        for (int j = 0; j < 64; ++j) cnt[t][p[j]]++;
    }
    __syncthreads();
    if (t < 128) {
        int run = 0;
        for (int c = 0; c < 128; ++c) {
            int x2 = cnt[c][t];
            cnt[c][t] = (unsigned short)run;
            run += x2;
        }
        tot[t] = run;
    }
    __syncthreads();
    if (t == 0) {
        int run = 0;
        for (int v = 0; v < 128; ++v) { base[v] = run; run += tot[v]; }
    }
    __syncthreads();
    if (t < 128) {
        const int* p = hp + t * 64;
        for (int j = 0; j < 64; ++j) {
            int v = p[j];
            int c = cnt[t][v];
            cnt[t][v] = (unsigned short)(c + 1);
            int pos = base[v] + c;
            op[pos] = t * 64 + j;
            rp[t * 64 + j] = pos;
        }
    }
}

// ---- cast x fp32 -> f16 ----
__global__ __launch_bounds__(256) void castx_kernel(
    const float* __restrict__ x, _Float16* __restrict__ xh)
{
    int i = blockIdx.x * 256 + threadIdx.x;
    float4 f = ((const float4*)x)[i];
    _Float16 h4[4] = {(_Float16)f.x, (_Float16)f.y, (_Float16)f.z, (_Float16)f.w};
    *(short4*)&xh[(size_t)i * 4] = *(short4*)h4;
}

// ---- transpose+cast: W[K][N] fp32 -> Wt[N][K] f16 ----
__global__ __launch_bounds__(256) void transpose_kernel(
    const float* __restrict__ W, _Float16* __restrict__ Wt, int K, int N)
{
    __shared__ float tile[32][33];
    int bx = blockIdx.x, by = blockIdx.y;
    int tx = threadIdx.x & 31, ty = threadIdx.x >> 5;
    for (int i = ty; i < 32; i += 8)
        tile[i][tx] = W[(size_t)(by * 32 + i) * N + bx * 32 + tx];
    __syncthreads();
    for (int i = ty; i < 32; i += 8)
        Wt[(size_t)(bx * 32 + i) * K + by * 32 + tx] = (_Float16)tile[tx][i];
}

// ---- gather sampled K/V rows (sorted order) into dense per-bh buffers ----
__global__ __launch_bounds__(256) void gather_samp_kernel(
    const _Float16* __restrict__ ks, const _Float16* __restrict__ vs,
    const int* __restrict__ sampled, _Float16* __restrict__ ksamp,
    _Float16* __restrict__ vsamp)
{
    int bh = blockIdx.x;
    int key = blockIdx.y * 64 + (threadIdx.x >> 2);
    int qtr = (threadIdx.x & 3) * 16;
    size_t hb = (size_t)bh << 13;
    int p = sampled[bh * 256 + key];
    size_t src = (hb + p) * 64 + qtr;
    size_t dst = ((size_t)bh * 256 + key) * 64 + qtr;
    *(f16x8*)(ksamp + dst)     = *(const f16x8*)(ks + src);
    *(f16x8*)(ksamp + dst + 8) = *(const f16x8*)(ks + src + 8);
    *(f16x8*)(vsamp + dst)     = *(const f16x8*)(vs + src);
    *(f16x8*)(vsamp + dst + 8) = *(const f16x8*)(vs + src + 8);
}

// ---- plain f16 MFMA GEMM, BK=64 + XOR swizzle (R16): MODE 0=+bias, 2=no bias ----
template <int MODE>
__global__ __launch_bounds__(256) void mfma_gemm(
    const _Float16* __restrict__ A, const _Float16* __restrict__ Bt,
    const float* __restrict__ bias, float* __restrict__ C, int K, int N)
{
    __shared__ __align__(16) _Float16 As[128 * 64];
    __shared__ __align__(16) _Float16 Bs[128 * 64];
    int t = threadIdx.x;
    int w = t >> 6, l = t & 63;
    int m0 = blockIdx.y * 128, n0 = blockIdx.x * 128;
    int srow = 32 * w + (l >> 3);
    int sslot = ((l & 7) ^ (l >> 3)) * 8;
    const _Float16* ga = A + (size_t)(m0 + srow) * K + sslot;
    const _Float16* gb = Bt + (size_t)(n0 + srow) * K + sslot;
    int wr = w >> 1, wc = w & 1;
    int rl = l & 15, ks = l >> 4;
    f32x4 acc[4][4];
#pragma unroll
    for (int m = 0; m < 4; ++m)
#pragma unroll
        for (int n = 0; n < 4; ++n) acc[m][n] = (f32x4){0.f, 0.f, 0.f, 0.f};
    for (int kk = 0; kk < K; kk += 64) {
        __syncthreads();
#pragma unroll
        for (int i = 0; i < 4; ++i) {
            gl_lds16(ga + (size_t)(8 * i) * K + kk, (char*)As + (32 * w + 8 * i) * 128);
            gl_lds16(gb + (size_t)(8 * i) * K + kk, (char*)Bs + (32 * w + 8 * i) * 128);
        }
        __syncthreads();
        f16x8 af[4][2], bf[4][2];
#pragma unroll
        for (int m = 0; m < 4; ++m) {
            int r = 64 * wr + 16 * m + rl;
            int sw = (r & 7) << 4;
#pragma unroll
            for (int s = 0; s < 2; ++s)
                af[m][s] = *(const f16x8*)((char*)As + r * 128 + (((s * 4 + ks) << 4) ^ sw));
        }
#pragma unroll
        for (int n = 0; n < 4; ++n) {
            int r = 64 * wc + 16 * n + rl;
            int sw = (r & 7) << 4;
#pragma unroll
            for (int s = 0; s < 2; ++s)
                bf[n][s] = *(const f16x8*)((char*)Bs + r * 128 + (((s * 4 + ks) << 4) ^ sw));
        }
#pragma unroll
        for (int m = 0; m < 4; ++m)
#pragma unroll
            for (int n = 0; n < 4; ++n) {
                acc[m][n] = __builtin_amdgcn_mfma_f32_16x16x32_f16(
                    af[m][0], bf[n][0], acc[m][n], 0, 0, 0);
                acc[m][n] = __builtin_amdgcn_mfma_f32_16x16x32_f16(
                    af[m][1], bf[n][1], acc[m][n], 0, 0, 0);
            }
    }
#pragma unroll
    for (int m = 0; m < 4; ++m)
#pragma unroll
        for (int n = 0; n < 4; ++n) {
            int gn = n0 + 64 * wc + 16 * n + rl;
            float bv = (MODE == 2) ? 0.f : bias[gn];
#pragma unroll
            for (int j = 0; j < 4; ++j) {
                int gm = m0 + 64 * wr + 16 * m + 4 * ks + j;
                C[(size_t)gm * N + gn] = acc[m][n][j] + bv;
            }
        }
}

// ---- QKV GEMM: 256x256, BK=64, 8 waves, double-buffered pipeline (R17) ----
__global__ __launch_bounds__(512) void gemm_qkv_kernel(
    const _Float16* __restrict__ Wt, const _Float16* __restrict__ xh,
    const float* __restrict__ bias, _Float16* __restrict__ Q,
    _Float16* __restrict__ Kb, _Float16* __restrict__ Vb,
    const int* __restrict__ qrank, const int* __restrict__ krank)
{
    extern __shared__ __align__(16) char smem[];   // [buf][A 32K | B 32K] = 128 KB
    const int K = 1024;
    int bid = blockIdx.x;
    int xcd = bid & 7, slot = bid >> 3;
    int ty = slot / 12, tx = slot - ty * 12;
    int m0 = tx * 256;
    int n0 = (xcd * 8 + ty) * 256;
    int t = threadIdx.x;
    int w = t >> 6, l = t & 63;
    int wr = w >> 2, wc = w & 3;
    int rl = l & 15, ks = l >> 4;
    int srow = t >> 3;
    int sslot = (t & 7) ^ ((t >> 3) & 7);
    const _Float16* gA = Wt + (size_t)m0 * K + sslot * 8;
    const _Float16* gB = xh + (size_t)n0 * K + sslot * 8;
    char* dstT = smem + t * 16;

    auto STAGE = [&](int buf, int op, int half, int kt) {
        const _Float16* src = op ? gB : gA;
        char* d = dstT + buf * 65536 + op * 32768 + half * 16384;
        size_t ro = (size_t)(half * 128 + srow) * K + kt * 64;
        gl_lds16(src + ro, d);
        gl_lds16(src + ro + (size_t)64 * K, d + 8192);
    };

    int fbase = m0 + 128 * wr;
    int s0 = fbase >> 10;
    int h0 = (fbase >> 6) & 15;
    int b2 = n0 >> 13;
    const int* rk = (s0 == 0) ? qrank : krank;
    _Float16* dq = (s0 == 0) ? Q : (s0 == 1 ? Kb : Vb);
    int tl = (n0 & 8191) + 64 * wc;
    int pos[2][4];
#pragma unroll
    for (int hf = 0; hf < 2; ++hf)
#pragma unroll
        for (int n = 0; n < 4; ++n)
            pos[hf][n] = rk[((size_t)(b2 * 16 + h0 + hf) << 13) + tl + 16 * n + rl];
    float4 bias4[8];
#pragma unroll
    for (int m = 0; m < 8; ++m)
        bias4[m] = *(const float4*)&bias[fbase + 16 * m + 4 * ks];

    f32x4 acc[8][4];
#pragma unroll
    for (int m = 0; m < 8; ++m)
#pragma unroll
        for (int n = 0; n < 4; ++n) acc[m][n] = (f32x4){0.f, 0.f, 0.f, 0.f};

    STAGE(0, 0, 0, 0); STAGE(0, 0, 1, 0); STAGE(0, 1, 0, 0); STAGE(0, 1, 1, 0);
    STAGE(1, 1, 0, 1); STAGE(1, 1, 1, 1);

    for (int tt = 0; tt < 16; ++tt) {
        int buf = tt & 1, obuf = buf ^ 1;
        if (tt < 15) asm volatile("s_waitcnt vmcnt(4)" ::: "memory");
        else         asm volatile("s_waitcnt vmcnt(0)" ::: "memory");
        __builtin_amdgcn_sched_barrier(0);
        __builtin_amdgcn_s_barrier();
        __builtin_amdgcn_sched_barrier(0);
        const char* Ab = smem + buf * 65536;
        const char* Bb = Ab + 32768;
        f16x8 bf[4][2], af01[2][2];
#pragma unroll
        for (int n = 0; n < 4; ++n) {
            int r = 64 * wc + 16 * n + rl;
            int sw = (r & 7) << 4;
            bf[n][0] = *(const f16x8*)(Bb + r * 128 + ((ks << 4) ^ sw));
            bf[n][1] = *(const f16x8*)(Bb + r * 128 + (((4 + ks) << 4) ^ sw));
        }
#pragma unroll
        for (int m = 0; m < 2; ++m) {
            int r = 128 * wr + 16 * m + rl;
            int sw = (r & 7) << 4;
            af01[m][0] = *(const f16x8*)(Ab + r * 128 + ((ks << 4) ^ sw));
            af01[m][1] = *(const f16x8*)(Ab + r * 128 + (((4 + ks) << 4) ^ sw));
        }
        if (tt + 1 < 16) STAGE(obuf, 0, 0, tt + 1);
        __builtin_amdgcn_s_setprio(1);
#pragma unroll
        for (int m = 0; m < 2; ++m)
#pragma unroll
            for (int n = 0; n < 4; ++n) {
                acc[m][n] = __builtin_amdgcn_mfma_f32_16x16x32_f16(
                    af01[m][0], bf[n][0], acc[m][n], 0, 0, 0);
                acc[m][n] = __builtin_amdgcn_mfma_f32_16x16x32_f16(
                    af01[m][1], bf[n][1], acc[m][n], 0, 0, 0);
            }
        __builtin_amdgcn_s_setprio(0);
        f16x8 af27[6][2];
#pragma unroll
        for (int m = 0; m < 6; ++m) {
            int r = 128 * wr + 16 * (m + 2) + rl;
            int sw = (r & 7) << 4;
            af27[m][0] = *(const f16x8*)(Ab + r * 128 + ((ks << 4) ^ sw));
            af27[m][1] = *(const f16x8*)(Ab + r * 128 + (((4 + ks) << 4) ^ sw));
        }
        if (tt + 1 < 16) STAGE(obuf, 0, 1, tt + 1);
        __builtin_amdgcn_s_setprio(1);
#pragma unroll
        for (int m = 0; m < 2; ++m)
#pragma unroll
            for (int n = 0; n < 4; ++n) {
                acc[m + 2][n] = __builtin_amdgcn_mfma_f32_16x16x32_f16(
                    af27[m][0], bf[n][0], acc[m + 2][n], 0, 0, 0);
                acc[m + 2][n] = __builtin_amdgcn_mfma_f32_16x16x32_f16(
                    af27[m][1], bf[n][1], acc[m + 2][n], 0, 0, 0);
            }
        __builtin_amdgcn_s_setprio(0);
        asm volatile("" ::: "memory");
        __builtin_amdgcn_s_barrier();
        __builtin_amdgcn_sched_barrier(0);
        if (tt + 2 < 16) STAGE(buf, 1, 0, tt + 2);
        __builtin_amdgcn_s_setprio(1);
#pragma unroll
        for (int m = 2; m < 4; ++m)
#pragma unroll
            for (int n = 0; n < 4; ++n) {
                acc[m + 2][n] = __builtin_amdgcn_mfma_f32_16x16x32_f16(
                    af27[m][0], bf[n][0], acc[m + 2][n], 0, 0, 0);
                acc[m + 2][n] = __builtin_amdgcn_mfma_f32_16x16x32_f16(
                    af27[m][1], bf[n][1], acc[m + 2][n], 0, 0, 0);
            }
        __builtin_amdgcn_s_setprio(0);
        if (tt + 2 < 16) STAGE(buf, 1, 1, tt + 2);
        __builtin_amdgcn_s_setprio(1);
#pragma unroll
        for (int m = 4; m < 6; ++m)
#pragma unroll
            for (int n = 0; n < 4; ++n) {
                acc[m + 2][n] = __builtin_amdgcn_mfma_f32_16x16x32_f16(
                    af27[m][0], bf[n][0], acc[m + 2][n], 0, 0, 0);
                acc[m + 2][n] = __builtin_amdgcn_mfma_f32_16x16x32_f16(
                    af27[m][1], bf[n][1], acc[m + 2][n], 0, 0, 0);
            }
        __builtin_amdgcn_s_setprio(0);
    }
#pragma unroll
    for (int m = 0; m < 8; ++m) {
        int hf = m >> 2;
        size_t bhb = ((size_t)(b2 * 16 + h0 + hf) << 13);
        int d = 16 * (m & 3) + 4 * ks;
#pragma unroll
        for (int n = 0; n < 4; ++n) {
            f16x4 st;
            st[0] = (_Float16)(acc[m][n][0] + bias4[m].x);
            st[1] = (_Float16)(acc[m][n][1] + bias4[m].y);
            st[2] = (_Float16)(acc[m][n][2] + bias4[m].z);
            st[3] = (_Float16)(acc[m][n][3] + bias4[m].w);
            *(f16x4*)(dq + (bhb + pos[hf][n]) * 64 + d) = st;
        }
    }
}

// ---- OUT GEMM: same validated 256x256 pipeline template, fp32+bias epilogue.
// A = pre (tokens, m-side), B = Wtp (features, n-side); stores lane-coalesced.
__global__ __launch_bounds__(512) void gemm_out_kernel(
    const _Float16* __restrict__ Ap, const _Float16* __restrict__ Bt,
    const float* __restrict__ bias, float* __restrict__ C)
{
    extern __shared__ __align__(16) char smem[];   // 128 KB
    const int K = 1024;
    int bid = blockIdx.x;                 // 256 = 64 m-tiles x 4 n-tiles
    int m0 = (bid >> 2) * 256;
    int n0 = (bid & 3) * 256;
    int t = threadIdx.x;
    int w = t >> 6, l = t & 63;
    int wr = w >> 2, wc = w & 3;
    int rl = l & 15, ks = l >> 4;
    int srow = t >> 3;
    int sslot = (t & 7) ^ ((t >> 3) & 7);
    const _Float16* gA = Ap + (size_t)m0 * K + sslot * 8;
    const _Float16* gB = Bt + (size_t)n0 * K + sslot * 8;
    char* dstT = smem + t * 16;

    auto STAGE = [&](int buf, int op, int half, int kt) {
        const _Float16* src = op ? gB : gA;
        char* d = dstT + buf * 65536 + op * 32768 + half * 16384;
        size_t ro = (size_t)(half * 128 + srow) * K + kt * 64;
        gl_lds16(src + ro, d);
        gl_lds16(src + ro + (size_t)64 * K, d + 8192);
    };

    f32x4 acc[8][4];
#pragma unroll
    for (int m = 0; m < 8; ++m)
#pragma unroll
        for (int n = 0; n < 4; ++n) acc[m][n] = (f32x4){0.f, 0.f, 0.f, 0.f};

    STAGE(0, 0, 0, 0); STAGE(0, 0, 1, 0); STAGE(0, 1, 0, 0); STAGE(0, 1, 1, 0);
    STAGE(1, 1, 0, 1); STAGE(1, 1, 1, 1);

    for (int tt = 0; tt < 16; ++tt) {
        int buf = tt & 1, obuf = buf ^ 1;
        if (tt < 15) asm volatile("s_waitcnt vmcnt(4)" ::: "memory");
        else         asm volatile("s_waitcnt vmcnt(0)" ::: "memory");
        __builtin_amdgcn_sched_barrier(0);
        __builtin_amdgcn_s_barrier();
        __builtin_amdgcn_sched_barrier(0);
        const char* Ab = smem + buf * 65536;
        const char* Bb = Ab + 32768;
        f16x8 bf[4][2], af01[2][2];
#pragma unroll
        for (int n = 0; n < 4; ++n) {
            int r = 64 * wc + 16 * n + rl;
            int sw = (r & 7) << 4;
            bf[n][0] = *(const f16x8*)(Bb + r * 128 + ((ks << 4) ^ sw));
            bf[n][1] = *(const f16x8*)(Bb + r * 128 + (((4 + ks) << 4) ^ sw));
        }
#pragma unroll
        for (int m = 0; m < 2; ++m) {
            int r = 128 * wr + 16 * m + rl;
            int sw = (r & 7) << 4;
            af01[m][0] = *(const f16x8*)(Ab + r * 128 + ((ks << 4) ^ sw));
            af01[m][1] = *(const f16x8*)(Ab + r * 128 + (((4 + ks) << 4) ^ sw));
        }
        if (tt + 1 < 16) STAGE(obuf, 0, 0, tt + 1);
        __builtin_amdgcn_s_setprio(1);
#pragma unroll
        for (int m = 0; m < 2; ++m)
#pragma unroll
            for (int n = 0; n < 4; ++n) {
                acc[m][n] = __builtin_amdgcn_mfma_f32_16x16x32_f16(
                    af01[m][0], bf[n][0], acc[m][n], 0, 0, 0);
                acc[m][n] = __builtin_amdgcn_mfma_f32_16x16x32_f16(
                    af01[m][1], bf[n][1], acc[m][n], 0, 0, 0);
            }
        __builtin_amdgcn_s_setprio(0);
        f16x8 af27[6][2];
#pragma unroll
        for (int m = 0; m < 6; ++m) {
            int r = 128 * wr + 16 * (m + 2) + rl;
            int sw = (r & 7) << 4;
            af27[m][0] = *(const f16x8*)(Ab + r * 128 + ((ks << 4) ^ sw));
            af27[m][1] = *(const f16x8*)(Ab + r * 128 + (((4 + ks) << 4) ^ sw));
        }
        if (tt + 1 < 16) STAGE(obuf, 0, 1, tt + 1);
        __builtin_amdgcn_s_setprio(1);
#pragma unroll
        for (int m = 0; m < 2; ++m)
#pragma unroll
            for (int n = 0; n < 4; ++n) {
                acc[m + 2][n] = __builtin_amdgcn_mfma_f32_16x16x32_f16(
                    af27[m][0], bf[n][0], acc[m + 2][n], 0, 0, 0);
                acc[m + 2][n] = __builtin_amdgcn_mfma_f32_16x16x32_f16(
                    af27[m][1], bf[n][1], acc[m + 2][n], 0, 0, 0);
            }
        __builtin_amdgcn_s_setprio(0);
        asm volatile("" ::: "memory");
        __builtin_amdgcn_s_barrier();
        __builtin_amdgcn_sched_barrier(0);
        if (tt + 2 < 16) STAGE(buf, 1, 0, tt + 2);
        __builtin_amdgcn_s_setprio(1);
#pragma unroll
        for (int m = 2; m < 4; ++m)
#pragma unroll
            for (int n = 0; n < 4; ++n) {
                acc[m + 2][n] = __builtin_amdgcn_mfma_f32_16x16x32_f16(
                    af27[m][0], bf[n][0], acc[m + 2][n], 0, 0, 0);
                acc[m + 2][n] = __builtin_amdgcn_mfma_f32_16x16x32_f16(
                    af27[m][1], bf[n][1], acc[m + 2][n], 0, 0, 0);
            }
        __builtin_amdgcn_s_setprio(0);
        if (tt + 2 < 16) STAGE(buf, 1, 1, tt + 2);
        __builtin_amdgcn_s_setprio(1);
#pragma unroll
        for (int m = 4; m < 6; ++m)
#pragma unroll
            for (int n = 0; n < 4; ++n) {
                acc[m + 2][n] = __builtin_amdgcn_mfma_f32_16x16x32_f16(
                    af27[m][0], bf[n][0], acc[m + 2][n], 0, 0, 0);
                acc[m + 2][n] = __builtin_amdgcn_mfma_f32_16x16x32_f16(
                    af27[m][1], bf[n][1], acc[m + 2][n], 0, 0, 0);
            }
        __builtin_amdgcn_s_setprio(0);
    }
#pragma unroll
    for (int m = 0; m < 8; ++m)
#pragma unroll
        for (int n = 0; n < 4; ++n) {
            int gn = n0 + 64 * wc + 16 * n + rl;
            float bv = bias[gn];
#pragma unroll
            for (int j = 0; j < 4; ++j) {
                int gm = m0 + 128 * wr + 16 * m + 4 * ks + j;
                C[(size_t)gm * 1024 + gn] = acc[m][n][j] + bv;
            }
        }
}

// ---- MFMA fused attention; coalesced K/V; XCD-chunked grid (R12-R17) ----
__global__ __launch_bounds__(256) void attn_mfma_kernel(
    const _Float16* __restrict__ qs_, const _Float16* __restrict__ ks_,
    const _Float16* __restrict__ vs_, const _Float16* __restrict__ ksamp,
    const _Float16* __restrict__ vsamp, const int* __restrict__ qidx,
    const int* __restrict__ sampled, _Float16* __restrict__ pre)
{
    __shared__ __align__(16) _Float16 Vt[2][64 * 68];
    int bid = blockIdx.x;
    int nb = (bid & 7) * 256 + (bid >> 3);
    int bh = nb >> 6, qb = (nb >> 1) & 31, half = nb & 1;
    int bb = bh >> 4, hh = bh & 15;
    size_t hb = (size_t)bh << 13;
    size_t bhs = (size_t)bh * 256;
    int t = threadIdx.x;
    int w = t >> 6, l = t & 63;
    int g = l >> 4, c16 = l & 15;
    int kg = t & 15, dg = t >> 4;
    int qw0 = qb * 256 + half * 128 + w * 32;
    const _Float16 qs = (_Float16)0.125f;

    int orig[2];
    f16x8 qf[2][2];
#pragma unroll
    for (int n = 0; n < 2; ++n) {
        int row = qw0 + 16 * n + c16;
        orig[n] = qidx[hb + row];
        const _Float16* qp = qs_ + (hb + row) * 64 + g * 8;
        qf[n][0] = *(const f16x8*)(qp);
        qf[n][1] = *(const f16x8*)(qp + 32);
#pragma unroll
        for (int j = 0; j < 8; ++j) { qf[n][0][j] *= qs; qf[n][1][j] *= qs; }
    }
    f32x4 o[4][2];
    float mr[2], lr[2];
#pragma unroll
    for (int n = 0; n < 2; ++n) {
        mr[n] = -1e30f; lr[n] = 0.f;
#pragma unroll
        for (int d2 = 0; d2 < 4; ++d2) o[d2][n] = (f32x4){0.f, 0.f, 0.f, 0.f};
    }
    const float LOG32 = 3.4657359027997265f;

    {
        const _Float16* vb = vs_ + (hb + qb * 256) * 64;
        f16x4 vr[4];
#pragma unroll
        for (int j2 = 0; j2 < 4; ++j2)
            vr[j2] = *(const f16x4*)(vb + (4 * kg + j2) * 64 + 4 * dg);
#pragma unroll
        for (int i = 0; i < 4; ++i) {
            f16x4 o4 = {vr[0][i], vr[1][i], vr[2][i], vr[3][i]};
            *(f16x4*)&Vt[0][(4 * dg + i) * 68 + 4 * kg] = o4;
        }
    }

    for (int c = 0; c < 8; ++c) {
        int cur = c & 1, nxt = cur ^ 1;
        bool samp = c >= 4;
        __syncthreads();
        const _Float16* kb = samp ? ksamp + (bhs + (size_t)(c - 4) * 64) * 64
                                  : ks_ + (hb + qb * 256 + (size_t)c * 64) * 64;
        f16x8 kf[4][2];
#pragma unroll
        for (int m = 0; m < 4; ++m) {
            const _Float16* kp = kb + (16 * m + c16) * 64 + g * 8;
            kf[m][0] = *(const f16x8*)(kp);
            kf[m][1] = *(const f16x8*)(kp + 32);
        }
        int4 spv[4];
        if (samp) {
#pragma unroll
            for (int m = 0; m < 4; ++m)
                spv[m] = *(const int4*)(sampled + bhs + (c - 4) * 64 + 16 * m + 4 * g);
        }
        f32x4 sacc[4][2];
#pragma unroll
        for (int m = 0; m < 4; ++m)
#pragma unroll
            for (int n = 0; n < 2; ++n) sacc[m][n] = (f32x4){0.f, 0.f, 0.f, 0.f};
#pragma unroll
        for (int m = 0; m < 4; ++m) {
#pragma unroll
            for (int n = 0; n < 2; ++n)
                sacc[m][n] = __builtin_amdgcn_mfma_f32_16x16x32_f16(
                    kf[m][0], qf[n][0], sacc[m][n], 0, 0, 0);
#pragma unroll
            for (int n = 0; n < 2; ++n)
                sacc[m][n] = __builtin_amdgcn_mfma_f32_16x16x32_f16(
                    kf[m][1], qf[n][1], sacc[m][n], 0, 0, 0);
        }
        f16x4 vrn[4];
        if (c < 7) {
            const _Float16* vb = (c + 1 >= 4)
                ? vsamp + (bhs + (size_t)(c - 3) * 64) * 64
                : vs_ + (hb + qb * 256 + (size_t)(c + 1) * 64) * 64;
#pragma unroll
            for (int j2 = 0; j2 < 4; ++j2)
                vrn[j2] = *(const f16x4*)(vb + (4 * kg + j2) * 64 + 4 * dg);
        }
        f16x4 av[4][4];
#pragma unroll
        for (int m = 0; m < 4; ++m)
#pragma unroll
            for (int d2 = 0; d2 < 4; ++d2)
                av[m][d2] = *(const f16x4*)&Vt[cur][(16 * d2 + c16) * 68 + 16 * m + 4 * g];
        bool msk[4][4];
#pragma unroll
        for (int m = 0; m < 4; ++m) {
            msk[m][0] = samp && ((spv[m].x >> 8) == qb);
            msk[m][1] = samp && ((spv[m].y >> 8) == qb);
            msk[m][2] = samp && ((spv[m].z >> 8) == qb);
            msk[m][3] = samp && ((spv[m].w >> 8) == qb);
        }
        float badd = samp ? LOG32 : 0.f;
#pragma unroll
        for (int n = 0; n < 2; ++n) {
            float sv[16];
#pragma unroll
            for (int m = 0; m < 4; ++m)
#pragma unroll
                for (int r = 0; r < 4; ++r)
                    sv[4 * m + r] = msk[m][r] ? -1e30f : sacc[m][n][r] + badd;
            float a0 = fmaxf(fmaxf(sv[0], sv[1]), sv[2]);
            float a1 = fmaxf(fmaxf(sv[3], sv[4]), sv[5]);
            float a2 = fmaxf(fmaxf(sv[6], sv[7]), sv[8]);
            float a3 = fmaxf(fmaxf(sv[9], sv[10]), sv[11]);
            float a4 = fmaxf(fmaxf(sv[12], sv[13]), sv[14]);
            float cm = fmaxf(fmaxf(fmaxf(a0, a1), a2), fmaxf(fmaxf(a3, a4), sv[15]));
            cm = fmaxf(cm, __shfl_xor(cm, 16, 64));
            cm = fmaxf(cm, __shfl_xor(cm, 32, 64));
            if (__any(cm > mr[n])) {
                float nm = fmaxf(mr[n], cm);
                float fq = __expf(mr[n] - nm);
                mr[n] = nm;
                lr[n] *= fq;
#pragma unroll
                for (int d2 = 0; d2 < 4; ++d2) {
                    o[d2][n][0] *= fq; o[d2][n][1] *= fq;
                    o[d2][n][2] *= fq; o[d2][n][3] *= fq;
                }
            }
            float pv16[16];
#pragma unroll
            for (int r = 0; r < 16; ++r) pv16[r] = __expf(sv[r] - mr[n]);
            float s0 = (pv16[0] + pv16[1]) + (pv16[2] + pv16[3]);
            float s1 = (pv16[4] + pv16[5]) + (pv16[6] + pv16[7]);
            float s2 = (pv16[8] + pv16[9]) + (pv16[10] + pv16[11]);
            float s3 = (pv16[12] + pv16[13]) + (pv16[14] + pv16[15]);
            float ps = (s0 + s1) + (s2 + s3);
            ps += __shfl_xor(ps, 16, 64);
            ps += __shfl_xor(ps, 32, 64);
            lr[n] += ps;
            f16x4 pb[4];
#pragma unroll
            for (int m = 0; m < 4; ++m) {
                fp16x2 c0 = __builtin_amdgcn_cvt_pkrtz(pv16[4 * m + 0], pv16[4 * m + 1]);
                fp16x2 c1 = __builtin_amdgcn_cvt_pkrtz(pv16[4 * m + 2], pv16[4 * m + 3]);
                pb[m][0] = (_Float16)c0[0]; pb[m][1] = (_Float16)c0[1];
                pb[m][2] = (_Float16)c1[0]; pb[m][3] = (_Float16)c1[1];
            }
#pragma unroll
            for (int d2 = 0; d2 < 4; ++d2)
#pragma unroll
                for (int m = 0; m < 4; ++m)
                    o[d2][n] = __builtin_amdgcn_mfma_f32_16x16x16f16(
                        av[m][d2], pb[m], o[d2][n], 0, 0, 0);
        }
        if (c < 7) {
#pragma unroll
            for (int i = 0; i < 4; ++i) {
                f16x4 o4 = {vrn[0][i], vrn[1][i], vrn[2][i], vrn[3][i]};
                *(f16x4*)&Vt[nxt][(4 * dg + i) * 68 + 4 * kg] = o4;
            }
        }
    }
#pragma unroll
    for (int n = 0; n < 2; ++n) {
        float invl = 1.f / lr[n];
        _Float16* pp = pre + ((size_t)(bb * 8192 + orig[n])) * 1024 + hh * 64;
#pragma unroll
        for (int d2 = 0; d2 < 4; ++d2) {
            f16x4 st;
            st[0] = (_Float16)(o[d2][n][0] * invl);
            st[1] = (_Float16)(o[d2][n][1] * invl);
            st[2] = (_Float16)(o[d2][n][2] * invl);
            st[3] = (_Float16)(o[d2][n][3] * invl);
            *(f16x4*)(pp + 16 * d2 + 4 * g) = st;
        }
    }
}

extern "C" void kernel_launch(void* const* d_in, const int* in_sizes, int n_in,
                              void* d_out, int out_size, void* d_ws, size_t ws_size,
                              hipStream_t stream)
{
    (void)in_sizes; (void)n_in; (void)out_size; (void)ws_size;
    const float* x     = (const float*)d_in[0];
    const float* Wqkv  = (const float*)d_in[1];
    const float* bqkv  = (const float*)d_in[2];
    const float* Wproj = (const float*)d_in[3];
    const float* bproj = (const float*)d_in[4];
    const float* proj  = (const float*)d_in[5];
    const int*   samp  = (const int*)d_in[6];
    float* out = (float*)d_out;

    char* ws = (char*)d_ws;
    size_t off = 0;
    auto take = [&](size_t bytes) {
        char* p = ws + off;
        off = (off + bytes + 255) & ~(size_t)255;
        return p;
    };
    _Float16* xh  = (_Float16*)take(33554432);   // x f16; reused as `pre`
    _Float16* q   = (_Float16*)take(33554432);   // [B,H,L,64] f16, SORTED rows
    _Float16* k   = (_Float16*)take(33554432);
    _Float16* v   = (_Float16*)take(33554432);
    float* scores = (float*)take(16777216);
    _Float16* Wtq = (_Float16*)take(6291456);
    _Float16* Wtp = (_Float16*)take(2097152);
    _Float16* foldh = (_Float16*)take(524288);
    _Float16* ksamp = (_Float16*)take(1048576);  // [32][256][64] f16
    _Float16* vsamp = (_Float16*)take(1048576);
    double* fold   = (double*)take(1835008);
    double* bfold  = (double*)take(1792);
    float* bfold32 = (float*)take(896);
    int* wcount = (int*)take(256);
    int* wlist  = (int*)take(WLIST_CAP * 4);
    int* hq    = (int*)take(1048576);
    int* hk    = (int*)take(1048576);
    int* qidx  = (int*)take(1048576);
    int* kidx  = (int*)take(1048576);
    int* qrank = (int*)take(1048576);
    int* krank = (int*)take(1048576);
    _Float16* pre = xh;   // alias: xh dead after gemm_qkv
    // total ~170 MB

    (void)hipFuncSetAttribute((const void*)gemm_qkv_kernel,
                              hipFuncAttributeMaxDynamicSharedMemorySize, 131072);
    (void)hipFuncSetAttribute((const void*)gemm_out_kernel,
                              hipFuncAttributeMaxDynamicSharedMemorySize, 131072);
    (void)hipMemsetAsync(wcount, 0, 4, stream);
    castx_kernel<<<dim3(16384), dim3(256), 0, stream>>>(x, xh);
    fold_kernel<<<dim3(896), dim3(256), 0, stream>>>(
        Wqkv, bqkv, proj, fold, bfold, foldh, bfold32);
    mfma_gemm<2><<<dim3(2, 128), dim3(256), 0, stream>>>(
        xh, foldh, nullptr, scores, 1024, 256);
    hashext_kernel<<<dim3(2048), dim3(256), 0, stream>>>(
        scores, bfold32, hq, hk, wcount, wlist);
    refine_kernel<<<dim3(2048), dim3(256), 0, stream>>>(
        x, fold, bfold, wcount, wlist, hq, hk);
    sort_kernel<<<dim3(64), dim3(256), 0, stream>>>(
        hq, hk, qidx, kidx, qrank, krank);
    transpose_kernel<<<dim3(96, 32), dim3(256), 0, stream>>>(Wqkv, Wtq, 1024, 3072);
    transpose_kernel<<<dim3(32, 32), dim3(256), 0, stream>>>(Wproj, Wtp, 1024, 1024);
    gemm_qkv_kernel<<<dim3(768), dim3(512), 131072, stream>>>(
        Wtq, xh, bqkv, q, k, v, qrank, krank);
    gather_samp_kernel<<<dim3(32, 4), dim3(256), 0, stream>>>(
        k, v, samp, ksamp, vsamp);
    attn_mfma_kernel<<<dim3(2048), dim3(256), 0, stream>>>(
        q, k, v, ksamp, vsamp, qidx, samp, pre);
    gemm_out_kernel<<<dim3(256), dim3(512), 131072, stream>>>(
        pre, Wtp, bproj, out);
}

// Round 19
// 524.649 us; speedup vs baseline: 1.1561x; 1.0122x over previous
//
#include <hip/hip_runtime.h>
#include <hip/hip_fp16.h>
#include <math.h>

// Shapes (fixed): B=2, H=16, L=8192, dh=64, D=1024, 3*INNER=3072, NPROJ=7,
// BLOCK=256, SAMPLE=256.

typedef _Float16 f16x8 __attribute__((ext_vector_type(8)));
typedef _Float16 f16x4 __attribute__((ext_vector_type(4)));
typedef __fp16 fp16x2 __attribute__((ext_vector_type(2)));   // cvt_pkrtz native type
typedef float f32x4 __attribute__((ext_vector_type(4)));

#define WLIST_CAP 524288
#define TAU 0.06f

__device__ __forceinline__ void gl_lds16(const void* g, void* s) {
    __builtin_amdgcn_global_load_lds(
        (const __attribute__((address_space(1))) unsigned int*)g,
        (__attribute__((address_space(3))) unsigned int*)s, 16, 0, 0);
}

// ---- fused prep: castx | fold | transpose(Wqkv) | transpose(Wproj).
// All four are independent (disjoint outputs); branch is blockIdx-uniform so
// the __syncthreads in the transpose path is non-divergent.
__global__ __launch_bounds__(256) void prep_kernel(
    const float* __restrict__ x, _Float16* __restrict__ xh,
    const float* __restrict__ Wqkv, const float* __restrict__ bqkv,
    const float* __restrict__ proj, double* __restrict__ fold,
    double* __restrict__ bfold, _Float16* __restrict__ foldh,
    float* __restrict__ bfold32, const float* __restrict__ Wproj,
    _Float16* __restrict__ Wtq, _Float16* __restrict__ Wtp)
{
    __shared__ float tile[32][33];
    int b = blockIdx.x;
    if (b < 16384) {
        // ---- castx: x fp32 -> f16 ----
        int i = b * 256 + threadIdx.x;
        float4 f = ((const float4*)x)[i];
        _Float16 h4[4] = {(_Float16)f.x, (_Float16)f.y, (_Float16)f.z, (_Float16)f.w};
        *(short4*)&xh[(size_t)i * 4] = *(short4*)h4;
    } else if (b < 17280) {
        // ---- fold (fp64 exact) + f16 fold matrix ----
        int idx = (b - 16384) * 256 + threadIdx.x;
        if (idx < 2 * 16 * 7 * 1024) {
            int task = idx / 7168;
            int rem = idx - task * 7168;
            int i = rem / 7;
            int r = rem - i * 7;
            int h = task & 15, w = task >> 4;
            double s = 0.0;
            const float* wp = Wqkv + (size_t)i * 3072 + w * 1024 + h * 64;
            for (int d = 0; d < 64; ++d)
                s += (double)wp[d] * (double)proj[d * 7 + r];
            fold[idx] = s;
            foldh[((size_t)task * 7 + r) * 1024 + i] = (_Float16)s;
        }
        if (idx < 32768)    // zero-pad foldh rows 224..255
            foldh[229376 + idx] = (_Float16)0.f;
        if (idx < 224) {
            int r = idx % 7;
            int task = idx / 7;
            int h = task & 15, w = task >> 4;
            double s = 0.0;
            for (int d = 0; d < 64; ++d)
                s += (double)bqkv[w * 1024 + h * 64 + d] * (double)proj[d * 7 + r];
            bfold[idx] = s;
            bfold32[idx] = (float)s;
        }
    } else if (b < 20352) {
        // ---- transpose+cast Wqkv[1024][3072] -> Wtq[3072][1024] ----
        int i = b - 17280;
        int bx = i % 96, by = i / 96;
        int tx = threadIdx.x & 31, ty = threadIdx.x >> 5;
        for (int r = ty; r < 32; r += 8)
            tile[r][tx] = Wqkv[(size_t)(by * 32 + r) * 3072 + bx * 32 + tx];
        __syncthreads();
        for (int r = ty; r < 32; r += 8)
            Wtq[(size_t)(bx * 32 + r) * 1024 + by * 32 + tx] = (_Float16)tile[tx][r];
    } else {
        // ---- transpose+cast Wproj[1024][1024] -> Wtp[1024][1024] ----
        int i = b - 20352;
        int bx = i & 31, by = i >> 5;
        int tx = threadIdx.x & 31, ty = threadIdx.x >> 5;
        for (int r = ty; r < 32; r += 8)
            tile[r][tx] = Wproj[(size_t)(by * 32 + r) * 1024 + bx * 32 + tx];
        __syncthreads();
        for (int r = ty; r < 32; r += 8)
            Wtp[(size_t)(bx * 32 + r) * 1024 + by * 32 + tx] = (_Float16)tile[tx][r];
    }
}

// ---- hash extract: scores + bias -> gray hash; flag |val|<TAU ----
__global__ __launch_bounds__(256) void hashext_kernel(
    const float* __restrict__ scores, const float* __restrict__ bfold32,
    int* __restrict__ hq, int* __restrict__ hk,
    int* __restrict__ wcount, int* __restrict__ wlist)
{
    int tid = blockIdx.x * 256 + threadIdx.x;
    int row = tid >> 5, task = tid & 31;
    const float* sp = scores + (size_t)row * 256 + task * 7;
    int id = 0, fl = 0;
#pragma unroll
    for (int r = 0; r < 7; ++r) {
        float val = sp[r] + bfold32[task * 7 + r];
        if (fabsf(val) < TAU) fl = 1;
        if (val > 0.f) id |= (1 << r);
    }
    int hsh = id ^ (id >> 1);
    int w = task >> 4, h = task & 15;
    int b = row >> 13, l = row & 8191;
    (w ? hk : hq)[((size_t)(b * 16 + h) << 13) + l] = hsh;
    if (fl) {
        int slot = atomicAdd(wcount, 1);
        if (slot < WLIST_CAP) wlist[slot] = task * 16384 + row;
    }
}

// ---- refine: one WAVE per flagged (task,row); lane-parallel exact fp64 dot ----
__global__ __launch_bounds__(256) void refine_kernel(
    const float* __restrict__ x, const double* __restrict__ fold,
    const double* __restrict__ bfold, const int* __restrict__ wcount,
    const int* __restrict__ wlist, int* __restrict__ hq, int* __restrict__ hk)
{
    int n = *wcount;
    if (n > WLIST_CAP) n = WLIST_CAP;
    int lane = threadIdx.x & 63;
    int wid = (blockIdx.x * 256 + threadIdx.x) >> 6;
    int nw = gridDim.x * 4;
    for (int e = wid; e < n; e += nw) {
        int code = wlist[e];
        int task = code >> 14, grow = code & 16383;
        const double* f = fold + (size_t)task * 7168;
        const float* xp = x + (size_t)grow * 1024;
        double acc[7] = {0, 0, 0, 0, 0, 0, 0};
        for (int i = lane; i < 1024; i += 64) {
            double xv = (double)xp[i];
#pragma unroll
            for (int rr = 0; rr < 7; ++rr)
                acc[rr] = fma(xv, f[(size_t)i * 7 + rr], acc[rr]);
        }
        int id = 0;
#pragma unroll
        for (int rr = 0; rr < 7; ++rr) {
            double a = acc[rr];
#pragma unroll
            for (int off = 32; off > 0; off >>= 1) a += __shfl_xor(a, off, 64);
            if (a + bfold[task * 7 + rr] > 0.0) id |= (1 << rr);
        }
        if (lane == 0) {
            int hsh = id ^ (id >> 1);
            int w = task >> 4, h = task & 15;
            int b = grow >> 13, l = grow & 8191;
            (w ? hk : hq)[((size_t)(b * 16 + h) << 13) + l] = hsh;
        }
    }
}

// ---- stable counting sort (128 buckets) per (b,h); also emits rank (inverse) ----
__global__ __launch_bounds__(256) void sort_kernel(
    const int* __restrict__ hq, const int* __restrict__ hk,
    int* __restrict__ qidx, int* __restrict__ kidx,
    int* __restrict__ qrank, int* __restrict__ krank)
{
    __shared__ unsigned short cnt[128][128];
    __shared__ int tot[128];
    __shared__ int base[128];
    int blk = blockIdx.x;
    int sel = blk >> 5, bh = blk & 31;
    const int* hp = (sel ? hk : hq) + ((size_t)bh << 13);
    int* op = (sel ? kidx : qidx) + ((size_t)bh << 13);
    int* rp = (sel ? krank : qrank) + ((size_t)bh << 13);
    int t = threadIdx.x;
    for (int i = t; i < 128 * 128 / 2; i += 256) ((unsigned int*)cnt)[i] = 0u;
    __syncthreads();
    if (t < 128) {
        const int* p = hp + t * 64;
        for (int j = 0; j < 64; ++j) cnt[t][p[j]]++;
    }
    __syncthreads();
    if (t < 128) {
        int run = 0;
        for (int c = 0; c < 128; ++c) {
            int x2 = cnt[c][t];
            cnt[c][t] = (unsigned short)run;
            run += x2;
        }
        tot[t] = run;
    }
    __syncthreads();
    if (t == 0) {
        int run = 0;
        for (int v = 0; v < 128; ++v) { base[v] = run; run += tot[v]; }
    }
    __syncthreads();
    if (t < 128) {
        const int* p = hp + t * 64;
        for (int j = 0; j < 64; ++j) {
            int v = p[j];
            int c = cnt[t][v];
            cnt[t][v] = (unsigned short)(c + 1);
            int pos = base[v] + c;
            op[pos] = t * 64 + j;
            rp[t * 64 + j] = pos;
        }
    }
}

// ---- gather sampled K/V rows (sorted order) into dense per-bh buffers ----
__global__ __launch_bounds__(256) void gather_samp_kernel(
    const _Float16* __restrict__ ks, const _Float16* __restrict__ vs,
    const int* __restrict__ sampled, _Float16* __restrict__ ksamp,
    _Float16* __restrict__ vsamp)
{
    int bh = blockIdx.x;
    int key = blockIdx.y * 64 + (threadIdx.x >> 2);
    int qtr = (threadIdx.x & 3) * 16;
    size_t hb = (size_t)bh << 13;
    int p = sampled[bh * 256 + key];
    size_t src = (hb + p) * 64 + qtr;
    size_t dst = ((size_t)bh * 256 + key) * 64 + qtr;
    *(f16x8*)(ksamp + dst)     = *(const f16x8*)(ks + src);
    *(f16x8*)(ksamp + dst + 8) = *(const f16x8*)(ks + src + 8);
    *(f16x8*)(vsamp + dst)     = *(const f16x8*)(vs + src);
    *(f16x8*)(vsamp + dst + 8) = *(const f16x8*)(vs + src + 8);
}

// ---- plain f16 MFMA GEMM, BK=64 + XOR swizzle (R16): MODE 0=+bias, 2=no bias ----
template <int MODE>
__global__ __launch_bounds__(256) void mfma_gemm(
    const _Float16* __restrict__ A, const _Float16* __restrict__ Bt,
    const float* __restrict__ bias, float* __restrict__ C, int K, int N)
{
    __shared__ __align__(16) _Float16 As[128 * 64];
    __shared__ __align__(16) _Float16 Bs[128 * 64];
    int t = threadIdx.x;
    int w = t >> 6, l = t & 63;
    int m0 = blockIdx.y * 128, n0 = blockIdx.x * 128;
    int srow = 32 * w + (l >> 3);
    int sslot = ((l & 7) ^ (l >> 3)) * 8;
    const _Float16* ga = A + (size_t)(m0 + srow) * K + sslot;
    const _Float16* gb = Bt + (size_t)(n0 + srow) * K + sslot;
    int wr = w >> 1, wc = w & 1;
    int rl = l & 15, ks = l >> 4;
    f32x4 acc[4][4];
#pragma unroll
    for (int m = 0; m < 4; ++m)
#pragma unroll
        for (int n = 0; n < 4; ++n) acc[m][n] = (f32x4){0.f, 0.f, 0.f, 0.f};
    for (int kk = 0; kk < K; kk += 64) {
        __syncthreads();
#pragma unroll
        for (int i = 0; i < 4; ++i) {
            gl_lds16(ga + (size_t)(8 * i) * K + kk, (char*)As + (32 * w + 8 * i) * 128);
            gl_lds16(gb + (size_t)(8 * i) * K + kk, (char*)Bs + (32 * w + 8 * i) * 128);
        }
        __syncthreads();
        f16x8 af[4][2], bf[4][2];
#pragma unroll
        for (int m = 0; m < 4; ++m) {
            int r = 64 * wr + 16 * m + rl;
            int sw = (r & 7) << 4;
#pragma unroll
            for (int s = 0; s < 2; ++s)
                af[m][s] = *(const f16x8*)((char*)As + r * 128 + (((s * 4 + ks) << 4) ^ sw));
        }
#pragma unroll
        for (int n = 0; n < 4; ++n) {
            int r = 64 * wc + 16 * n + rl;
            int sw = (r & 7) << 4;
#pragma unroll
            for (int s = 0; s < 2; ++s)
                bf[n][s] = *(const f16x8*)((char*)Bs + r * 128 + (((s * 4 + ks) << 4) ^ sw));
        }
#pragma unroll
        for (int m = 0; m < 4; ++m)
#pragma unroll
            for (int n = 0; n < 4; ++n) {
                acc[m][n] = __builtin_amdgcn_mfma_f32_16x16x32_f16(
                    af[m][0], bf[n][0], acc[m][n], 0, 0, 0);
                acc[m][n] = __builtin_amdgcn_mfma_f32_16x16x32_f16(
                    af[m][1], bf[n][1], acc[m][n], 0, 0, 0);
            }
    }
#pragma unroll
    for (int m = 0; m < 4; ++m)
#pragma unroll
        for (int n = 0; n < 4; ++n) {
            int gn = n0 + 64 * wc + 16 * n + rl;
            float bv = (MODE == 2) ? 0.f : bias[gn];
#pragma unroll
            for (int j = 0; j < 4; ++j) {
                int gm = m0 + 64 * wr + 16 * m + 4 * ks + j;
                C[(size_t)gm * N + gn] = acc[m][n][j] + bv;
            }
        }
}

// ---- QKV GEMM: 256x256, BK=64, 8 waves, double-buffered pipeline (R17) ----
__global__ __launch_bounds__(512) void gemm_qkv_kernel(
    const _Float16* __restrict__ Wt, const _Float16* __restrict__ xh,
    const float* __restrict__ bias, _Float16* __restrict__ Q,
    _Float16* __restrict__ Kb, _Float16* __restrict__ Vb,
    const int* __restrict__ qrank, const int* __restrict__ krank)
{
    extern __shared__ __align__(16) char smem[];   // [buf][A 32K | B 32K] = 128 KB
    const int K = 1024;
    int bid = blockIdx.x;
    int xcd = bid & 7, slot = bid >> 3;
    int ty = slot / 12, tx = slot - ty * 12;
    int m0 = tx * 256;
    int n0 = (xcd * 8 + ty) * 256;
    int t = threadIdx.x;
    int w = t >> 6, l = t & 63;
    int wr = w >> 2, wc = w & 3;
    int rl = l & 15, ks = l >> 4;
    int srow = t >> 3;
    int sslot = (t & 7) ^ ((t >> 3) & 7);
    const _Float16* gA = Wt + (size_t)m0 * K + sslot * 8;
    const _Float16* gB = xh + (size_t)n0 * K + sslot * 8;
    char* dstT = smem + t * 16;

    auto STAGE = [&](int buf, int op, int half, int kt) {
        const _Float16* src = op ? gB : gA;
        char* d = dstT + buf * 65536 + op * 32768 + half * 16384;
        size_t ro = (size_t)(half * 128 + srow) * K + kt * 64;
        gl_lds16(src + ro, d);
        gl_lds16(src + ro + (size_t)64 * K, d + 8192);
    };

    int fbase = m0 + 128 * wr;
    int s0 = fbase >> 10;
    int h0 = (fbase >> 6) & 15;
    int b2 = n0 >> 13;
    const int* rk = (s0 == 0) ? qrank : krank;
    _Float16* dq = (s0 == 0) ? Q : (s0 == 1 ? Kb : Vb);
    int tl = (n0 & 8191) + 64 * wc;
    int pos[2][4];
#pragma unroll
    for (int hf = 0; hf < 2; ++hf)
#pragma unroll
        for (int n = 0; n < 4; ++n)
            pos[hf][n] = rk[((size_t)(b2 * 16 + h0 + hf) << 13) + tl + 16 * n + rl];
    float4 bias4[8];
#pragma unroll
    for (int m = 0; m < 8; ++m)
        bias4[m] = *(const float4*)&bias[fbase + 16 * m + 4 * ks];

    f32x4 acc[8][4];
#pragma unroll
    for (int m = 0; m < 8; ++m)
#pragma unroll
        for (int n = 0; n < 4; ++n) acc[m][n] = (f32x4){0.f, 0.f, 0.f, 0.f};

    STAGE(0, 0, 0, 0); STAGE(0, 0, 1, 0); STAGE(0, 1, 0, 0); STAGE(0, 1, 1, 0);
    STAGE(1, 1, 0, 1); STAGE(1, 1, 1, 1);

    for (int tt = 0; tt < 16; ++tt) {
        int buf = tt & 1, obuf = buf ^ 1;
        if (tt < 15) asm volatile("s_waitcnt vmcnt(4)" ::: "memory");
        else         asm volatile("s_waitcnt vmcnt(0)" ::: "memory");
        __builtin_amdgcn_sched_barrier(0);
        __builtin_amdgcn_s_barrier();
        __builtin_amdgcn_sched_barrier(0);
        const char* Ab = smem + buf * 65536;
        const char* Bb = Ab + 32768;
        f16x8 bf[4][2], af01[2][2];
#pragma unroll
        for (int n = 0; n < 4; ++n) {
            int r = 64 * wc + 16 * n + rl;
            int sw = (r & 7) << 4;
            bf[n][0] = *(const f16x8*)(Bb + r * 128 + ((ks << 4) ^ sw));
            bf[n][1] = *(const f16x8*)(Bb + r * 128 + (((4 + ks) << 4) ^ sw));
        }
#pragma unroll
        for (int m = 0; m < 2; ++m) {
            int r = 128 * wr + 16 * m + rl;
            int sw = (r & 7) << 4;
            af01[m][0] = *(const f16x8*)(Ab + r * 128 + ((ks << 4) ^ sw));
            af01[m][1] = *(const f16x8*)(Ab + r * 128 + (((4 + ks) << 4) ^ sw));
        }
        if (tt + 1 < 16) STAGE(obuf, 0, 0, tt + 1);
        __builtin_amdgcn_s_setprio(1);
#pragma unroll
        for (int m = 0; m < 2; ++m)
#pragma unroll
            for (int n = 0; n < 4; ++n) {
                acc[m][n] = __builtin_amdgcn_mfma_f32_16x16x32_f16(
                    af01[m][0], bf[n][0], acc[m][n], 0, 0, 0);
                acc[m][n] = __builtin_amdgcn_mfma_f32_16x16x32_f16(
                    af01[m][1], bf[n][1], acc[m][n], 0, 0, 0);
            }
        __builtin_amdgcn_s_setprio(0);
        f16x8 af27[6][2];
#pragma unroll
        for (int m = 0; m < 6; ++m) {
            int r = 128 * wr + 16 * (m + 2) + rl;
            int sw = (r & 7) << 4;
            af27[m][0] = *(const f16x8*)(Ab + r * 128 + ((ks << 4) ^ sw));
            af27[m][1] = *(const f16x8*)(Ab + r * 128 + (((4 + ks) << 4) ^ sw));
        }
        if (tt + 1 < 16) STAGE(obuf, 0, 1, tt + 1);
        __builtin_amdgcn_s_setprio(1);
#pragma unroll
        for (int m = 0; m < 2; ++m)
#pragma unroll
            for (int n = 0; n < 4; ++n) {
                acc[m + 2][n] = __builtin_amdgcn_mfma_f32_16x16x32_f16(
                    af27[m][0], bf[n][0], acc[m + 2][n], 0, 0, 0);
                acc[m + 2][n] = __builtin_amdgcn_mfma_f32_16x16x32_f16(
                    af27[m][1], bf[n][1], acc[m + 2][n], 0, 0, 0);
            }
        __builtin_amdgcn_s_setprio(0);
        asm volatile("" ::: "memory");
        __builtin_amdgcn_s_barrier();
        __builtin_amdgcn_sched_barrier(0);
        if (tt + 2 < 16) STAGE(buf, 1, 0, tt + 2);
        __builtin_amdgcn_s_setprio(1);
#pragma unroll
        for (int m = 2; m < 4; ++m)
#pragma unroll
            for (int n = 0; n < 4; ++n) {
                acc[m + 2][n] = __builtin_amdgcn_mfma_f32_16x16x32_f16(
                    af27[m][0], bf[n][0], acc[m + 2][n], 0, 0, 0);
                acc[m + 2][n] = __builtin_amdgcn_mfma_f32_16x16x32_f16(
                    af27[m][1], bf[n][1], acc[m + 2][n], 0, 0, 0);
            }
        __builtin_amdgcn_s_setprio(0);
        if (tt + 2 < 16) STAGE(buf, 1, 1, tt + 2);
        __builtin_amdgcn_s_setprio(1);
#pragma unroll
        for (int m = 4; m < 6; ++m)
#pragma unroll
            for (int n = 0; n < 4; ++n) {
                acc[m + 2][n] = __builtin_amdgcn_mfma_f32_16x16x32_f16(
                    af27[m][0], bf[n][0], acc[m + 2][n], 0, 0, 0);
                acc[m + 2][n] = __builtin_amdgcn_mfma_f32_16x16x32_f16(
                    af27[m][1], bf[n][1], acc[m + 2][n], 0, 0, 0);
            }
        __builtin_amdgcn_s_setprio(0);
    }
#pragma unroll
    for (int m = 0; m < 8; ++m) {
        int hf = m >> 2;
        size_t bhb = ((size_t)(b2 * 16 + h0 + hf) << 13);
        int d = 16 * (m & 3) + 4 * ks;
#pragma unroll
        for (int n = 0; n < 4; ++n) {
            f16x4 st;
            st[0] = (_Float16)(acc[m][n][0] + bias4[m].x);
            st[1] = (_Float16)(acc[m][n][1] + bias4[m].y);
            st[2] = (_Float16)(acc[m][n][2] + bias4[m].z);
            st[3] = (_Float16)(acc[m][n][3] + bias4[m].w);
            *(f16x4*)(dq + (bhb + pos[hf][n]) * 64 + d) = st;
        }
    }
}

// ---- OUT GEMM: validated 256x256 pipeline template, fp32+bias epilogue ----
__global__ __launch_bounds__(512) void gemm_out_kernel(
    const _Float16* __restrict__ Ap, const _Float16* __restrict__ Bt,
    const float* __restrict__ bias, float* __restrict__ C)
{
    extern __shared__ __align__(16) char smem[];   // 128 KB
    const int K = 1024;
    int bid = blockIdx.x;                 // 256 = 64 m-tiles x 4 n-tiles
    int m0 = (bid >> 2) * 256;
    int n0 = (bid & 3) * 256;
    int t = threadIdx.x;
    int w = t >> 6, l = t & 63;
    int wr = w >> 2, wc = w & 3;
    int rl = l & 15, ks = l >> 4;
    int srow = t >> 3;
    int sslot = (t & 7) ^ ((t >> 3) & 7);
    const _Float16* gA = Ap + (size_t)m0 * K + sslot * 8;
    const _Float16* gB = Bt + (size_t)n0 * K + sslot * 8;
    char* dstT = smem + t * 16;

    auto STAGE = [&](int buf, int op, int half, int kt) {
        const _Float16* src = op ? gB : gA;
        char* d = dstT + buf * 65536 + op * 32768 + half * 16384;
        size_t ro = (size_t)(half * 128 + srow) * K + kt * 64;
        gl_lds16(src + ro, d);
        gl_lds16(src + ro + (size_t)64 * K, d + 8192);
    };

    f32x4 acc[8][4];
#pragma unroll
    for (int m = 0; m < 8; ++m)
#pragma unroll
        for (int n = 0; n < 4; ++n) acc[m][n] = (f32x4){0.f, 0.f, 0.f, 0.f};

    STAGE(0, 0, 0, 0); STAGE(0, 0, 1, 0); STAGE(0, 1, 0, 0); STAGE(0, 1, 1, 0);
    STAGE(1, 1, 0, 1); STAGE(1, 1, 1, 1);

    for (int tt = 0; tt < 16; ++tt) {
        int buf = tt & 1, obuf = buf ^ 1;
        if (tt < 15) asm volatile("s_waitcnt vmcnt(4)" ::: "memory");
        else         asm volatile("s_waitcnt vmcnt(0)" ::: "memory");
        __builtin_amdgcn_sched_barrier(0);
        __builtin_amdgcn_s_barrier();
        __builtin_amdgcn_sched_barrier(0);
        const char* Ab = smem + buf * 65536;
        const char* Bb = Ab + 32768;
        f16x8 bf[4][2], af01[2][2];
#pragma unroll
        for (int n = 0; n < 4; ++n) {
            int r = 64 * wc + 16 * n + rl;
            int sw = (r & 7) << 4;
            bf[n][0] = *(const f16x8*)(Bb + r * 128 + ((ks << 4) ^ sw));
            bf[n][1] = *(const f16x8*)(Bb + r * 128 + (((4 + ks) << 4) ^ sw));
        }
#pragma unroll
        for (int m = 0; m < 2; ++m) {
            int r = 128 * wr + 16 * m + rl;
            int sw = (r & 7) << 4;
            af01[m][0] = *(const f16x8*)(Ab + r * 128 + ((ks << 4) ^ sw));
            af01[m][1] = *(const f16x8*)(Ab + r * 128 + (((4 + ks) << 4) ^ sw));
        }
        if (tt + 1 < 16) STAGE(obuf, 0, 0, tt + 1);
        __builtin_amdgcn_s_setprio(1);
#pragma unroll
        for (int m = 0; m < 2; ++m)
#pragma unroll
            for (int n = 0; n < 4; ++n) {
                acc[m][n] = __builtin_amdgcn_mfma_f32_16x16x32_f16(
                    af01[m][0], bf[n][0], acc[m][n], 0, 0, 0);
                acc[m][n] = __builtin_amdgcn_mfma_f32_16x16x32_f16(
                    af01[m][1], bf[n][1], acc[m][n], 0, 0, 0);
            }
        __builtin_amdgcn_s_setprio(0);
        f16x8 af27[6][2];
#pragma unroll
        for (int m = 0; m < 6; ++m) {
            int r = 128 * wr + 16 * (m + 2) + rl;
            int sw = (r & 7) << 4;
            af27[m][0] = *(const f16x8*)(Ab + r * 128 + ((ks << 4) ^ sw));
            af27[m][1] = *(const f16x8*)(Ab + r * 128 + (((4 + ks) << 4) ^ sw));
        }
        if (tt + 1 < 16) STAGE(obuf, 0, 1, tt + 1);
        __builtin_amdgcn_s_setprio(1);
#pragma unroll
        for (int m = 0; m < 2; ++m)
#pragma unroll
            for (int n = 0; n < 4; ++n) {
                acc[m + 2][n] = __builtin_amdgcn_mfma_f32_16x16x32_f16(
                    af27[m][0], bf[n][0], acc[m + 2][n], 0, 0, 0);
                acc[m + 2][n] = __builtin_amdgcn_mfma_f32_16x16x32_f16(
                    af27[m][1], bf[n][1], acc[m + 2][n], 0, 0, 0);
            }
        __builtin_amdgcn_s_setprio(0);
        asm volatile("" ::: "memory");
        __builtin_amdgcn_s_barrier();
        __builtin_amdgcn_sched_barrier(0);
        if (tt + 2 < 16) STAGE(buf, 1, 0, tt + 2);
        __builtin_amdgcn_s_setprio(1);
#pragma unroll
        for (int m = 2; m < 4; ++m)
#pragma unroll
            for (int n = 0; n < 4; ++n) {
                acc[m + 2][n] = __builtin_amdgcn_mfma_f32_16x16x32_f16(
                    af27[m][0], bf[n][0], acc[m + 2][n], 0, 0, 0);
                acc[m + 2][n] = __builtin_amdgcn_mfma_f32_16x16x32_f16(
                    af27[m][1], bf[n][1], acc[m + 2][n], 0, 0, 0);
            }
        __builtin_amdgcn_s_setprio(0);
        if (tt + 2 < 16) STAGE(buf, 1, 1, tt + 2);
        __builtin_amdgcn_s_setprio(1);
#pragma unroll
        for (int m = 4; m < 6; ++m)
#pragma unroll
            for (int n = 0; n < 4; ++n) {
                acc[m + 2][n] = __builtin_amdgcn_mfma_f32_16x16x32_f16(
                    af27[m][0], bf[n][0], acc[m + 2][n], 0, 0, 0);
                acc[m + 2][n] = __builtin_amdgcn_mfma_f32_16x16x32_f16(
                    af27[m][1], bf[n][1], acc[m + 2][n], 0, 0, 0);
            }
        __builtin_amdgcn_s_setprio(0);
    }
#pragma unroll
    for (int m = 0; m < 8; ++m)
#pragma unroll
        for (int n = 0; n < 4; ++n) {
            int gn = n0 + 64 * wc + 16 * n + rl;
            float bv = bias[gn];
#pragma unroll
            for (int j = 0; j < 4; ++j) {
                int gm = m0 + 128 * wr + 16 * m + 4 * ks + j;
                C[(size_t)gm * 1024 + gn] = acc[m][n][j] + bv;
            }
        }
}

// ---- MFMA fused attention; coalesced K/V; XCD-chunked grid (R12-R18) ----
__global__ __launch_bounds__(256) void attn_mfma_kernel(
    const _Float16* __restrict__ qs_, const _Float16* __restrict__ ks_,
    const _Float16* __restrict__ vs_, const _Float16* __restrict__ ksamp,
    const _Float16* __restrict__ vsamp, const int* __restrict__ qidx,
    const int* __restrict__ sampled, _Float16* __restrict__ pre)
{
    __shared__ __align__(16) _Float16 Vt[2][64 * 68];
    int bid = blockIdx.x;
    int nb = (bid & 7) * 256 + (bid >> 3);
    int bh = nb >> 6, qb = (nb >> 1) & 31, half = nb & 1;
    int bb = bh >> 4, hh = bh & 15;
    size_t hb = (size_t)bh << 13;
    size_t bhs = (size_t)bh * 256;
    int t = threadIdx.x;
    int w = t >> 6, l = t & 63;
    int g = l >> 4, c16 = l & 15;
    int kg = t & 15, dg = t >> 4;
    int qw0 = qb * 256 + half * 128 + w * 32;
    const _Float16 qs = (_Float16)0.125f;

    int orig[2];
    f16x8 qf[2][2];
#pragma unroll
    for (int n = 0; n < 2; ++n) {
        int row = qw0 + 16 * n + c16;
        orig[n] = qidx[hb + row];
        const _Float16* qp = qs_ + (hb + row) * 64 + g * 8;
        qf[n][0] = *(const f16x8*)(qp);
        qf[n][1] = *(const f16x8*)(qp + 32);
#pragma unroll
        for (int j = 0; j < 8; ++j) { qf[n][0][j] *= qs; qf[n][1][j] *= qs; }
    }
    f32x4 o[4][2];
    float mr[2], lr[2];
#pragma unroll
    for (int n = 0; n < 2; ++n) {
        mr[n] = -1e30f; lr[n] = 0.f;
#pragma unroll
        for (int d2 = 0; d2 < 4; ++d2) o[d2][n] = (f32x4){0.f, 0.f, 0.f, 0.f};
    }
    const float LOG32 = 3.4657359027997265f;

    {
        const _Float16* vb = vs_ + (hb + qb * 256) * 64;
        f16x4 vr[4];
#pragma unroll
        for (int j2 = 0; j2 < 4; ++j2)
            vr[j2] = *(const f16x4*)(vb + (4 * kg + j2) * 64 + 4 * dg);
#pragma unroll
        for (int i = 0; i < 4; ++i) {
            f16x4 o4 = {vr[0][i], vr[1][i], vr[2][i], vr[3][i]};
            *(f16x4*)&Vt[0][(4 * dg + i) * 68 + 4 * kg] = o4;
        }
    }

    for (int c = 0; c < 8; ++c) {
        int cur = c & 1, nxt = cur ^ 1;
        bool samp = c >= 4;
        __syncthreads();
        const _Float16* kb = samp ? ksamp + (bhs + (size_t)(c - 4) * 64) * 64
                                  : ks_ + (hb + qb * 256 + (size_t)c * 64) * 64;
        f16x8 kf[4][2];
#pragma unroll
        for (int m = 0; m < 4; ++m) {
            const _Float16* kp = kb + (16 * m + c16) * 64 + g * 8;
            kf[m][0] = *(const f16x8*)(kp);
            kf[m][1] = *(const f16x8*)(kp + 32);
        }
        int4 spv[4];
        if (samp) {
#pragma unroll
            for (int m = 0; m < 4; ++m)
                spv[m] = *(const int4*)(sampled + bhs + (c - 4) * 64 + 16 * m + 4 * g);
        }
        f32x4 sacc[4][2];
#pragma unroll
        for (int m = 0; m < 4; ++m)
#pragma unroll
            for (int n = 0; n < 2; ++n) sacc[m][n] = (f32x4){0.f, 0.f, 0.f, 0.f};
#pragma unroll
        for (int m = 0; m < 4; ++m) {
#pragma unroll
            for (int n = 0; n < 2; ++n)
                sacc[m][n] = __builtin_amdgcn_mfma_f32_16x16x32_f16(
                    kf[m][0], qf[n][0], sacc[m][n], 0, 0, 0);
#pragma unroll
            for (int n = 0; n < 2; ++n)
                sacc[m][n] = __builtin_amdgcn_mfma_f32_16x16x32_f16(
                    kf[m][1], qf[n][1], sacc[m][n], 0, 0, 0);
        }
        f16x4 vrn[4];
        if (c < 7) {
            const _Float16* vb = (c + 1 >= 4)
                ? vsamp + (bhs + (size_t)(c - 3) * 64) * 64
                : vs_ + (hb + qb * 256 + (size_t)(c + 1) * 64) * 64;
#pragma unroll
            for (int j2 = 0; j2 < 4; ++j2)
                vrn[j2] = *(const f16x4*)(vb + (4 * kg + j2) * 64 + 4 * dg);
        }
        f16x4 av[4][4];
#pragma unroll
        for (int m = 0; m < 4; ++m)
#pragma unroll
            for (int d2 = 0; d2 < 4; ++d2)
                av[m][d2] = *(const f16x4*)&Vt[cur][(16 * d2 + c16) * 68 + 16 * m + 4 * g];
        bool msk[4][4];
#pragma unroll
        for (int m = 0; m < 4; ++m) {
            msk[m][0] = samp && ((spv[m].x >> 8) == qb);
            msk[m][1] = samp && ((spv[m].y >> 8) == qb);
            msk[m][2] = samp && ((spv[m].z >> 8) == qb);
            msk[m][3] = samp && ((spv[m].w >> 8) == qb);
        }
        float badd = samp ? LOG32 : 0.f;
#pragma unroll
        for (int n = 0; n < 2; ++n) {
            float sv[16];
#pragma unroll
            for (int m = 0; m < 4; ++m)
#pragma unroll
                for (int r = 0; r < 4; ++r)
                    sv[4 * m + r] = msk[m][r] ? -1e30f : sacc[m][n][r] + badd;
            float a0 = fmaxf(fmaxf(sv[0], sv[1]), sv[2]);
            float a1 = fmaxf(fmaxf(sv[3], sv[4]), sv[5]);
            float a2 = fmaxf(fmaxf(sv[6], sv[7]), sv[8]);
            float a3 = fmaxf(fmaxf(sv[9], sv[10]), sv[11]);
            float a4 = fmaxf(fmaxf(sv[12], sv[13]), sv[14]);
            float cm = fmaxf(fmaxf(fmaxf(a0, a1), a2), fmaxf(fmaxf(a3, a4), sv[15]));
            cm = fmaxf(cm, __shfl_xor(cm, 16, 64));
            cm = fmaxf(cm, __shfl_xor(cm, 32, 64));
            if (__any(cm > mr[n])) {
                float nm = fmaxf(mr[n], cm);
                float fq = __expf(mr[n] - nm);
                mr[n] = nm;
                lr[n] *= fq;
#pragma unroll
                for (int d2 = 0; d2 < 4; ++d2) {
                    o[d2][n][0] *= fq; o[d2][n][1] *= fq;
                    o[d2][n][2] *= fq; o[d2][n][3] *= fq;
                }
            }
            float pv16[16];
#pragma unroll
            for (int r = 0; r < 16; ++r) pv16[r] = __expf(sv[r] - mr[n]);
            float s0 = (pv16[0] + pv16[1]) + (pv16[2] + pv16[3]);
            float s1 = (pv16[4] + pv16[5]) + (pv16[6] + pv16[7]);
            float s2 = (pv16[8] + pv16[9]) + (pv16[10] + pv16[11]);
            float s3 = (pv16[12] + pv16[13]) + (pv16[14] + pv16[15]);
            float ps = (s0 + s1) + (s2 + s3);
            ps += __shfl_xor(ps, 16, 64);
            ps += __shfl_xor(ps, 32, 64);
            lr[n] += ps;
            f16x4 pb[4];
#pragma unroll
            for (int m = 0; m < 4; ++m) {
                fp16x2 c0 = __builtin_amdgcn_cvt_pkrtz(pv16[4 * m + 0], pv16[4 * m + 1]);
                fp16x2 c1 = __builtin_amdgcn_cvt_pkrtz(pv16[4 * m + 2], pv16[4 * m + 3]);
                pb[m][0] = (_Float16)c0[0]; pb[m][1] = (_Float16)c0[1];
                pb[m][2] = (_Float16)c1[0]; pb[m][3] = (_Float16)c1[1];
            }
#pragma unroll
            for (int d2 = 0; d2 < 4; ++d2)
#pragma unroll
                for (int m = 0; m < 4; ++m)
                    o[d2][n] = __builtin_amdgcn_mfma_f32_16x16x16f16(
                        av[m][d2], pb[m], o[d2][n], 0, 0, 0);
        }
        if (c < 7) {
#pragma unroll
            for (int i = 0; i < 4; ++i) {
                f16x4 o4 = {vrn[0][i], vrn[1][i], vrn[2][i], vrn[3][i]};
                *(f16x4*)&Vt[nxt][(4 * dg + i) * 68 + 4 * kg] = o4;
            }
        }
    }
#pragma unroll
    for (int n = 0; n < 2; ++n) {
        float invl = 1.f / lr[n];
        _Float16* pp = pre + ((size_t)(bb * 8192 + orig[n])) * 1024 + hh * 64;
#pragma unroll
        for (int d2 = 0; d2 < 4; ++d2) {
            f16x4 st;
            st[0] = (_Float16)(o[d2][n][0] * invl);
            st[1] = (_Float16)(o[d2][n][1] * invl);
            st[2] = (_Float16)(o[d2][n][2] * invl);
            st[3] = (_Float16)(o[d2][n][3] * invl);
            *(f16x4*)(pp + 16 * d2 + 4 * g) = st;
        }
    }
}

extern "C" void kernel_launch(void* const* d_in, const int* in_sizes, int n_in,
                              void* d_out, int out_size, void* d_ws, size_t ws_size,
                              hipStream_t stream)
{
    (void)in_sizes; (void)n_in; (void)out_size; (void)ws_size;
    const float* x     = (const float*)d_in[0];
    const float* Wqkv  = (const float*)d_in[1];
    const float* bqkv  = (const float*)d_in[2];
    const float* Wproj = (const float*)d_in[3];
    const float* bproj = (const float*)d_in[4];
    const float* proj  = (const float*)d_in[5];
    const int*   samp  = (const int*)d_in[6];
    float* out = (float*)d_out;

    char* ws = (char*)d_ws;
    size_t off = 0;
    auto take = [&](size_t bytes) {
        char* p = ws + off;
        off = (off + bytes + 255) & ~(size_t)255;
        return p;
    };
    _Float16* xh  = (_Float16*)take(33554432);   // x f16; reused as `pre`
    _Float16* q   = (_Float16*)take(33554432);   // [B,H,L,64] f16, SORTED rows
    _Float16* k   = (_Float16*)take(33554432);
    _Float16* v   = (_Float16*)take(33554432);
    float* scores = (float*)take(16777216);
    _Float16* Wtq = (_Float16*)take(6291456);
    _Float16* Wtp = (_Float16*)take(2097152);
    _Float16* foldh = (_Float16*)take(524288);
    _Float16* ksamp = (_Float16*)take(1048576);  // [32][256][64] f16
    _Float16* vsamp = (_Float16*)take(1048576);
    double* fold   = (double*)take(1835008);
    double* bfold  = (double*)take(1792);
    float* bfold32 = (float*)take(896);
    int* wcount = (int*)take(256);
    int* wlist  = (int*)take(WLIST_CAP * 4);
    int* hq    = (int*)take(1048576);
    int* hk    = (int*)take(1048576);
    int* qidx  = (int*)take(1048576);
    int* kidx  = (int*)take(1048576);
    int* qrank = (int*)take(1048576);
    int* krank = (int*)take(1048576);
    _Float16* pre = xh;   // alias: xh dead after gemm_qkv
    // total ~170 MB

    (void)hipFuncSetAttribute((const void*)gemm_qkv_kernel,
                              hipFuncAttributeMaxDynamicSharedMemorySize, 131072);
    (void)hipFuncSetAttribute((const void*)gemm_out_kernel,
                              hipFuncAttributeMaxDynamicSharedMemorySize, 131072);
    (void)hipMemsetAsync(wcount, 0, 4, stream);
    prep_kernel<<<dim3(21376), dim3(256), 0, stream>>>(
        x, xh, Wqkv, bqkv, proj, fold, bfold, foldh, bfold32, Wproj, Wtq, Wtp);
    mfma_gemm<2><<<dim3(2, 128), dim3(256), 0, stream>>>(
        xh, foldh, nullptr, scores, 1024, 256);
    hashext_kernel<<<dim3(2048), dim3(256), 0, stream>>>(
        scores, bfold32, hq, hk, wcount, wlist);
    refine_kernel<<<dim3(2048), dim3(256), 0, stream>>>(
        x, fold, bfold, wcount, wlist, hq, hk);
    sort_kernel<<<dim3(64), dim3(256), 0, stream>>>(
        hq, hk, qidx, kidx, qrank, krank);
    gemm_qkv_kernel<<<dim3(768), dim3(512), 131072, stream>>>(
        Wtq, xh, bqkv, q, k, v, qrank, krank);
    gather_samp_kernel<<<dim3(32, 4), dim3(256), 0, stream>>>(
        k, v, samp, ksamp, vsamp);
    attn_mfma_kernel<<<dim3(2048), dim3(256), 0, stream>>>(
        q, k, v, ksamp, vsamp, qidx, samp, pre);
    gemm_out_kernel<<<dim3(256), dim3(512), 131072, stream>>>(
        pre, Wtp, bproj, out);
}